// Round 11
// baseline (984.504 us; speedup 1.0000x reference)
//
#include <hip/hip_runtime.h>
#include <hip/hip_bf16.h>
#include <stdint.h>

typedef __bf16 bf16_t;
typedef __bf16 bf16x8 __attribute__((ext_vector_type(8)));
typedef float  f32x4  __attribute__((ext_vector_type(4)));

#define DEV __device__ __forceinline__

constexpr int   Bn = 2, Tn = 2048, Dn = 2048, Hn = 16, DHn = 128;
constexpr int   BTn = Bn * Tn;          // 4096 rows
constexpr int   TD3 = 3 * Dn;           // 6144
constexpr int   FGn = 5461, FGPn = 5632; // pad to 44*128 / 22*256
constexpr float EPSf   = 1e-5f;
constexpr float LOG2E  = 1.4426950408889634f;
constexpr float ASCALE = 0.08838834764831845f;   // 1/sqrt(128)
constexpr float LN1E4  = 9.210340371976184f;     // ln(10000)

// async global->LDS, 16B per lane, wave-uniform LDS base
DEV void gld16(void* lds, const void* g) {
  __builtin_amdgcn_global_load_lds(
      (__attribute__((address_space(1))) void*)(void*)g,
      (__attribute__((address_space(3))) void*)lds, 16, 0, 0);
}

// inline-asm LDS read, ordered only by explicit s_waitcnt lgkmcnt(N)
DEV bf16x8 dsr128(const bf16_t* p) {
  bf16x8 r;
  asm volatile("ds_read_b128 %0, %1"
               : "=v"(r)
               : "v"((const __attribute__((address_space(3))) bf16_t*)p));
  return r;
}

// ---------------- RMSNorm (fp32 in -> bf16 out) ----------------
__global__ __launch_bounds__(256)
void rmsnorm_k(const float* __restrict__ x, const float* __restrict__ w,
               bf16_t* __restrict__ out) {
  const int row = blockIdx.x;
  const int tid = threadIdx.x;
  const float* xr = x + (size_t)row * Dn;
  float4 a = ((const float4*)xr)[tid * 2];
  float4 b = ((const float4*)xr)[tid * 2 + 1];
  float ss = a.x*a.x + a.y*a.y + a.z*a.z + a.w*a.w
           + b.x*b.x + b.y*b.y + b.z*b.z + b.w*b.w;
#pragma unroll
  for (int off = 32; off > 0; off >>= 1) ss += __shfl_xor(ss, off, 64);
  __shared__ float red[4];
  if ((tid & 63) == 0) red[tid >> 6] = ss;
  __syncthreads();
  float tot = red[0] + red[1] + red[2] + red[3];
  float rms = rsqrtf(tot * (1.0f / Dn) + EPSf);
  float4 wa = ((const float4*)w)[tid * 2];
  float4 wb = ((const float4*)w)[tid * 2 + 1];
  bf16x8 o;
  o[0] = (bf16_t)(a.x * rms * wa.x); o[1] = (bf16_t)(a.y * rms * wa.y);
  o[2] = (bf16_t)(a.z * rms * wa.z); o[3] = (bf16_t)(a.w * rms * wa.w);
  o[4] = (bf16_t)(b.x * rms * wb.x); o[5] = (bf16_t)(b.y * rms * wb.y);
  o[6] = (bf16_t)(b.z * rms * wb.z); o[7] = (bf16_t)(b.w * rms * wb.w);
  *(bf16x8*)&out[(size_t)row * Dn + tid * 8] = o;
}

// ---------------- fp32 -> bf16 convert with zero padding ----------------
__global__ __launch_bounds__(256)
void cvt_pad_k(const float* __restrict__ src, bf16_t* __restrict__ dst,
               int srcR, int srcC, int dstC, int n8) {
  int i = blockIdx.x * 256 + threadIdx.x;
  if (i >= n8) return;
  long base = (long)i * 8;
  int r = (int)(base / dstC);
  int c = (int)(base % dstC);
  bf16x8 o;
#pragma unroll
  for (int k = 0; k < 8; ++k) {
    int cc = c + k;
    float v = (r < srcR && cc < srcC) ? src[(size_t)r * srcC + cc] : 0.0f;
    o[k] = (bf16_t)v;
  }
  *(bf16x8*)&dst[base] = o;
}

// ---------------- reduce: out = E + P0+P1+P2+P3 (split-K partials) -------
__global__ __launch_bounds__(256)
void reduce4(float* __restrict__ out, const float* __restrict__ E,
             const bf16_t* __restrict__ P0, const bf16_t* __restrict__ P1,
             const bf16_t* __restrict__ P2, const bf16_t* __restrict__ P3) {
  int i = blockIdx.x * 256 + threadIdx.x;     // 8 elems per thread
  bf16x8 p0 = *(const bf16x8*)&P0[(size_t)i * 8];
  bf16x8 p1 = *(const bf16x8*)&P1[(size_t)i * 8];
  bf16x8 p2 = *(const bf16x8*)&P2[(size_t)i * 8];
  bf16x8 p3 = *(const bf16x8*)&P3[(size_t)i * 8];
  float4 e0 = ((const float4*)E)[i * 2];
  float4 e1 = ((const float4*)E)[i * 2 + 1];
  float4 o0, o1;
  o0.x = e0.x + (float)p0[0] + (float)p1[0] + (float)p2[0] + (float)p3[0];
  o0.y = e0.y + (float)p0[1] + (float)p1[1] + (float)p2[1] + (float)p3[1];
  o0.z = e0.z + (float)p0[2] + (float)p1[2] + (float)p2[2] + (float)p3[2];
  o0.w = e0.w + (float)p0[3] + (float)p1[3] + (float)p2[3] + (float)p3[3];
  o1.x = e1.x + (float)p0[4] + (float)p1[4] + (float)p2[4] + (float)p3[4];
  o1.y = e1.y + (float)p0[5] + (float)p1[5] + (float)p2[5] + (float)p3[5];
  o1.z = e1.z + (float)p0[6] + (float)p1[6] + (float)p2[6] + (float)p3[6];
  o1.w = e1.w + (float)p0[7] + (float)p1[7] + (float)p2[7] + (float)p3[7];
  ((float4*)out)[i * 2]     = o0;
  ((float4*)out)[i * 2 + 1] = o1;
}

// ---------------- GEMM 256x256, A via 4-slot LDS ring, B direct L2->reg --
// Per step: 8 ds_read_b128 (A frags), 4 global B-loads (next step, C++:
// compiler inserts the counted vmcnt before their MFMA use), 2 gld16 (A
// slot T+3). FIFO proof of A publish: compiler's wait for B(T) (issued
// step T-1 BEFORE gldA(T+2)) drains gldA(T+1) -> slot T+1 is landed by
// the end-of-step barrier; asm vmcnt(8) is the independent guarantee.
// LDS = 64 KB -> 2 blocks/CU co-resident (R8: worth 1.45x).
// EPI: 0 = bf16 store ; 1 = f32 out = resid + acc
template<int EPI>
__global__ __launch_bounds__(512, 2)
void gemm256(const bf16_t* __restrict__ A, const bf16_t* __restrict__ W,
             void* Cp, const void* Ep, int M, int N, int K, int ldc, int nby) {
  __shared__ __align__(128) bf16_t As[4][256 * 32];   // 64 KB
  const int tid = threadIdx.x;
  const int lane = tid & 63, w = tid >> 6;
  const int wm = w >> 2, wn = w & 3;
  const int g = lane >> 4, q = lane & 15;

  const int nwg = gridDim.x;
  const int cpx = nwg >> 3;
  const int nid = (blockIdx.x & 7) * cpx + (blockIdx.x >> 3);
  const int bx = nid / nby, by = nid % nby;
  const int row0 = by * 256, col0 = bx * 256;

  f32x4 acc[8][4] = {};

  // A staging source (inverse of LDS chunk permutation)
  const bf16_t* Asrc[2];
  int aoff[2];
#pragma unroll
  for (int i = 0; i < 2; ++i) {
    int line = i * 64 + (tid >> 3);
    int val  = (tid & 7) ^ (line & 7);
    int r    = (val >> 2) * 128 + line;
    int c    = val & 3;
    Asrc[i] = A + (size_t)(row0 + r) * K + c * 8;
    aoff[i] = i * 8192 + w * 1024;
  }
  // B per-lane row pointers (direct global loads)
  const bf16_t* Wrow[4];
#pragma unroll
  for (int n = 0; n < 4; ++n)
    Wrow[n] = W + (size_t)(col0 + wn * 64 + n * 16 + q) * K + g * 8;

  int offA[8];
#pragma unroll
  for (int m = 0; m < 8; ++m) {
    int r = wm * 128 + m * 16 + q;
    offA[m] = (r & 127) * 128 + ((((r >> 7) * 4 + g) ^ (r & 7)) * 16);
  }

  const int NT = K >> 5;
  auto stage_half = [&](int T, int h) {
    gld16((char*)As[T & 3] + aoff[h], Asrc[h] + (size_t)T * 32);
  };
  auto ldB = [&](int T, bf16x8 (&dst)[4]) {
#pragma unroll
    for (int n = 0; n < 4; ++n) dst[n] = *(const bf16x8*)(Wrow[n] + (size_t)T * 32);
  };

  bf16x8 af[8], b0[4], b1[4];

  auto step = [&](int T, bf16x8 (&bc)[4], bf16x8 (&bn)[4],
                  bool st, bool pf, int pub) {
    const char* as_ = (const char*)As[T & 3];
#pragma unroll
    for (int m = 0; m < 8; ++m) af[m] = dsr128((const bf16_t*)(as_ + offA[m]));
    if (pf) ldB(T + 1, bn);
    if (st) { stage_half(T + 3, 0); stage_half(T + 3, 1); }
    asm volatile("s_waitcnt lgkmcnt(0)" ::: "memory");
    __builtin_amdgcn_sched_barrier(0);
    __builtin_amdgcn_s_setprio(1);
#pragma unroll
    for (int m = 0; m < 8; ++m)
#pragma unroll
      for (int n = 0; n < 4; ++n)
        acc[m][n] = __builtin_amdgcn_mfma_f32_16x16x32_bf16(af[m], bc[n], acc[m][n], 0, 0, 0);
    __builtin_amdgcn_s_setprio(0);
    __builtin_amdgcn_sched_barrier(0);
    if (pub == 1)      asm volatile("s_waitcnt vmcnt(8)" ::: "memory");
    else if (pub == 0) asm volatile("s_waitcnt vmcnt(0)" ::: "memory");
    asm volatile("s_barrier" ::: "memory");
  };

  stage_half(0, 0); stage_half(0, 1);
  stage_half(1, 0); stage_half(1, 1);
  stage_half(2, 0); stage_half(2, 1);
  ldB(0, b0);
  asm volatile("s_waitcnt vmcnt(8)" ::: "memory");   // slot 0 landed
  asm volatile("s_barrier" ::: "memory");

  int T = 0;
  for (; T < NT - 4; T += 2) {
    step(T,     b0, b1, true, true, 1);
    step(T + 1, b1, b0, true, true, 1);
  }
  step(NT - 4, b0, b1, true,  true,  1);
  step(NT - 3, b1, b0, false, true,  0);
  step(NT - 2, b0, b1, false, true,  0);
  step(NT - 1, b1, b0, false, false, 2);

#pragma unroll
  for (int m = 0; m < 8; ++m) {
#pragma unroll
    for (int n = 0; n < 4; ++n) {
#pragma unroll
      for (int j = 0; j < 4; ++j) {
        int r = row0 + wm * 128 + m * 16 + g * 4 + j;
        int c = col0 + wn * 64 + n * 16 + q;
        size_t idx = (size_t)r * ldc + c;
        float v = acc[m][n][j];
        if (EPI == 0) ((bf16_t*)Cp)[idx] = (bf16_t)v;
        else          ((float*)Cp)[idx] = ((const float*)Ep)[idx] + v;
      }
    }
  }
}

// ------- split-K=4 GEMM (proj & mlp): P[s] = A[:,ks] @ W[:,ks]^T ---------
// 512 blocks (= full 2/CU co-residency), 256x256 tiles, M=4096 N=2048.
// Same A-ring + B-direct structure as gemm256.
__global__ __launch_bounds__(512, 2)
void gemm_sk(const bf16_t* __restrict__ A, const bf16_t* __restrict__ W,
             bf16_t* __restrict__ P0, bf16_t* __restrict__ P1,
             bf16_t* __restrict__ P2, bf16_t* __restrict__ P3,
             int ldk, int klen, int ldc) {
  __shared__ __align__(128) bf16_t As[4][256 * 32];   // 64 KB
  const int tid = threadIdx.x;
  const int lane = tid & 63, w = tid >> 6;
  const int wm = w >> 2, wn = w & 3;
  const int g = lane >> 4, q = lane & 15;

  const int nid = (blockIdx.x & 7) * 64 + (blockIdx.x >> 3);  // 512 blocks
  const int s   = nid >> 7;
  const int t   = nid & 127;
  const int bx = t >> 4, by = t & 15;
  const int row0 = by * 256, col0 = bx * 256;
  const int kofs = s * klen;
  bf16_t* P = (s == 0) ? P0 : (s == 1) ? P1 : (s == 2) ? P2 : P3;

  f32x4 acc[8][4] = {};

  const bf16_t* Asrc[2];
  int aoff[2];
#pragma unroll
  for (int i = 0; i < 2; ++i) {
    int line = i * 64 + (tid >> 3);
    int val  = (tid & 7) ^ (line & 7);
    int r    = (val >> 2) * 128 + line;
    int c    = val & 3;
    Asrc[i] = A + (size_t)(row0 + r) * ldk + kofs + c * 8;
    aoff[i] = i * 8192 + w * 1024;
  }
  const bf16_t* Wrow[4];
#pragma unroll
  for (int n = 0; n < 4; ++n)
    Wrow[n] = W + (size_t)(col0 + wn * 64 + n * 16 + q) * ldk + kofs + g * 8;

  int offA[8];
#pragma unroll
  for (int m = 0; m < 8; ++m) {
    int r = wm * 128 + m * 16 + q;
    offA[m] = (r & 127) * 128 + ((((r >> 7) * 4 + g) ^ (r & 7)) * 16);
  }

  const int NT = klen >> 5;
  auto stage_half = [&](int T, int h) {
    gld16((char*)As[T & 3] + aoff[h], Asrc[h] + (size_t)T * 32);
  };
  auto ldB = [&](int T, bf16x8 (&dst)[4]) {
#pragma unroll
    for (int n = 0; n < 4; ++n) dst[n] = *(const bf16x8*)(Wrow[n] + (size_t)T * 32);
  };

  bf16x8 af[8], b0[4], b1[4];

  auto step = [&](int T, bf16x8 (&bc)[4], bf16x8 (&bn)[4],
                  bool st, bool pf, int pub) {
    const char* as_ = (const char*)As[T & 3];
#pragma unroll
    for (int m = 0; m < 8; ++m) af[m] = dsr128((const bf16_t*)(as_ + offA[m]));
    if (pf) ldB(T + 1, bn);
    if (st) { stage_half(T + 3, 0); stage_half(T + 3, 1); }
    asm volatile("s_waitcnt lgkmcnt(0)" ::: "memory");
    __builtin_amdgcn_sched_barrier(0);
    __builtin_amdgcn_s_setprio(1);
#pragma unroll
    for (int m = 0; m < 8; ++m)
#pragma unroll
      for (int n = 0; n < 4; ++n)
        acc[m][n] = __builtin_amdgcn_mfma_f32_16x16x32_bf16(af[m], bc[n], acc[m][n], 0, 0, 0);
    __builtin_amdgcn_s_setprio(0);
    __builtin_amdgcn_sched_barrier(0);
    if (pub == 1)      asm volatile("s_waitcnt vmcnt(8)" ::: "memory");
    else if (pub == 0) asm volatile("s_waitcnt vmcnt(0)" ::: "memory");
    asm volatile("s_barrier" ::: "memory");
  };

  stage_half(0, 0); stage_half(0, 1);
  stage_half(1, 0); stage_half(1, 1);
  stage_half(2, 0); stage_half(2, 1);
  ldB(0, b0);
  asm volatile("s_waitcnt vmcnt(8)" ::: "memory");
  asm volatile("s_barrier" ::: "memory");

  int T = 0;
  for (; T < NT - 4; T += 2) {
    step(T,     b0, b1, true, true, 1);
    step(T + 1, b1, b0, true, true, 1);
  }
  step(NT - 4, b0, b1, true,  true,  1);
  step(NT - 3, b1, b0, false, true,  0);
  step(NT - 2, b0, b1, false, true,  0);
  step(NT - 1, b1, b0, false, false, 2);

#pragma unroll
  for (int m = 0; m < 8; ++m)
#pragma unroll
    for (int n = 0; n < 4; ++n)
#pragma unroll
      for (int j = 0; j < 4; ++j) {
        int r = row0 + wm * 128 + m * 16 + g * 4 + j;
        int c = col0 + wn * 64 + n * 16 + q;
        P[(size_t)r * ldc + c] = (bf16_t)acc[m][n][j];
      }
}

// ------- fused gate+val dual GEMM: Out = silu(A Wg^T) * (A Wv^T) ---------
// 256M x 128N tile, A via 4-slot ring (64 KB), G/V direct L2->reg.
__global__ __launch_bounds__(512, 2)
void gemmgv(const bf16_t* __restrict__ A, const bf16_t* __restrict__ Wg,
            const bf16_t* __restrict__ Wv, bf16_t* __restrict__ Out,
            int K, int ldc, int nby) {
  __shared__ __align__(128) bf16_t As[4][256 * 32];   // 64 KB
  const int tid = threadIdx.x;
  const int lane = tid & 63, w = tid >> 6;
  const int wm = w >> 2, wn = w & 3;
  const int g = lane >> 4, q = lane & 15;

  const int nwg = gridDim.x;                 // 704, % 8 == 0
  const int cpx = nwg >> 3;
  const int nid = (blockIdx.x & 7) * cpx + (blockIdx.x >> 3);
  const int bx = nid / nby, by = nid % nby;
  const int row0 = by * 256, col0 = bx * 128;

  f32x4 ag[8][2] = {}, av[8][2] = {};

  const bf16_t* Asrc[2];
  int aoff[2];
#pragma unroll
  for (int i = 0; i < 2; ++i) {
    int line = i * 64 + (tid >> 3);
    int val  = (tid & 7) ^ (line & 7);
    int r    = (val >> 2) * 128 + line;
    int c    = val & 3;
    Asrc[i] = A + (size_t)(row0 + r) * K + c * 8;
    aoff[i] = i * 8192 + w * 1024;
  }
  const bf16_t* Grow[2];
  const bf16_t* Vrow[2];
#pragma unroll
  for (int n = 0; n < 2; ++n) {
    int r = col0 + wn * 32 + n * 16 + q;
    Grow[n] = Wg + (size_t)r * K + g * 8;
    Vrow[n] = Wv + (size_t)r * K + g * 8;
  }

  int offA[8];
#pragma unroll
  for (int m = 0; m < 8; ++m) {
    int r = wm * 128 + m * 16 + q;
    offA[m] = (r & 127) * 128 + ((((r >> 7) * 4 + g) ^ (r & 7)) * 16);
  }

  const int NT = K >> 5;
  auto stage_half = [&](int T, int h) {
    gld16((char*)As[T & 3] + aoff[h], Asrc[h] + (size_t)T * 32);
  };
  auto ldB = [&](int T, bf16x8 (&dg)[2], bf16x8 (&dv)[2]) {
#pragma unroll
    for (int n = 0; n < 2; ++n) {
      dg[n] = *(const bf16x8*)(Grow[n] + (size_t)T * 32);
      dv[n] = *(const bf16x8*)(Vrow[n] + (size_t)T * 32);
    }
  };

  bf16x8 af[8], g0[2], v0[2], g1[2], v1[2];

  auto step = [&](int T, bf16x8 (&gc)[2], bf16x8 (&vc)[2],
                  bf16x8 (&gn)[2], bf16x8 (&vn)[2], bool st, bool pf, int pub) {
    const char* as_ = (const char*)As[T & 3];
#pragma unroll
    for (int m = 0; m < 8; ++m) af[m] = dsr128((const bf16_t*)(as_ + offA[m]));
    if (pf) ldB(T + 1, gn, vn);
    if (st) { stage_half(T + 3, 0); stage_half(T + 3, 1); }
    asm volatile("s_waitcnt lgkmcnt(0)" ::: "memory");
    __builtin_amdgcn_sched_barrier(0);
    __builtin_amdgcn_s_setprio(1);
#pragma unroll
    for (int m = 0; m < 8; ++m)
#pragma unroll
      for (int n = 0; n < 2; ++n) {
        ag[m][n] = __builtin_amdgcn_mfma_f32_16x16x32_bf16(af[m], gc[n], ag[m][n], 0, 0, 0);
        av[m][n] = __builtin_amdgcn_mfma_f32_16x16x32_bf16(af[m], vc[n], av[m][n], 0, 0, 0);
      }
    __builtin_amdgcn_s_setprio(0);
    __builtin_amdgcn_sched_barrier(0);
    if (pub == 1)      asm volatile("s_waitcnt vmcnt(8)" ::: "memory");
    else if (pub == 0) asm volatile("s_waitcnt vmcnt(0)" ::: "memory");
    asm volatile("s_barrier" ::: "memory");
  };

  stage_half(0, 0); stage_half(0, 1);
  stage_half(1, 0); stage_half(1, 1);
  stage_half(2, 0); stage_half(2, 1);
  ldB(0, g0, v0);
  asm volatile("s_waitcnt vmcnt(8)" ::: "memory");
  asm volatile("s_barrier" ::: "memory");

  int T = 0;
  for (; T < NT - 4; T += 2) {
    step(T,     g0, v0, g1, v1, true, true, 1);
    step(T + 1, g1, v1, g0, v0, true, true, 1);
  }
  step(NT - 4, g0, v0, g1, v1, true,  true,  1);
  step(NT - 3, g1, v1, g0, v0, false, true,  0);
  step(NT - 2, g0, v0, g1, v1, false, true,  0);
  step(NT - 1, g1, v1, g0, v0, false, false, 2);

#pragma unroll
  for (int m = 0; m < 8; ++m) {
#pragma unroll
    for (int n = 0; n < 2; ++n) {
#pragma unroll
      for (int j = 0; j < 4; ++j) {
        int r = row0 + wm * 128 + m * 16 + g * 4 + j;
        int c = col0 + wn * 32 + n * 16 + q;
        float gt = ag[m][n][j];
        float sgm = gt / (1.0f + __expf(-gt));
        Out[(size_t)r * ldc + c] = (bf16_t)(sgm * av[m][n][j]);
      }
    }
  }
}

// ---------------- RoPE + split + V transpose ----------------
__global__ __launch_bounds__(256)
void rope_k(const bf16_t* __restrict__ qkv, bf16_t* __restrict__ Qb,
            bf16_t* __restrict__ Kb, bf16_t* __restrict__ Vt) {
  const int t0 = blockIdx.x * 32;
  const int bh = blockIdx.y;
  const int b = bh >> 4, hh = bh & 15;
  __shared__ bf16_t Vl[32][132];

#pragma unroll
  for (int it = 0; it < 2; ++it) {
    int task = threadIdx.x + it * 256;
    int tt = task >> 4, ck = task & 15, d0 = ck * 8;
    int tg = t0 + tt;
    const bf16_t* srow = qkv + (size_t)(b * Tn + tg) * TD3 + hh * DHn + d0;
    bf16x8 qv = *(const bf16x8*)(srow);
    bf16x8 kv = *(const bf16x8*)(srow + Dn);
    bf16x8 vv = *(const bf16x8*)(srow + 2 * Dn);
    bf16x8 qo, ko;
#pragma unroll
    for (int p = 0; p < 4; ++p) {
      int jj = (d0 >> 1) + p;
      float fr = __expf(-((float)(2 * jj) / 128.0f) * LN1E4);
      float ang = (float)tg * fr;
      float cs = cosf(ang), sn = sinf(ang);
      float qe = (float)qv[2 * p], qod = (float)qv[2 * p + 1];
      float ke = (float)kv[2 * p], kod = (float)kv[2 * p + 1];
      qo[2 * p]     = (bf16_t)((qe * cs - qod * sn) * ASCALE);
      qo[2 * p + 1] = (bf16_t)((qod * cs + qe * sn) * ASCALE);
      ko[2 * p]     = (bf16_t)(ke * cs - kod * sn);
      ko[2 * p + 1] = (bf16_t)(kod * cs + ke * sn);
    }
    *(bf16x8*)&Qb[((size_t)bh * Tn + tg) * DHn + d0] = qo;
    *(bf16x8*)&Kb[((size_t)bh * Tn + tg) * DHn + d0] = ko;
    *(bf16x8*)&Vl[tt][d0] = vv;
  }
  __syncthreads();
#pragma unroll
  for (int it = 0; it < 2; ++it) {
    int task = threadIdx.x + it * 256;
    int dd = task >> 2, tc = (task & 3) * 8;
    bf16x8 ov;
#pragma unroll
    for (int i = 0; i < 8; ++i) ov[i] = Vl[tc + i][dd];
    *(bf16x8*)&Vt[((size_t)bh * DHn + dd) * Tn + t0 + tc] = ov;
  }
}

// ---------------- causal flash attention, paired q-tiles ----------------
__global__ __launch_bounds__(256, 2)
void attn_k(const bf16_t* __restrict__ Qb, const bf16_t* __restrict__ Kb,
            const bf16_t* __restrict__ Vt, bf16_t* __restrict__ Y) {
  const int orig = blockIdx.x + 16 * blockIdx.y;   // 512 blocks total
  const int nid  = (orig & 7) * 64 + (orig >> 3);  // XCD-chunked, bijective
  const int pi = nid & 15;
  const int bh = nid >> 4;
  const int b = bh >> 4, hh = bh & 15;
  const int tid = threadIdx.x, lane = tid & 63, w = tid >> 6;
  const int g = lane >> 4, q = lane & 15;
  const int iA = pi, iB = 31 - pi;
  const int kmax = iB;

  __shared__ bf16_t Ks[2][64 * 128];
  __shared__ bf16_t Vs[2][128 * 64];
  __shared__ bf16_t Ps[4][16 * 72];

  bf16x8 aqA[4], aqB[4];
  {
    const bf16_t* QrA = Qb + ((size_t)bh * Tn + iA * 64 + w * 16 + q) * DHn;
    const bf16_t* QrB = Qb + ((size_t)bh * Tn + iB * 64 + w * 16 + q) * DHn;
#pragma unroll
    for (int s = 0; s < 4; ++s) {
      aqA[s] = *(const bf16x8*)(QrA + s * 32 + g * 8);
      aqB[s] = *(const bf16x8*)(QrB + s * 32 + g * 8);
    }
  }

  f32x4 oA[8] = {}, oB[8] = {};
  float mA[4], lA[4], mB[4], lB[4];
#pragma unroll
  for (int j = 0; j < 4; ++j) {
    mA[j] = -__builtin_inff(); lA[j] = 0.0f;
    mB[j] = -__builtin_inff(); lB[j] = 0.0f;
  }

  auto stage = [&](int buf, int kt) {
    const int k0 = kt * 64;
#pragma unroll
    for (int l = 0; l < 4; ++l) {
      int ci = (w * 4 + l) * 64 + lane;
      int kr = ci >> 4, kc = (ci & 15) ^ (kr & 7);
      gld16((char*)Ks[buf] + (w * 4 + l) * 1024,
            Kb + ((size_t)bh * Tn + k0 + kr) * DHn + kc * 8);
      int vr = ci >> 3, vc = (ci & 7) ^ (vr & 7);
      gld16((char*)Vs[buf] + (w * 4 + l) * 1024,
            Vt + ((size_t)bh * DHn + vr) * Tn + k0 + vc * 8);
    }
  };

  stage(0, 0);

  for (int kt = 0; kt <= kmax; ++kt) {
    __syncthreads();
    if (kt < kmax) stage((kt + 1) & 1, kt + 1);
    const bf16_t* ks = Ks[kt & 1];
    const bf16_t* vs = Vs[kt & 1];
    const bool actA = (kt <= iA);
    const int k0 = kt * 64;

    f32x4 saA[4] = {}, saB[4] = {};
    __builtin_amdgcn_s_setprio(1);
    if (actA) {
#pragma unroll
      for (int s = 0; s < 4; ++s) {
#pragma unroll
        for (int n = 0; n < 4; ++n) {
          bf16x8 bk = *(const bf16x8*)&ks[(n * 16 + q) * 128 + (((s * 4 + g) ^ (q & 7)) * 8)];
          saA[n] = __builtin_amdgcn_mfma_f32_16x16x32_bf16(aqA[s], bk, saA[n], 0, 0, 0);
          saB[n] = __builtin_amdgcn_mfma_f32_16x16x32_bf16(aqB[s], bk, saB[n], 0, 0, 0);
        }
      }
    } else {
#pragma unroll
      for (int s = 0; s < 4; ++s) {
#pragma unroll
        for (int n = 0; n < 4; ++n) {
          bf16x8 bk = *(const bf16x8*)&ks[(n * 16 + q) * 128 + (((s * 4 + g) ^ (q & 7)) * 8)];
          saB[n] = __builtin_amdgcn_mfma_f32_16x16x32_bf16(aqB[s], bk, saB[n], 0, 0, 0);
        }
      }
    }
    __builtin_amdgcn_s_setprio(0);

    bf16x8 paA[2], paB[2];
    auto softmax_p = [&](f32x4* sa, float* mst, float* lst, int itile,
                         bf16x8* pa, int qrow) {
      if (kt == itile) {
#pragma unroll
        for (int n = 0; n < 4; ++n)
#pragma unroll
          for (int j = 0; j < 4; ++j) {
            int kc = k0 + n * 16 + q;
            int qr = qrow + g * 4 + j;
            if (kc > qr) sa[n][j] = -1e30f;
          }
      }
      float mx[4];
#pragma unroll
      for (int j = 0; j < 4; ++j) {
        mx[j] = fmaxf(fmaxf(sa[0][j], sa[1][j]), fmaxf(sa[2][j], sa[3][j]));
#pragma unroll
        for (int off = 1; off < 16; off <<= 1)
          mx[j] = fmaxf(mx[j], __shfl_xor(mx[j], off, 16));
      }
      float ps[4][4], rsum[4];
#pragma unroll
      for (int j = 0; j < 4; ++j) rsum[j] = 0.0f;
      float mnew[4], corr[4];
#pragma unroll
      for (int j = 0; j < 4; ++j) {
        mnew[j] = fmaxf(mst[j], mx[j]);
        corr[j] = exp2f((mst[j] - mnew[j]) * LOG2E);
      }
#pragma unroll
      for (int n = 0; n < 4; ++n)
#pragma unroll
        for (int j = 0; j < 4; ++j) {
          ps[n][j] = exp2f((sa[n][j] - mnew[j]) * LOG2E);
          rsum[j] += ps[n][j];
        }
#pragma unroll
      for (int j = 0; j < 4; ++j) {
#pragma unroll
        for (int off = 1; off < 16; off <<= 1)
          rsum[j] += __shfl_xor(rsum[j], off, 16);
        lst[j] = lst[j] * corr[j] + rsum[j];
        mst[j] = mnew[j];
      }
#pragma unroll
      for (int n = 0; n < 4; ++n)
#pragma unroll
        for (int j = 0; j < 4; ++j)
          Ps[w][(g * 4 + j) * 72 + n * 16 + q] = (bf16_t)ps[n][j];
#pragma unroll
      for (int s2 = 0; s2 < 2; ++s2)
        pa[s2] = *(const bf16x8*)&Ps[w][q * 72 + s2 * 32 + g * 8];
      return corr;
    };

    float cA[4], cB[4];
    if (actA) {
      auto c = softmax_p(saA, mA, lA, iA, paA, iA * 64 + w * 16);
#pragma unroll
      for (int j = 0; j < 4; ++j) cA[j] = c[j];
#pragma unroll
      for (int n8 = 0; n8 < 8; ++n8)
#pragma unroll
        for (int j = 0; j < 4; ++j) oA[n8][j] *= cA[j];
    }
    {
      auto c = softmax_p(saB, mB, lB, iB, paB, iB * 64 + w * 16);
#pragma unroll
      for (int j = 0; j < 4; ++j) cB[j] = c[j];
#pragma unroll
      for (int n8 = 0; n8 < 8; ++n8)
#pragma unroll
        for (int j = 0; j < 4; ++j) oB[n8][j] *= cB[j];
    }

    __builtin_amdgcn_s_setprio(1);
    if (actA) {
#pragma unroll
      for (int s2 = 0; s2 < 2; ++s2)
#pragma unroll
        for (int n8 = 0; n8 < 8; ++n8) {
          bf16x8 bv = *(const bf16x8*)&vs[(n8 * 16 + q) * 64 + (((s2 * 4 + g) ^ (q & 7)) * 8)];
          oA[n8] = __builtin_amdgcn_mfma_f32_16x16x32_bf16(paA[s2], bv, oA[n8], 0, 0, 0);
          oB[n8] = __builtin_amdgcn_mfma_f32_16x16x32_bf16(paB[s2], bv, oB[n8], 0, 0, 0);
        }
    } else {
#pragma unroll
      for (int s2 = 0; s2 < 2; ++s2)
#pragma unroll
        for (int n8 = 0; n8 < 8; ++n8) {
          bf16x8 bv = *(const bf16x8*)&vs[(n8 * 16 + q) * 64 + (((s2 * 4 + g) ^ (q & 7)) * 8)];
          oB[n8] = __builtin_amdgcn_mfma_f32_16x16x32_bf16(paB[s2], bv, oB[n8], 0, 0, 0);
        }
    }
    __builtin_amdgcn_s_setprio(0);
  }

#pragma unroll
  for (int n8 = 0; n8 < 8; ++n8)
#pragma unroll
    for (int j = 0; j < 4; ++j) {
      int trA = iA * 64 + w * 16 + g * 4 + j;
      int trB = iB * 64 + w * 16 + g * 4 + j;
      Y[(size_t)(b * Tn + trA) * Dn + hh * DHn + n8 * 16 + q] =
          (bf16_t)(oA[n8][j] / lA[j]);
      Y[(size_t)(b * Tn + trB) * Dn + hh * DHn + n8 * 16 + q] =
          (bf16_t)(oB[n8][j] / lB[j]);
    }
}

// ---------------- launcher ----------------
extern "C" void kernel_launch(void* const* d_in, const int* in_sizes, int n_in,
                              void* d_out, int out_size, void* d_ws, size_t ws_size,
                              hipStream_t stream) {
  const float* x      = (const float*)d_in[0];
  const float* n1w    = (const float*)d_in[1];
  const float* n2w    = (const float*)d_in[2];
  const float* attn_w = (const float*)d_in[3];
  const float* proj_w = (const float*)d_in[4];
  const float* gate_w = (const float*)d_in[5];
  const float* val_w  = (const float*)d_in[6];
  const float* mlp_w  = (const float*)d_in[7];

  char* ws = (char*)d_ws;
  bf16_t* h    = (bf16_t*)(ws);                  // 16.78MB
  bf16_t* bufA = (bf16_t*)(ws + 16777216);       // 50.3MB
  bf16_t* bufB = (bf16_t*)(ws + 67108864);       // 50.3MB
  bf16_t* wb   = (bf16_t*)(ws + 117440512);      // 25.2MB

  bf16_t* qkv  = bufA;
  bf16_t* wbV  = bufA;   // val weights (bufA free after rope)
  bf16_t* Qb   = bufB;
  bf16_t* Kb   = Qb + (size_t)32 * Tn * DHn;
  bf16_t* Vt   = Kb + (size_t)32 * Tn * DHn;
  bf16_t* gv   = bufB;   // gate*val output (bufB free after attn... after proj partials)
  bf16_t* y    = h;
  float*  out  = (float*)d_out;

  // proj partials: bufA + first 16.78MB of bufB (all dead at that point)
  bf16_t* Pp0 = (bf16_t*)(ws + 16777216);
  bf16_t* Pp1 = (bf16_t*)(ws + 2 * 16777216);
  bf16_t* Pp2 = (bf16_t*)(ws + 3 * 16777216);
  bf16_t* Pp3 = (bf16_t*)(ws + 4 * 16777216);
  // mlp partials: h + bufA (dead after gemmgv); gv (bufB) untouched
  bf16_t* Pm0 = (bf16_t*)(ws);
  bf16_t* Pm1 = (bf16_t*)(ws + 16777216);
  bf16_t* Pm2 = (bf16_t*)(ws + 2 * 16777216);
  bf16_t* Pm3 = (bf16_t*)(ws + 3 * 16777216);

  // 1) h1 = rmsnorm(x)
  rmsnorm_k<<<BTn, 256, 0, stream>>>(x, n1w, h);
  // 2) qkv = h1 @ attn_w^T
  cvt_pad_k<<<(TD3 * Dn / 8 + 255) / 256, 256, 0, stream>>>(attn_w, wb, TD3, Dn, Dn, TD3 * Dn / 8);
  gemm256<0><<<(TD3 / 256) * (BTn / 256), 512, 0, stream>>>(h, wb, (void*)qkv, nullptr, BTn, TD3, Dn, TD3, BTn / 256);
  // 3) rope + split + V^T
  rope_k<<<dim3(Tn / 32, 32), 256, 0, stream>>>(qkv, Qb, Kb, Vt);
  // 4) attention -> y
  attn_k<<<dim3(16, 32), 256, 0, stream>>>(Qb, Kb, Vt, y);
  // 5) x1 = x + y @ proj_w^T  (split-K=4, full-chip; reduce fuses residual)
  cvt_pad_k<<<(Dn * Dn / 8 + 255) / 256, 256, 0, stream>>>(proj_w, wb, Dn, Dn, Dn, Dn * Dn / 8);
  gemm_sk<<<512, 512, 0, stream>>>(y, wb, Pp0, Pp1, Pp2, Pp3, Dn, Dn / 4, Dn);
  reduce4<<<BTn * Dn / 8 / 256, 256, 0, stream>>>(out, x, Pp0, Pp1, Pp2, Pp3);
  // 6) h2 = rmsnorm(x1)
  rmsnorm_k<<<BTn, 256, 0, stream>>>(out, n2w, h);
  // 7+8) gv = silu(h2 @ gate_w^T) * (h2 @ val_w^T)
  cvt_pad_k<<<(FGPn * Dn / 8 + 255) / 256, 256, 0, stream>>>(gate_w, wb, FGn, Dn, Dn, FGPn * Dn / 8);
  cvt_pad_k<<<(FGPn * Dn / 8 + 255) / 256, 256, 0, stream>>>(val_w, wbV, FGn, Dn, Dn, FGPn * Dn / 8);
  gemmgv<<<(FGPn / 128) * (BTn / 256), 512, 0, stream>>>(h, wb, wbV, gv, Dn, FGPn, BTn / 256);
  // 9) out = x1 + gv @ mlp_w^T  (split-K=4, K=5632)
  cvt_pad_k<<<(Dn * FGPn / 8 + 255) / 256, 256, 0, stream>>>(mlp_w, wb, Dn, FGn, FGPn, Dn * FGPn / 8);
  gemm_sk<<<512, 512, 0, stream>>>(gv, wb, Pm0, Pm1, Pm2, Pm3, FGPn, FGPn / 4, Dn);
  reduce4<<<BTn * Dn / 8 / 256, 256, 0, stream>>>(out, out, Pm0, Pm1, Pm2, Pm3);
}

// Round 12
// 823.906 us; speedup vs baseline: 1.1949x; 1.1949x over previous
//
#include <hip/hip_runtime.h>
#include <hip/hip_bf16.h>
#include <stdint.h>

typedef __bf16 bf16_t;
typedef __bf16 bf16x8 __attribute__((ext_vector_type(8)));
typedef float  f32x4  __attribute__((ext_vector_type(4)));

#define DEV __device__ __forceinline__

constexpr int   Bn = 2, Tn = 2048, Dn = 2048, Hn = 16, DHn = 128;
constexpr int   BTn = Bn * Tn;          // 4096 rows
constexpr int   TD3 = 3 * Dn;           // 6144
constexpr int   FGn = 5461, FGPn = 5504; // pad to 43*128 (688 blocks, %8==0)
constexpr float EPSf   = 1e-5f;
constexpr float LOG2E  = 1.4426950408889634f;
constexpr float ASCALE = 0.08838834764831845f;   // 1/sqrt(128)
constexpr float LN1E4  = 9.210340371976184f;     // ln(10000)

// async global->LDS, 16B per lane, wave-uniform LDS base
DEV void gld16(void* lds, const void* g) {
  __builtin_amdgcn_global_load_lds(
      (__attribute__((address_space(1))) void*)(void*)g,
      (__attribute__((address_space(3))) void*)lds, 16, 0, 0);
}

// inline-asm LDS read, ordered only by explicit s_waitcnt lgkmcnt(N)
DEV bf16x8 dsr128(const bf16_t* p) {
  bf16x8 r;
  asm volatile("ds_read_b128 %0, %1"
               : "=v"(r)
               : "v"((const __attribute__((address_space(3))) bf16_t*)p));
  return r;
}

// ---------------- RMSNorm (fp32 in -> bf16 out) ----------------
__global__ __launch_bounds__(256)
void rmsnorm_k(const float* __restrict__ x, const float* __restrict__ w,
               bf16_t* __restrict__ out) {
  const int row = blockIdx.x;
  const int tid = threadIdx.x;
  const float* xr = x + (size_t)row * Dn;
  float4 a = ((const float4*)xr)[tid * 2];
  float4 b = ((const float4*)xr)[tid * 2 + 1];
  float ss = a.x*a.x + a.y*a.y + a.z*a.z + a.w*a.w
           + b.x*b.x + b.y*b.y + b.z*b.z + b.w*b.w;
#pragma unroll
  for (int off = 32; off > 0; off >>= 1) ss += __shfl_xor(ss, off, 64);
  __shared__ float red[4];
  if ((tid & 63) == 0) red[tid >> 6] = ss;
  __syncthreads();
  float tot = red[0] + red[1] + red[2] + red[3];
  float rms = rsqrtf(tot * (1.0f / Dn) + EPSf);
  float4 wa = ((const float4*)w)[tid * 2];
  float4 wb = ((const float4*)w)[tid * 2 + 1];
  bf16x8 o;
  o[0] = (bf16_t)(a.x * rms * wa.x); o[1] = (bf16_t)(a.y * rms * wa.y);
  o[2] = (bf16_t)(a.z * rms * wa.z); o[3] = (bf16_t)(a.w * rms * wa.w);
  o[4] = (bf16_t)(b.x * rms * wb.x); o[5] = (bf16_t)(b.y * rms * wb.y);
  o[6] = (bf16_t)(b.z * rms * wb.z); o[7] = (bf16_t)(b.w * rms * wb.w);
  *(bf16x8*)&out[(size_t)row * Dn + tid * 8] = o;
}

// ---------------- fp32 -> bf16 convert with zero padding ----------------
__global__ __launch_bounds__(256)
void cvt_pad_k(const float* __restrict__ src, bf16_t* __restrict__ dst,
               int srcR, int srcC, int dstC, int n8) {
  int i = blockIdx.x * 256 + threadIdx.x;
  if (i >= n8) return;
  long base = (long)i * 8;
  int r = (int)(base / dstC);
  int c = (int)(base % dstC);
  bf16x8 o;
#pragma unroll
  for (int k = 0; k < 8; ++k) {
    int cc = c + k;
    float v = (r < srcR && cc < srcC) ? src[(size_t)r * srcC + cc] : 0.0f;
    o[k] = (bf16_t)v;
  }
  *(bf16x8*)&dst[base] = o;
}

// ---------------- reduce: out += P0 + P1 (split-K partials) ----------------
__global__ __launch_bounds__(256)
void reduce_k(float* __restrict__ out, const bf16_t* __restrict__ P0,
              const bf16_t* __restrict__ P1) {
  int i = blockIdx.x * 256 + threadIdx.x;     // 8 elems per thread
  bf16x8 p0 = *(const bf16x8*)&P0[(size_t)i * 8];
  bf16x8 p1 = *(const bf16x8*)&P1[(size_t)i * 8];
  float4 o0 = ((const float4*)out)[i * 2];
  float4 o1 = ((const float4*)out)[i * 2 + 1];
  o0.x += (float)p0[0] + (float)p1[0];
  o0.y += (float)p0[1] + (float)p1[1];
  o0.z += (float)p0[2] + (float)p1[2];
  o0.w += (float)p0[3] + (float)p1[3];
  o1.x += (float)p0[4] + (float)p1[4];
  o1.y += (float)p0[5] + (float)p1[5];
  o1.z += (float)p0[6] + (float)p1[6];
  o1.w += (float)p0[7] + (float)p1[7];
  ((float4*)out)[i * 2]     = o0;
  ((float4*)out)[i * 2 + 1] = o1;
}

// ---------------- GEMM 256x256 (R8/R10 4-slot version, best measured) -----
// m201-style phases on 4-slot BK=32 ring (128 KiB), counted vmcnt, depth-3
// prefetch. ~3490 cyc/block-step (measured invariant).
// EPI: 0 = bf16 store ; 1 = f32 out = resid + acc
template<int EPI>
__global__ __launch_bounds__(512, 2)
void gemm256(const bf16_t* __restrict__ A, const bf16_t* __restrict__ W,
             void* Cp, const void* Ep, int M, int N, int K, int ldc, int nby) {
  __shared__ __align__(128) bf16_t As[4][256 * 32];
  __shared__ __align__(128) bf16_t Bs[4][256 * 32];
  const int tid = threadIdx.x;
  const int lane = tid & 63, w = tid >> 6;
  const int wm = w >> 2, wn = w & 3;
  const int g = lane >> 4, q = lane & 15;

  const int nwg = gridDim.x;
  const int cpx = nwg >> 3;
  const int nid = (blockIdx.x & 7) * cpx + (blockIdx.x >> 3);
  const int bx = nid / nby, by = nid % nby;
  const int row0 = by * 256, col0 = bx * 256;

  f32x4 acc[8][4] = {};

  const bf16_t* Asrc[2];
  const bf16_t* Wsrc[2];
  int aoff[2];
#pragma unroll
  for (int i = 0; i < 2; ++i) {
    int line = i * 64 + (tid >> 3);
    int val  = (tid & 7) ^ (line & 7);
    int r    = (val >> 2) * 128 + line;
    int c    = val & 3;
    Asrc[i] = A + (size_t)(row0 + r) * K + c * 8;
    Wsrc[i] = W + (size_t)(col0 + r) * K + c * 8;
    aoff[i] = i * 8192 + w * 1024;
  }

  int offA[8], offB[4];
#pragma unroll
  for (int m = 0; m < 8; ++m) {
    int r = wm * 128 + m * 16 + q;
    offA[m] = (r & 127) * 128 + ((((r >> 7) * 4 + g) ^ (r & 7)) * 16);
  }
#pragma unroll
  for (int n = 0; n < 4; ++n) {
    int r = wn * 64 + n * 16 + q;
    offB[n] = (r & 127) * 128 + ((((r >> 7) * 4 + g) ^ (r & 7)) * 16);
  }

  const int NT = K >> 5;
  auto stage_half = [&](int T, int h) {
    const int slot = T & 3, kk = T * 32;
    gld16((char*)As[slot] + aoff[h], Asrc[h] + kk);
    gld16((char*)Bs[slot] + aoff[h], Wsrc[h] + kk);
  };
  auto stage_full = [&](int T) { stage_half(T, 0); stage_half(T, 1); };

  bf16x8 af[8], bfr[4];

  auto step = [&](int T, bool do_stage, int waitsel) {
    const char* as_ = (const char*)As[T & 3];
    const char* bs_ = (const char*)Bs[T & 3];
#pragma unroll
    for (int m = 0; m < 4; ++m) af[m] = dsr128((const bf16_t*)(as_ + offA[m]));
#pragma unroll
    for (int n = 0; n < 4; ++n) bfr[n] = dsr128((const bf16_t*)(bs_ + offB[n]));
    if (do_stage) stage_half(T + 3, 0);
    asm volatile("s_barrier" ::: "memory");
    asm volatile("s_waitcnt lgkmcnt(0)" ::: "memory");
    __builtin_amdgcn_sched_barrier(0);
    __builtin_amdgcn_s_setprio(1);
#pragma unroll
    for (int m = 0; m < 4; ++m)
#pragma unroll
      for (int n = 0; n < 4; ++n)
        acc[m][n] = __builtin_amdgcn_mfma_f32_16x16x32_bf16(af[m], bfr[n], acc[m][n], 0, 0, 0);
    __builtin_amdgcn_s_setprio(0);
    __builtin_amdgcn_sched_barrier(0);
    asm volatile("s_barrier" ::: "memory");
#pragma unroll
    for (int m = 4; m < 8; ++m) af[m] = dsr128((const bf16_t*)(as_ + offA[m]));
    if (do_stage) stage_half(T + 3, 1);
    if (waitsel == 2)      asm volatile("s_waitcnt vmcnt(8)" ::: "memory");
    else if (waitsel == 1) asm volatile("s_waitcnt vmcnt(4)" ::: "memory");
    else if (waitsel == 0) asm volatile("s_waitcnt vmcnt(0)" ::: "memory");
    asm volatile("s_barrier" ::: "memory");
    asm volatile("s_waitcnt lgkmcnt(0)" ::: "memory");
    __builtin_amdgcn_sched_barrier(0);
    __builtin_amdgcn_s_setprio(1);
#pragma unroll
    for (int m = 4; m < 8; ++m)
#pragma unroll
      for (int n = 0; n < 4; ++n)
        acc[m][n] = __builtin_amdgcn_mfma_f32_16x16x32_bf16(af[m], bfr[n], acc[m][n], 0, 0, 0);
    __builtin_amdgcn_s_setprio(0);
    __builtin_amdgcn_sched_barrier(0);
    asm volatile("s_barrier" ::: "memory");
  };

  stage_full(0); stage_full(1); stage_full(2);
  asm volatile("s_waitcnt vmcnt(8)" ::: "memory");
  asm volatile("s_barrier" ::: "memory");

  for (int T = 0; T < NT - 3; ++T) step(T, true, 2);
  step(NT - 3, false, 1);
  step(NT - 2, false, 0);
  step(NT - 1, false, 3);

#pragma unroll
  for (int m = 0; m < 8; ++m) {
#pragma unroll
    for (int n = 0; n < 4; ++n) {
#pragma unroll
      for (int j = 0; j < 4; ++j) {
        int r = row0 + wm * 128 + m * 16 + g * 4 + j;
        int c = col0 + wn * 64 + n * 16 + q;
        size_t idx = (size_t)r * ldc + c;
        float v = acc[m][n][j];
        if (EPI == 0) ((bf16_t*)Cp)[idx] = (bf16_t)v;
        else          ((float*)Cp)[idx] = ((const float*)Ep)[idx] + v;
      }
    }
  }
}

// -------- split-K=2 GEMM for mlp, BK=64 experiment ------------------------
// 2-slot x (A 32KB + B 32KB) = 128KB, 1/CU, 256 blocks full-chip.
// One barrier + one vmcnt + two lgkm per 64-K (vs 2x that at BK=32):
// bets that the ~2000cyc/step residual is per-step sync overhead.
// Slot safety (2-slot): stage(T+1) writes slot (T+1)&1, whose step-(T-1)
// readers all retired at their lgkmcnt(0) BEFORE the end-of-step-(T-1)
// barrier; stage(T+1) is issued after that barrier. Publish: vmcnt(0) on
// this step's 8 gld16s, issued ~2000cyc before the wait (latency covered).
__global__ __launch_bounds__(512, 2)
void gemm_sk(const bf16_t* __restrict__ A, const bf16_t* __restrict__ W,
             bf16_t* __restrict__ P0, bf16_t* __restrict__ P1,
             int ldk, int klen, int ldc) {
  __shared__ __align__(128) bf16_t As[2][256 * 64];   // 2 x 32KB
  __shared__ __align__(128) bf16_t Bs[2][256 * 64];   // 2 x 32KB
  const int tid = threadIdx.x;
  const int lane = tid & 63, w = tid >> 6;
  const int wm = w >> 2, wn = w & 3;
  const int g = lane >> 4, q = lane & 15;

  const int nid = (blockIdx.x & 7) * 32 + (blockIdx.x >> 3);  // 256 blocks
  const int s   = nid >> 7;              // K-half
  const int rem = nid & 127;
  const int bx = rem >> 4, by = rem & 15;
  const int row0 = by * 256, col0 = bx * 256;
  const int kofs = s * klen;
  bf16_t* P = s ? P1 : P0;

  f32x4 acc[8][4] = {};

  // staging sources: round i covers rows [64i,64i+64); LDS layout:
  // chunk16 (r, c) stored at byte r*128 + ((c ^ (r&7))*16), c in [0,8)
  const bf16_t* Asrc[4];
  const bf16_t* Wsrc[4];
  int aoff[4];
#pragma unroll
  for (int i = 0; i < 4; ++i) {
    int ci = i * 512 + tid;
    int r  = ci >> 3;
    int cs = (ci & 7) ^ (r & 7);
    Asrc[i] = A + (size_t)(row0 + r) * ldk + kofs + cs * 8;
    Wsrc[i] = W + (size_t)(col0 + r) * ldk + kofs + cs * 8;
    aoff[i] = i * 8192 + w * 1024;
  }

  // fragment LDS byte offsets per k-half kk: chunk = kk*4+g
  int offA[2][8], offB[2][4];
#pragma unroll
  for (int kk = 0; kk < 2; ++kk) {
#pragma unroll
    for (int m = 0; m < 8; ++m) {
      int r = wm * 128 + m * 16 + q;
      offA[kk][m] = r * 128 + (((kk * 4 + g) ^ (r & 7)) * 16);
    }
#pragma unroll
    for (int n = 0; n < 4; ++n) {
      int r = wn * 64 + n * 16 + q;
      offB[kk][n] = r * 128 + (((kk * 4 + g) ^ (r & 7)) * 16);
    }
  }

  const int NT = klen >> 6;              // 43 for klen=2752
  auto stage = [&](int T, int h) {       // h: 0 = rounds 0,1 ; 1 = rounds 2,3
    const int slot = T & 1;
    const size_t kk = (size_t)T * 64;
#pragma unroll
    for (int i = 0; i < 2; ++i) {
      int rd = h * 2 + i;
      gld16((char*)As[slot] + aoff[rd], Asrc[rd] + kk);
      gld16((char*)Bs[slot] + aoff[rd], Wsrc[rd] + kk);
    }
  };

  bf16x8 af[8], bfr[4];

  auto half = [&](const char* as_, const char* bs_, int kk) {
#pragma unroll
    for (int m = 0; m < 8; ++m) af[m] = dsr128((const bf16_t*)(as_ + offA[kk][m]));
#pragma unroll
    for (int n = 0; n < 4; ++n) bfr[n] = dsr128((const bf16_t*)(bs_ + offB[kk][n]));
  };
  auto mfmas = [&]() {
    asm volatile("s_waitcnt lgkmcnt(0)" ::: "memory");
    __builtin_amdgcn_sched_barrier(0);
    __builtin_amdgcn_s_setprio(1);
#pragma unroll
    for (int m = 0; m < 8; ++m)
#pragma unroll
      for (int n = 0; n < 4; ++n)
        acc[m][n] = __builtin_amdgcn_mfma_f32_16x16x32_bf16(af[m], bfr[n], acc[m][n], 0, 0, 0);
    __builtin_amdgcn_s_setprio(0);
    __builtin_amdgcn_sched_barrier(0);
  };

  // prologue: slot 0 staged and published
  stage(0, 0); stage(0, 1);
  asm volatile("s_waitcnt vmcnt(0)" ::: "memory");
  asm volatile("s_barrier" ::: "memory");

  for (int T = 0; T < NT; ++T) {
    const char* as_ = (const char*)As[T & 1];
    const char* bs_ = (const char*)Bs[T & 1];
    const bool st = (T + 1 < NT);
    half(as_, bs_, 0);
    if (st) stage(T + 1, 0);
    mfmas();
    half(as_, bs_, 1);
    if (st) stage(T + 1, 1);
    mfmas();
    if (st) asm volatile("s_waitcnt vmcnt(0)" ::: "memory");  // slot T+1 landed
    asm volatile("s_barrier" ::: "memory");
  }

#pragma unroll
  for (int m = 0; m < 8; ++m)
#pragma unroll
    for (int n = 0; n < 4; ++n)
#pragma unroll
      for (int j = 0; j < 4; ++j) {
        int r = row0 + wm * 128 + m * 16 + g * 4 + j;
        int c = col0 + wn * 64 + n * 16 + q;
        P[(size_t)r * ldc + c] = (bf16_t)acc[m][n][j];
      }
}

// ------- fused gate+val dual GEMM: Out = silu(A Wg^T) * (A Wv^T) ---------
// (R10 exact: 256Mx128N, 2-slot 64KB A+G+V, measured ~253us)
__global__ __launch_bounds__(512, 2)
void gemmgv(const bf16_t* __restrict__ A, const bf16_t* __restrict__ Wg,
            const bf16_t* __restrict__ Wv, bf16_t* __restrict__ Out,
            int M, int N, int K, int ldc, int nby) {
  __shared__ __align__(128) bf16_t As[2][256 * 32];   // 32KB
  __shared__ __align__(128) bf16_t Gs[2][128 * 32];   // 16KB
  __shared__ __align__(128) bf16_t Vs[2][128 * 32];   // 16KB
  const int tid = threadIdx.x;
  const int lane = tid & 63, w = tid >> 6;
  const int wm = w >> 2, wn = w & 3;
  const int g = lane >> 4, q = lane & 15;

  const int nwg = gridDim.x;                 // 688, % 8 == 0
  const int cpx = nwg >> 3;
  const int nid = (blockIdx.x & 7) * cpx + (blockIdx.x >> 3);
  const int bx = nid / nby, by = nid % nby;
  const int row0 = by * 256, col0 = bx * 128;

  f32x4 accg[8][2] = {}, accv[8][2] = {};

  const bf16_t* Asrc[2];
  int aoff[2];
#pragma unroll
  for (int i = 0; i < 2; ++i) {
    int line = i * 64 + (tid >> 3);
    int val  = (tid & 7) ^ (line & 7);
    int r    = (val >> 2) * 128 + line;
    int c    = val & 3;
    Asrc[i] = A + (size_t)(row0 + r) * K + c * 8;
    aoff[i] = i * 8192 + w * 1024;
  }
  const int brow = tid >> 2;
  const int bchk = (tid & 3) ^ ((brow >> 1) & 3);
  const bf16_t* Gsrc = Wg + (size_t)(col0 + brow) * K + bchk * 8;
  const bf16_t* Vsrc = Wv + (size_t)(col0 + brow) * K + bchk * 8;
  const int boff = tid * 16;

  int offA[8], offB[2];
#pragma unroll
  for (int m = 0; m < 8; ++m) {
    int r = wm * 128 + m * 16 + q;
    offA[m] = (r & 127) * 128 + ((((r >> 7) * 4 + g) ^ (r & 7)) * 16);
  }
#pragma unroll
  for (int n = 0; n < 2; ++n) {
    int r = wn * 32 + n * 16 + q;
    offB[n] = r * 64 + ((g ^ ((r >> 1) & 3)) * 16);
  }

  const int NT = K >> 5;
  auto stage = [&](int T) {
    const int slot = T & 1, kk = T * 32;
    gld16((char*)As[slot] + aoff[0], Asrc[0] + kk);
    gld16((char*)As[slot] + aoff[1], Asrc[1] + kk);
    gld16((char*)Gs[slot] + boff, Gsrc + kk);
    gld16((char*)Vs[slot] + boff, Vsrc + kk);
  };

  stage(0);
  for (int T = 0; T < NT; ++T) {
    __syncthreads();
    if (T + 1 < NT) stage(T + 1);
    const char* as_ = (const char*)As[T & 1];
    const char* gs_ = (const char*)Gs[T & 1];
    const char* vs_ = (const char*)Vs[T & 1];
    bf16x8 af[8], bg[2], bv[2];
#pragma unroll
    for (int m = 0; m < 8; ++m) af[m] = *(const bf16x8*)(as_ + offA[m]);
#pragma unroll
    for (int n = 0; n < 2; ++n) {
      bg[n] = *(const bf16x8*)(gs_ + offB[n]);
      bv[n] = *(const bf16x8*)(vs_ + offB[n]);
    }
    __builtin_amdgcn_s_setprio(1);
#pragma unroll
    for (int m = 0; m < 8; ++m)
#pragma unroll
      for (int n = 0; n < 2; ++n) {
        accg[m][n] = __builtin_amdgcn_mfma_f32_16x16x32_bf16(af[m], bg[n], accg[m][n], 0, 0, 0);
        accv[m][n] = __builtin_amdgcn_mfma_f32_16x16x32_bf16(af[m], bv[n], accv[m][n], 0, 0, 0);
      }
    __builtin_amdgcn_s_setprio(0);
    __syncthreads();
  }

#pragma unroll
  for (int m = 0; m < 8; ++m) {
#pragma unroll
    for (int n = 0; n < 2; ++n) {
#pragma unroll
      for (int j = 0; j < 4; ++j) {
        int r = row0 + wm * 128 + m * 16 + g * 4 + j;
        int c = col0 + wn * 32 + n * 16 + q;
        float gt = accg[m][n][j];
        float sg = gt / (1.0f + __expf(-gt));
        Out[(size_t)r * ldc + c] = (bf16_t)(sg * accv[m][n][j]);
      }
    }
  }
}

// ---------------- RoPE + split + V transpose ----------------
__global__ __launch_bounds__(256)
void rope_k(const bf16_t* __restrict__ qkv, bf16_t* __restrict__ Qb,
            bf16_t* __restrict__ Kb, bf16_t* __restrict__ Vt) {
  const int t0 = blockIdx.x * 32;
  const int bh = blockIdx.y;
  const int b = bh >> 4, hh = bh & 15;
  __shared__ bf16_t Vl[32][132];

#pragma unroll
  for (int it = 0; it < 2; ++it) {
    int task = threadIdx.x + it * 256;
    int tt = task >> 4, ck = task & 15, d0 = ck * 8;
    int tg = t0 + tt;
    const bf16_t* srow = qkv + (size_t)(b * Tn + tg) * TD3 + hh * DHn + d0;
    bf16x8 qv = *(const bf16x8*)(srow);
    bf16x8 kv = *(const bf16x8*)(srow + Dn);
    bf16x8 vv = *(const bf16x8*)(srow + 2 * Dn);
    bf16x8 qo, ko;
#pragma unroll
    for (int p = 0; p < 4; ++p) {
      int jj = (d0 >> 1) + p;
      float fr = __expf(-((float)(2 * jj) / 128.0f) * LN1E4);
      float ang = (float)tg * fr;
      float cs = cosf(ang), sn = sinf(ang);
      float qe = (float)qv[2 * p], qod = (float)qv[2 * p + 1];
      float ke = (float)kv[2 * p], kod = (float)kv[2 * p + 1];
      qo[2 * p]     = (bf16_t)((qe * cs - qod * sn) * ASCALE);
      qo[2 * p + 1] = (bf16_t)((qod * cs + qe * sn) * ASCALE);
      ko[2 * p]     = (bf16_t)(ke * cs - kod * sn);
      ko[2 * p + 1] = (bf16_t)(kod * cs + ke * sn);
    }
    *(bf16x8*)&Qb[((size_t)bh * Tn + tg) * DHn + d0] = qo;
    *(bf16x8*)&Kb[((size_t)bh * Tn + tg) * DHn + d0] = ko;
    *(bf16x8*)&Vl[tt][d0] = vv;
  }
  __syncthreads();
#pragma unroll
  for (int it = 0; it < 2; ++it) {
    int task = threadIdx.x + it * 256;
    int dd = task >> 2, tc = (task & 3) * 8;
    bf16x8 ov;
#pragma unroll
    for (int i = 0; i < 8; ++i) ov[i] = Vl[tc + i][dd];
    *(bf16x8*)&Vt[((size_t)bh * DHn + dd) * Tn + t0 + tc] = ov;
  }
}

// ---------------- causal flash attention, paired q-tiles ----------------
__global__ __launch_bounds__(256, 2)
void attn_k(const bf16_t* __restrict__ Qb, const bf16_t* __restrict__ Kb,
            const bf16_t* __restrict__ Vt, bf16_t* __restrict__ Y) {
  const int orig = blockIdx.x + 16 * blockIdx.y;   // 512 blocks total
  const int nid  = (orig & 7) * 64 + (orig >> 3);  // XCD-chunked, bijective
  const int pi = nid & 15;
  const int bh = nid >> 4;
  const int b = bh >> 4, hh = bh & 15;
  const int tid = threadIdx.x, lane = tid & 63, w = tid >> 6;
  const int g = lane >> 4, q = lane & 15;
  const int iA = pi, iB = 31 - pi;
  const int kmax = iB;

  __shared__ bf16_t Ks[2][64 * 128];
  __shared__ bf16_t Vs[2][128 * 64];
  __shared__ bf16_t Ps[4][16 * 72];

  bf16x8 aqA[4], aqB[4];
  {
    const bf16_t* QrA = Qb + ((size_t)bh * Tn + iA * 64 + w * 16 + q) * DHn;
    const bf16_t* QrB = Qb + ((size_t)bh * Tn + iB * 64 + w * 16 + q) * DHn;
#pragma unroll
    for (int s = 0; s < 4; ++s) {
      aqA[s] = *(const bf16x8*)(QrA + s * 32 + g * 8);
      aqB[s] = *(const bf16x8*)(QrB + s * 32 + g * 8);
    }
  }

  f32x4 oA[8] = {}, oB[8] = {};
  float mA[4], lA[4], mB[4], lB[4];
#pragma unroll
  for (int j = 0; j < 4; ++j) {
    mA[j] = -__builtin_inff(); lA[j] = 0.0f;
    mB[j] = -__builtin_inff(); lB[j] = 0.0f;
  }

  auto stage = [&](int buf, int kt) {
    const int k0 = kt * 64;
#pragma unroll
    for (int l = 0; l < 4; ++l) {
      int ci = (w * 4 + l) * 64 + lane;
      int kr = ci >> 4, kc = (ci & 15) ^ (kr & 7);
      gld16((char*)Ks[buf] + (w * 4 + l) * 1024,
            Kb + ((size_t)bh * Tn + k0 + kr) * DHn + kc * 8);
      int vr = ci >> 3, vc = (ci & 7) ^ (vr & 7);
      gld16((char*)Vs[buf] + (w * 4 + l) * 1024,
            Vt + ((size_t)bh * DHn + vr) * Tn + k0 + vc * 8);
    }
  };

  stage(0, 0);

  for (int kt = 0; kt <= kmax; ++kt) {
    __syncthreads();
    if (kt < kmax) stage((kt + 1) & 1, kt + 1);
    const bf16_t* ks = Ks[kt & 1];
    const bf16_t* vs = Vs[kt & 1];
    const bool actA = (kt <= iA);
    const int k0 = kt * 64;

    f32x4 saA[4] = {}, saB[4] = {};
    __builtin_amdgcn_s_setprio(1);
    if (actA) {
#pragma unroll
      for (int s = 0; s < 4; ++s) {
#pragma unroll
        for (int n = 0; n < 4; ++n) {
          bf16x8 bk = *(const bf16x8*)&ks[(n * 16 + q) * 128 + (((s * 4 + g) ^ (q & 7)) * 8)];
          saA[n] = __builtin_amdgcn_mfma_f32_16x16x32_bf16(aqA[s], bk, saA[n], 0, 0, 0);
          saB[n] = __builtin_amdgcn_mfma_f32_16x16x32_bf16(aqB[s], bk, saB[n], 0, 0, 0);
        }
      }
    } else {
#pragma unroll
      for (int s = 0; s < 4; ++s) {
#pragma unroll
        for (int n = 0; n < 4; ++n) {
          bf16x8 bk = *(const bf16x8*)&ks[(n * 16 + q) * 128 + (((s * 4 + g) ^ (q & 7)) * 8)];
          saB[n] = __builtin_amdgcn_mfma_f32_16x16x32_bf16(aqB[s], bk, saB[n], 0, 0, 0);
        }
      }
    }
    __builtin_amdgcn_s_setprio(0);

    bf16x8 paA[2], paB[2];
    auto softmax_p = [&](f32x4* sa, float* mst, float* lst, int itile,
                         bf16x8* pa, int qrow) {
      if (kt == itile) {
#pragma unroll
        for (int n = 0; n < 4; ++n)
#pragma unroll
          for (int j = 0; j < 4; ++j) {
            int kc = k0 + n * 16 + q;
            int qr = qrow + g * 4 + j;
            if (kc > qr) sa[n][j] = -1e30f;
          }
      }
      float mx[4];
#pragma unroll
      for (int j = 0; j < 4; ++j) {
        mx[j] = fmaxf(fmaxf(sa[0][j], sa[1][j]), fmaxf(sa[2][j], sa[3][j]));
#pragma unroll
        for (int off = 1; off < 16; off <<= 1)
          mx[j] = fmaxf(mx[j], __shfl_xor(mx[j], off, 16));
      }
      float ps[4][4], rsum[4];
#pragma unroll
      for (int j = 0; j < 4; ++j) rsum[j] = 0.0f;
      float mnew[4], corr[4];
#pragma unroll
      for (int j = 0; j < 4; ++j) {
        mnew[j] = fmaxf(mst[j], mx[j]);
        corr[j] = exp2f((mst[j] - mnew[j]) * LOG2E);
      }
#pragma unroll
      for (int n = 0; n < 4; ++n)
#pragma unroll
        for (int j = 0; j < 4; ++j) {
          ps[n][j] = exp2f((sa[n][j] - mnew[j]) * LOG2E);
          rsum[j] += ps[n][j];
        }
#pragma unroll
      for (int j = 0; j < 4; ++j) {
#pragma unroll
        for (int off = 1; off < 16; off <<= 1)
          rsum[j] += __shfl_xor(rsum[j], off, 16);
        lst[j] = lst[j] * corr[j] + rsum[j];
        mst[j] = mnew[j];
      }
#pragma unroll
      for (int n = 0; n < 4; ++n)
#pragma unroll
        for (int j = 0; j < 4; ++j)
          Ps[w][(g * 4 + j) * 72 + n * 16 + q] = (bf16_t)ps[n][j];
#pragma unroll
      for (int s2 = 0; s2 < 2; ++s2)
        pa[s2] = *(const bf16x8*)&Ps[w][q * 72 + s2 * 32 + g * 8];
      return corr;
    };

    float cA[4], cB[4];
    if (actA) {
      auto c = softmax_p(saA, mA, lA, iA, paA, iA * 64 + w * 16);
#pragma unroll
      for (int j = 0; j < 4; ++j) cA[j] = c[j];
#pragma unroll
      for (int n8 = 0; n8 < 8; ++n8)
#pragma unroll
        for (int j = 0; j < 4; ++j) oA[n8][j] *= cA[j];
    }
    {
      auto c = softmax_p(saB, mB, lB, iB, paB, iB * 64 + w * 16);
#pragma unroll
      for (int j = 0; j < 4; ++j) cB[j] = c[j];
#pragma unroll
      for (int n8 = 0; n8 < 8; ++n8)
#pragma unroll
        for (int j = 0; j < 4; ++j) oB[n8][j] *= cB[j];
    }

    __builtin_amdgcn_s_setprio(1);
    if (actA) {
#pragma unroll
      for (int s2 = 0; s2 < 2; ++s2)
#pragma unroll
        for (int n8 = 0; n8 < 8; ++n8) {
          bf16x8 bv = *(const bf16x8*)&vs[(n8 * 16 + q) * 64 + (((s2 * 4 + g) ^ (q & 7)) * 8)];
          oA[n8] = __builtin_amdgcn_mfma_f32_16x16x32_bf16(paA[s2], bv, oA[n8], 0, 0, 0);
          oB[n8] = __builtin_amdgcn_mfma_f32_16x16x32_bf16(paB[s2], bv, oB[n8], 0, 0, 0);
        }
    } else {
#pragma unroll
      for (int s2 = 0; s2 < 2; ++s2)
#pragma unroll
        for (int n8 = 0; n8 < 8; ++n8) {
          bf16x8 bv = *(const bf16x8*)&vs[(n8 * 16 + q) * 64 + (((s2 * 4 + g) ^ (q & 7)) * 8)];
          oB[n8] = __builtin_amdgcn_mfma_f32_16x16x32_bf16(paB[s2], bv, oB[n8], 0, 0, 0);
        }
    }
    __builtin_amdgcn_s_setprio(0);
  }

#pragma unroll
  for (int n8 = 0; n8 < 8; ++n8)
#pragma unroll
    for (int j = 0; j < 4; ++j) {
      int trA = iA * 64 + w * 16 + g * 4 + j;
      int trB = iB * 64 + w * 16 + g * 4 + j;
      Y[(size_t)(b * Tn + trA) * Dn + hh * DHn + n8 * 16 + q] =
          (bf16_t)(oA[n8][j] / lA[j]);
      Y[(size_t)(b * Tn + trB) * Dn + hh * DHn + n8 * 16 + q] =
          (bf16_t)(oB[n8][j] / lB[j]);
    }
}

// ---------------- launcher ----------------
extern "C" void kernel_launch(void* const* d_in, const int* in_sizes, int n_in,
                              void* d_out, int out_size, void* d_ws, size_t ws_size,
                              hipStream_t stream) {
  const float* x      = (const float*)d_in[0];
  const float* n1w    = (const float*)d_in[1];
  const float* n2w    = (const float*)d_in[2];
  const float* attn_w = (const float*)d_in[3];
  const float* proj_w = (const float*)d_in[4];
  const float* gate_w = (const float*)d_in[5];
  const float* val_w  = (const float*)d_in[6];
  const float* mlp_w  = (const float*)d_in[7];

  char* ws = (char*)d_ws;
  bf16_t* h    = (bf16_t*)(ws);                  // 16.78MB
  bf16_t* bufA = (bf16_t*)(ws + 16777216);       // 50.3MB
  bf16_t* bufB = (bf16_t*)(ws + 67108864);       // 50.3MB
  bf16_t* wb   = (bf16_t*)(ws + 117440512);      // 25.2MB

  bf16_t* qkv  = bufA;
  bf16_t* wbV  = bufA;   // val weights (bufA free after rope)
  bf16_t* Qb   = bufB;
  bf16_t* Kb   = Qb + (size_t)32 * Tn * DHn;
  bf16_t* Vt   = Kb + (size_t)32 * Tn * DHn;
  bf16_t* gv   = bufB;   // gate*val output (bufB free after attn)
  bf16_t* y    = h;
  bf16_t* P0   = h;      // split-K partial 0 (h free after gemmgv)
  bf16_t* P1   = bufA;   // split-K partial 1 (bufA free after gemmgv)
  float*  out  = (float*)d_out;

  // 1) h1 = rmsnorm(x)
  rmsnorm_k<<<BTn, 256, 0, stream>>>(x, n1w, h);
  // 2) qkv = h1 @ attn_w^T
  cvt_pad_k<<<(TD3 * Dn / 8 + 255) / 256, 256, 0, stream>>>(attn_w, wb, TD3, Dn, Dn, TD3 * Dn / 8);
  gemm256<0><<<(TD3 / 256) * (BTn / 256), 512, 0, stream>>>(h, wb, (void*)qkv, nullptr, BTn, TD3, Dn, TD3, BTn / 256);
  // 3) rope + split + V^T
  rope_k<<<dim3(Tn / 32, 32), 256, 0, stream>>>(qkv, Qb, Kb, Vt);
  // 4) attention -> y
  attn_k<<<dim3(16, 32), 256, 0, stream>>>(Qb, Kb, Vt, y);
  // 5) x1 = x + y @ proj_w^T  (fp32, into d_out)
  cvt_pad_k<<<(Dn * Dn / 8 + 255) / 256, 256, 0, stream>>>(proj_w, wb, Dn, Dn, Dn, Dn * Dn / 8);
  gemm256<1><<<(Dn / 256) * (BTn / 256), 512, 0, stream>>>(y, wb, (void*)out, (const void*)x, BTn, Dn, Dn, Dn, BTn / 256);
  // 6) h2 = rmsnorm(x1)
  rmsnorm_k<<<BTn, 256, 0, stream>>>(out, n2w, h);
  // 7+8) gv = silu(h2 @ gate_w^T) * (h2 @ val_w^T)  -- fused dual GEMM
  cvt_pad_k<<<(FGPn * Dn / 8 + 255) / 256, 256, 0, stream>>>(gate_w, wb, FGn, Dn, Dn, FGPn * Dn / 8);
  cvt_pad_k<<<(FGPn * Dn / 8 + 255) / 256, 256, 0, stream>>>(val_w, wbV, FGn, Dn, Dn, FGPn * Dn / 8);
  gemmgv<<<(FGPn / 128) * (BTn / 256), 512, 0, stream>>>(h, wb, wbV, gv, BTn, FGPn, Dn, FGPn, BTn / 256);
  // 9) mlp split-K=2 (BK=64): P0/P1 = gv[:, s*2752:] @ mlp_w[:, s*2752:]^T
  cvt_pad_k<<<(Dn * FGPn / 8 + 255) / 256, 256, 0, stream>>>(mlp_w, wb, Dn, FGn, FGPn, Dn * FGPn / 8);
  gemm_sk<<<256, 512, 0, stream>>>(gv, wb, P0, P1, FGPn, FGPn / 2, Dn);
  // 10) out += P0 + P1
  reduce_k<<<BTn * Dn / 8 / 256, 256, 0, stream>>>(out, P0, P1);
}

// Round 13
// 814.666 us; speedup vs baseline: 1.2085x; 1.0113x over previous
//
#include <hip/hip_runtime.h>
#include <hip/hip_bf16.h>
#include <stdint.h>

typedef __bf16 bf16_t;
typedef __bf16 bf16x8 __attribute__((ext_vector_type(8)));
typedef float  f32x4  __attribute__((ext_vector_type(4)));

#define DEV __device__ __forceinline__

constexpr int   Bn = 2, Tn = 2048, Dn = 2048, Hn = 16, DHn = 128;
constexpr int   BTn = Bn * Tn;          // 4096 rows
constexpr int   TD3 = 3 * Dn;           // 6144
constexpr int   FGn = 5461, FGPn = 5504; // pad to 43*128 (688 blocks, %8==0)
constexpr float EPSf   = 1e-5f;
constexpr float LOG2E  = 1.4426950408889634f;
constexpr float ASCALE = 0.08838834764831845f;   // 1/sqrt(128)
constexpr float LN1E4  = 9.210340371976184f;     // ln(10000)

// async global->LDS, 16B per lane, wave-uniform LDS base
DEV void gld16(void* lds, const void* g) {
  __builtin_amdgcn_global_load_lds(
      (__attribute__((address_space(1))) void*)(void*)g,
      (__attribute__((address_space(3))) void*)lds, 16, 0, 0);
}

// inline-asm LDS read, ordered only by explicit s_waitcnt lgkmcnt(N)
DEV bf16x8 dsr128(const bf16_t* p) {
  bf16x8 r;
  asm volatile("ds_read_b128 %0, %1"
               : "=v"(r)
               : "v"((const __attribute__((address_space(3))) bf16_t*)p));
  return r;
}

// ---------------- RMSNorm (fp32 in -> bf16 out) ----------------
__global__ __launch_bounds__(256)
void rmsnorm_k(const float* __restrict__ x, const float* __restrict__ w,
               bf16_t* __restrict__ out) {
  const int row = blockIdx.x;
  const int tid = threadIdx.x;
  const float* xr = x + (size_t)row * Dn;
  float4 a = ((const float4*)xr)[tid * 2];
  float4 b = ((const float4*)xr)[tid * 2 + 1];
  float ss = a.x*a.x + a.y*a.y + a.z*a.z + a.w*a.w
           + b.x*b.x + b.y*b.y + b.z*b.z + b.w*b.w;
#pragma unroll
  for (int off = 32; off > 0; off >>= 1) ss += __shfl_xor(ss, off, 64);
  __shared__ float red[4];
  if ((tid & 63) == 0) red[tid >> 6] = ss;
  __syncthreads();
  float tot = red[0] + red[1] + red[2] + red[3];
  float rms = rsqrtf(tot * (1.0f / Dn) + EPSf);
  float4 wa = ((const float4*)w)[tid * 2];
  float4 wb = ((const float4*)w)[tid * 2 + 1];
  bf16x8 o;
  o[0] = (bf16_t)(a.x * rms * wa.x); o[1] = (bf16_t)(a.y * rms * wa.y);
  o[2] = (bf16_t)(a.z * rms * wa.z); o[3] = (bf16_t)(a.w * rms * wa.w);
  o[4] = (bf16_t)(b.x * rms * wb.x); o[5] = (bf16_t)(b.y * rms * wb.y);
  o[6] = (bf16_t)(b.z * rms * wb.z); o[7] = (bf16_t)(b.w * rms * wb.w);
  *(bf16x8*)&out[(size_t)row * Dn + tid * 8] = o;
}

// ---------------- fp32 -> bf16 convert with zero padding ----------------
__global__ __launch_bounds__(256)
void cvt_pad_k(const float* __restrict__ src, bf16_t* __restrict__ dst,
               int srcR, int srcC, int dstC, int n8) {
  int i = blockIdx.x * 256 + threadIdx.x;
  if (i >= n8) return;
  long base = (long)i * 8;
  int r = (int)(base / dstC);
  int c = (int)(base % dstC);
  bf16x8 o;
#pragma unroll
  for (int k = 0; k < 8; ++k) {
    int cc = c + k;
    float v = (r < srcR && cc < srcC) ? src[(size_t)r * srcC + cc] : 0.0f;
    o[k] = (bf16_t)v;
  }
  *(bf16x8*)&dst[base] = o;
}

// ---------------- reduce: out += P0 + P1 (split-K partials) ----------------
__global__ __launch_bounds__(256)
void reduce_k(float* __restrict__ out, const bf16_t* __restrict__ P0,
              const bf16_t* __restrict__ P1) {
  int i = blockIdx.x * 256 + threadIdx.x;     // 8 elems per thread
  bf16x8 p0 = *(const bf16x8*)&P0[(size_t)i * 8];
  bf16x8 p1 = *(const bf16x8*)&P1[(size_t)i * 8];
  float4 o0 = ((const float4*)out)[i * 2];
  float4 o1 = ((const float4*)out)[i * 2 + 1];
  o0.x += (float)p0[0] + (float)p1[0];
  o0.y += (float)p0[1] + (float)p1[1];
  o0.z += (float)p0[2] + (float)p1[2];
  o0.w += (float)p0[3] + (float)p1[3];
  o1.x += (float)p0[4] + (float)p1[4];
  o1.y += (float)p0[5] + (float)p1[5];
  o1.z += (float)p0[6] + (float)p1[6];
  o1.w += (float)p0[7] + (float)p1[7];
  ((float4*)out)[i * 2]     = o0;
  ((float4*)out)[i * 2 + 1] = o1;
}

// ---------------- GEMM 256x256, 4-slot ring, ONE barrier per K-step ------
// Step: {12 ds_read (all frags of T) ; stage(T+3) ; lgkmcnt(0) ; 32 MFMA ;
// counted vmcnt ; s_barrier}. Waves drift within the step: LDS-read storm
// of trailing waves overlaps MFMA of leading waves (phase-serialization was
// the 3490cyc/step wall in the 2-/4-barrier variants; R5's 1-barrier test
// was invalid - its lgkm waits were no-ops).
// Slot safety: reads of slot (T-1)&3 retire at step T-1's lgkmcnt(0) before
// its barrier; stage(T+3) (same slot) is issued after that barrier. Publish:
// vmcnt(8) leaves T+2/T+3 in flight, guarantees T+1's 4 gld retired.
// EPI: 0 = bf16 store ; 1 = f32 out = resid + acc
template<int EPI>
__global__ __launch_bounds__(512, 2)
void gemm256(const bf16_t* __restrict__ A, const bf16_t* __restrict__ W,
             void* Cp, const void* Ep, int M, int N, int K, int ldc, int nby) {
  __shared__ __align__(128) bf16_t As[4][256 * 32];
  __shared__ __align__(128) bf16_t Bs[4][256 * 32];
  const int tid = threadIdx.x;
  const int lane = tid & 63, w = tid >> 6;
  const int wm = w >> 2, wn = w & 3;
  const int g = lane >> 4, q = lane & 15;

  const int nwg = gridDim.x;
  const int cpx = nwg >> 3;
  const int nid = (blockIdx.x & 7) * cpx + (blockIdx.x >> 3);
  const int bx = nid / nby, by = nid % nby;
  const int row0 = by * 256, col0 = bx * 256;

  f32x4 acc[8][4] = {};

  const bf16_t* Asrc[2];
  const bf16_t* Wsrc[2];
  int aoff[2];
#pragma unroll
  for (int i = 0; i < 2; ++i) {
    int line = i * 64 + (tid >> 3);
    int val  = (tid & 7) ^ (line & 7);
    int r    = (val >> 2) * 128 + line;
    int c    = val & 3;
    Asrc[i] = A + (size_t)(row0 + r) * K + c * 8;
    Wsrc[i] = W + (size_t)(col0 + r) * K + c * 8;
    aoff[i] = i * 8192 + w * 1024;
  }

  int offA[8], offB[4];
#pragma unroll
  for (int m = 0; m < 8; ++m) {
    int r = wm * 128 + m * 16 + q;
    offA[m] = (r & 127) * 128 + ((((r >> 7) * 4 + g) ^ (r & 7)) * 16);
  }
#pragma unroll
  for (int n = 0; n < 4; ++n) {
    int r = wn * 64 + n * 16 + q;
    offB[n] = (r & 127) * 128 + ((((r >> 7) * 4 + g) ^ (r & 7)) * 16);
  }

  const int NT = K >> 5;
  auto stage_full = [&](int T) {           // 4 gld16
    const int slot = T & 3, kk = T * 32;
#pragma unroll
    for (int i = 0; i < 2; ++i) {
      gld16((char*)As[slot] + aoff[i], Asrc[i] + kk);
      gld16((char*)Bs[slot] + aoff[i], Wsrc[i] + kk);
    }
  };

  bf16x8 af[8], bfr[4];

  // waitsel: 2=vmcnt(8), 1=vmcnt(4), 0=vmcnt(0), 3=none
  auto step = [&](int T, bool do_stage, int waitsel) {
    const char* as_ = (const char*)As[T & 3];
    const char* bs_ = (const char*)Bs[T & 3];
#pragma unroll
    for (int m = 0; m < 8; ++m) af[m] = dsr128((const bf16_t*)(as_ + offA[m]));
#pragma unroll
    for (int n = 0; n < 4; ++n) bfr[n] = dsr128((const bf16_t*)(bs_ + offB[n]));
    if (do_stage) stage_full(T + 3);
    asm volatile("s_waitcnt lgkmcnt(0)" ::: "memory");
    __builtin_amdgcn_sched_barrier(0);
    __builtin_amdgcn_s_setprio(1);
#pragma unroll
    for (int m = 0; m < 8; ++m)
#pragma unroll
      for (int n = 0; n < 4; ++n)
        acc[m][n] = __builtin_amdgcn_mfma_f32_16x16x32_bf16(af[m], bfr[n], acc[m][n], 0, 0, 0);
    __builtin_amdgcn_s_setprio(0);
    __builtin_amdgcn_sched_barrier(0);
    if (waitsel == 2)      asm volatile("s_waitcnt vmcnt(8)" ::: "memory");
    else if (waitsel == 1) asm volatile("s_waitcnt vmcnt(4)" ::: "memory");
    else if (waitsel == 0) asm volatile("s_waitcnt vmcnt(0)" ::: "memory");
    asm volatile("s_barrier" ::: "memory");
  };

  stage_full(0); stage_full(1); stage_full(2);
  asm volatile("s_waitcnt vmcnt(8)" ::: "memory");   // slot 0 landed (own)
  asm volatile("s_barrier" ::: "memory");

  for (int T = 0; T < NT - 3; ++T) step(T, true, 2);
  step(NT - 3, false, 1);
  step(NT - 2, false, 0);
  step(NT - 1, false, 3);

#pragma unroll
  for (int m = 0; m < 8; ++m) {
#pragma unroll
    for (int n = 0; n < 4; ++n) {
#pragma unroll
      for (int j = 0; j < 4; ++j) {
        int r = row0 + wm * 128 + m * 16 + g * 4 + j;
        int c = col0 + wn * 64 + n * 16 + q;
        size_t idx = (size_t)r * ldc + c;
        float v = acc[m][n][j];
        if (EPI == 0) ((bf16_t*)Cp)[idx] = (bf16_t)v;
        else          ((float*)Cp)[idx] = ((const float*)Ep)[idx] + v;
      }
    }
  }
}

// -------- split-K=2 GEMM for mlp, BK=64 (R12, kept as-is) -----------------
__global__ __launch_bounds__(512, 2)
void gemm_sk(const bf16_t* __restrict__ A, const bf16_t* __restrict__ W,
             bf16_t* __restrict__ P0, bf16_t* __restrict__ P1,
             int ldk, int klen, int ldc) {
  __shared__ __align__(128) bf16_t As[2][256 * 64];   // 2 x 32KB
  __shared__ __align__(128) bf16_t Bs[2][256 * 64];   // 2 x 32KB
  const int tid = threadIdx.x;
  const int lane = tid & 63, w = tid >> 6;
  const int wm = w >> 2, wn = w & 3;
  const int g = lane >> 4, q = lane & 15;

  const int nid = (blockIdx.x & 7) * 32 + (blockIdx.x >> 3);  // 256 blocks
  const int s   = nid >> 7;              // K-half
  const int rem = nid & 127;
  const int bx = rem >> 4, by = rem & 15;
  const int row0 = by * 256, col0 = bx * 256;
  const int kofs = s * klen;
  bf16_t* P = s ? P1 : P0;

  f32x4 acc[8][4] = {};

  const bf16_t* Asrc[4];
  const bf16_t* Wsrc[4];
  int aoff[4];
#pragma unroll
  for (int i = 0; i < 4; ++i) {
    int ci = i * 512 + tid;
    int r  = ci >> 3;
    int cs = (ci & 7) ^ (r & 7);
    Asrc[i] = A + (size_t)(row0 + r) * ldk + kofs + cs * 8;
    Wsrc[i] = W + (size_t)(col0 + r) * ldk + kofs + cs * 8;
    aoff[i] = i * 8192 + w * 1024;
  }

  int offA[2][8], offB[2][4];
#pragma unroll
  for (int kk = 0; kk < 2; ++kk) {
#pragma unroll
    for (int m = 0; m < 8; ++m) {
      int r = wm * 128 + m * 16 + q;
      offA[kk][m] = r * 128 + (((kk * 4 + g) ^ (r & 7)) * 16);
    }
#pragma unroll
    for (int n = 0; n < 4; ++n) {
      int r = wn * 64 + n * 16 + q;
      offB[kk][n] = r * 128 + (((kk * 4 + g) ^ (r & 7)) * 16);
    }
  }

  const int NT = klen >> 6;              // 43 for klen=2752
  auto stage = [&](int T, int h) {
    const int slot = T & 1;
    const size_t kk = (size_t)T * 64;
#pragma unroll
    for (int i = 0; i < 2; ++i) {
      int rd = h * 2 + i;
      gld16((char*)As[slot] + aoff[rd], Asrc[rd] + kk);
      gld16((char*)Bs[slot] + aoff[rd], Wsrc[rd] + kk);
    }
  };

  bf16x8 af[8], bfr[4];

  auto half = [&](const char* as_, const char* bs_, int kk) {
#pragma unroll
    for (int m = 0; m < 8; ++m) af[m] = dsr128((const bf16_t*)(as_ + offA[kk][m]));
#pragma unroll
    for (int n = 0; n < 4; ++n) bfr[n] = dsr128((const bf16_t*)(bs_ + offB[kk][n]));
  };
  auto mfmas = [&]() {
    asm volatile("s_waitcnt lgkmcnt(0)" ::: "memory");
    __builtin_amdgcn_sched_barrier(0);
    __builtin_amdgcn_s_setprio(1);
#pragma unroll
    for (int m = 0; m < 8; ++m)
#pragma unroll
      for (int n = 0; n < 4; ++n)
        acc[m][n] = __builtin_amdgcn_mfma_f32_16x16x32_bf16(af[m], bfr[n], acc[m][n], 0, 0, 0);
    __builtin_amdgcn_s_setprio(0);
    __builtin_amdgcn_sched_barrier(0);
  };

  stage(0, 0); stage(0, 1);
  asm volatile("s_waitcnt vmcnt(0)" ::: "memory");
  asm volatile("s_barrier" ::: "memory");

  for (int T = 0; T < NT; ++T) {
    const char* as_ = (const char*)As[T & 1];
    const char* bs_ = (const char*)Bs[T & 1];
    const bool st = (T + 1 < NT);
    half(as_, bs_, 0);
    if (st) stage(T + 1, 0);
    mfmas();
    half(as_, bs_, 1);
    if (st) stage(T + 1, 1);
    mfmas();
    if (st) asm volatile("s_waitcnt vmcnt(0)" ::: "memory");
    asm volatile("s_barrier" ::: "memory");
  }

#pragma unroll
  for (int m = 0; m < 8; ++m)
#pragma unroll
    for (int n = 0; n < 4; ++n)
#pragma unroll
      for (int j = 0; j < 4; ++j) {
        int r = row0 + wm * 128 + m * 16 + g * 4 + j;
        int c = col0 + wn * 64 + n * 16 + q;
        P[(size_t)r * ldc + c] = (bf16_t)acc[m][n][j];
      }
}

// ------- fused gate+val dual GEMM: Out = silu(A Wg^T) * (A Wv^T) ---------
// (R10/R12 exact: 256Mx128N, 2-slot 64KB A+G+V, measured ~252us)
__global__ __launch_bounds__(512, 2)
void gemmgv(const bf16_t* __restrict__ A, const bf16_t* __restrict__ Wg,
            const bf16_t* __restrict__ Wv, bf16_t* __restrict__ Out,
            int M, int N, int K, int ldc, int nby) {
  __shared__ __align__(128) bf16_t As[2][256 * 32];   // 32KB
  __shared__ __align__(128) bf16_t Gs[2][128 * 32];   // 16KB
  __shared__ __align__(128) bf16_t Vs[2][128 * 32];   // 16KB
  const int tid = threadIdx.x;
  const int lane = tid & 63, w = tid >> 6;
  const int wm = w >> 2, wn = w & 3;
  const int g = lane >> 4, q = lane & 15;

  const int nwg = gridDim.x;                 // 688, % 8 == 0
  const int cpx = nwg >> 3;
  const int nid = (blockIdx.x & 7) * cpx + (blockIdx.x >> 3);
  const int bx = nid / nby, by = nid % nby;
  const int row0 = by * 256, col0 = bx * 128;

  f32x4 accg[8][2] = {}, accv[8][2] = {};

  const bf16_t* Asrc[2];
  int aoff[2];
#pragma unroll
  for (int i = 0; i < 2; ++i) {
    int line = i * 64 + (tid >> 3);
    int val  = (tid & 7) ^ (line & 7);
    int r    = (val >> 2) * 128 + line;
    int c    = val & 3;
    Asrc[i] = A + (size_t)(row0 + r) * K + c * 8;
    aoff[i] = i * 8192 + w * 1024;
  }
  const int brow = tid >> 2;
  const int bchk = (tid & 3) ^ ((brow >> 1) & 3);
  const bf16_t* Gsrc = Wg + (size_t)(col0 + brow) * K + bchk * 8;
  const bf16_t* Vsrc = Wv + (size_t)(col0 + brow) * K + bchk * 8;
  const int boff = tid * 16;

  int offA[8], offB[2];
#pragma unroll
  for (int m = 0; m < 8; ++m) {
    int r = wm * 128 + m * 16 + q;
    offA[m] = (r & 127) * 128 + ((((r >> 7) * 4 + g) ^ (r & 7)) * 16);
  }
#pragma unroll
  for (int n = 0; n < 2; ++n) {
    int r = wn * 32 + n * 16 + q;
    offB[n] = r * 64 + ((g ^ ((r >> 1) & 3)) * 16);
  }

  const int NT = K >> 5;
  auto stage = [&](int T) {
    const int slot = T & 1, kk = T * 32;
    gld16((char*)As[slot] + aoff[0], Asrc[0] + kk);
    gld16((char*)As[slot] + aoff[1], Asrc[1] + kk);
    gld16((char*)Gs[slot] + boff, Gsrc + kk);
    gld16((char*)Vs[slot] + boff, Vsrc + kk);
  };

  stage(0);
  for (int T = 0; T < NT; ++T) {
    __syncthreads();
    if (T + 1 < NT) stage(T + 1);
    const char* as_ = (const char*)As[T & 1];
    const char* gs_ = (const char*)Gs[T & 1];
    const char* vs_ = (const char*)Vs[T & 1];
    bf16x8 af[8], bg[2], bv[2];
#pragma unroll
    for (int m = 0; m < 8; ++m) af[m] = *(const bf16x8*)(as_ + offA[m]);
#pragma unroll
    for (int n = 0; n < 2; ++n) {
      bg[n] = *(const bf16x8*)(gs_ + offB[n]);
      bv[n] = *(const bf16x8*)(vs_ + offB[n]);
    }
    __builtin_amdgcn_s_setprio(1);
#pragma unroll
    for (int m = 0; m < 8; ++m)
#pragma unroll
      for (int n = 0; n < 2; ++n) {
        accg[m][n] = __builtin_amdgcn_mfma_f32_16x16x32_bf16(af[m], bg[n], accg[m][n], 0, 0, 0);
        accv[m][n] = __builtin_amdgcn_mfma_f32_16x16x32_bf16(af[m], bv[n], accv[m][n], 0, 0, 0);
      }
    __builtin_amdgcn_s_setprio(0);
    __syncthreads();
  }

#pragma unroll
  for (int m = 0; m < 8; ++m) {
#pragma unroll
    for (int n = 0; n < 2; ++n) {
#pragma unroll
      for (int j = 0; j < 4; ++j) {
        int r = row0 + wm * 128 + m * 16 + g * 4 + j;
        int c = col0 + wn * 32 + n * 16 + q;
        float gt = accg[m][n][j];
        float sg = gt / (1.0f + __expf(-gt));
        Out[(size_t)r * ldc + c] = (bf16_t)(sg * accv[m][n][j]);
      }
    }
  }
}

// ---------------- RoPE + split + V transpose ----------------
__global__ __launch_bounds__(256)
void rope_k(const bf16_t* __restrict__ qkv, bf16_t* __restrict__ Qb,
            bf16_t* __restrict__ Kb, bf16_t* __restrict__ Vt) {
  const int t0 = blockIdx.x * 32;
  const int bh = blockIdx.y;
  const int b = bh >> 4, hh = bh & 15;
  __shared__ bf16_t Vl[32][132];

#pragma unroll
  for (int it = 0; it < 2; ++it) {
    int task = threadIdx.x + it * 256;
    int tt = task >> 4, ck = task & 15, d0 = ck * 8;
    int tg = t0 + tt;
    const bf16_t* srow = qkv + (size_t)(b * Tn + tg) * TD3 + hh * DHn + d0;
    bf16x8 qv = *(const bf16x8*)(srow);
    bf16x8 kv = *(const bf16x8*)(srow + Dn);
    bf16x8 vv = *(const bf16x8*)(srow + 2 * Dn);
    bf16x8 qo, ko;
#pragma unroll
    for (int p = 0; p < 4; ++p) {
      int jj = (d0 >> 1) + p;
      float fr = __expf(-((float)(2 * jj) / 128.0f) * LN1E4);
      float ang = (float)tg * fr;
      float cs = cosf(ang), sn = sinf(ang);
      float qe = (float)qv[2 * p], qod = (float)qv[2 * p + 1];
      float ke = (float)kv[2 * p], kod = (float)kv[2 * p + 1];
      qo[2 * p]     = (bf16_t)((qe * cs - qod * sn) * ASCALE);
      qo[2 * p + 1] = (bf16_t)((qod * cs + qe * sn) * ASCALE);
      ko[2 * p]     = (bf16_t)(ke * cs - kod * sn);
      ko[2 * p + 1] = (bf16_t)(kod * cs + ke * sn);
    }
    *(bf16x8*)&Qb[((size_t)bh * Tn + tg) * DHn + d0] = qo;
    *(bf16x8*)&Kb[((size_t)bh * Tn + tg) * DHn + d0] = ko;
    *(bf16x8*)&Vl[tt][d0] = vv;
  }
  __syncthreads();
#pragma unroll
  for (int it = 0; it < 2; ++it) {
    int task = threadIdx.x + it * 256;
    int dd = task >> 2, tc = (task & 3) * 8;
    bf16x8 ov;
#pragma unroll
    for (int i = 0; i < 8; ++i) ov[i] = Vl[tc + i][dd];
    *(bf16x8*)&Vt[((size_t)bh * DHn + dd) * Tn + t0 + tc] = ov;
  }
}

// ---------------- causal flash attention, paired q-tiles ----------------
__global__ __launch_bounds__(256, 2)
void attn_k(const bf16_t* __restrict__ Qb, const bf16_t* __restrict__ Kb,
            const bf16_t* __restrict__ Vt, bf16_t* __restrict__ Y) {
  const int orig = blockIdx.x + 16 * blockIdx.y;   // 512 blocks total
  const int nid  = (orig & 7) * 64 + (orig >> 3);  // XCD-chunked, bijective
  const int pi = nid & 15;
  const int bh = nid >> 4;
  const int b = bh >> 4, hh = bh & 15;
  const int tid = threadIdx.x, lane = tid & 63, w = tid >> 6;
  const int g = lane >> 4, q = lane & 15;
  const int iA = pi, iB = 31 - pi;
  const int kmax = iB;

  __shared__ bf16_t Ks[2][64 * 128];
  __shared__ bf16_t Vs[2][128 * 64];
  __shared__ bf16_t Ps[4][16 * 72];

  bf16x8 aqA[4], aqB[4];
  {
    const bf16_t* QrA = Qb + ((size_t)bh * Tn + iA * 64 + w * 16 + q) * DHn;
    const bf16_t* QrB = Qb + ((size_t)bh * Tn + iB * 64 + w * 16 + q) * DHn;
#pragma unroll
    for (int s = 0; s < 4; ++s) {
      aqA[s] = *(const bf16x8*)(QrA + s * 32 + g * 8);
      aqB[s] = *(const bf16x8*)(QrB + s * 32 + g * 8);
    }
  }

  f32x4 oA[8] = {}, oB[8] = {};
  float mA[4], lA[4], mB[4], lB[4];
#pragma unroll
  for (int j = 0; j < 4; ++j) {
    mA[j] = -__builtin_inff(); lA[j] = 0.0f;
    mB[j] = -__builtin_inff(); lB[j] = 0.0f;
  }

  auto stage = [&](int buf, int kt) {
    const int k0 = kt * 64;
#pragma unroll
    for (int l = 0; l < 4; ++l) {
      int ci = (w * 4 + l) * 64 + lane;
      int kr = ci >> 4, kc = (ci & 15) ^ (kr & 7);
      gld16((char*)Ks[buf] + (w * 4 + l) * 1024,
            Kb + ((size_t)bh * Tn + k0 + kr) * DHn + kc * 8);
      int vr = ci >> 3, vc = (ci & 7) ^ (vr & 7);
      gld16((char*)Vs[buf] + (w * 4 + l) * 1024,
            Vt + ((size_t)bh * DHn + vr) * Tn + k0 + vc * 8);
    }
  };

  stage(0, 0);

  for (int kt = 0; kt <= kmax; ++kt) {
    __syncthreads();
    if (kt < kmax) stage((kt + 1) & 1, kt + 1);
    const bf16_t* ks = Ks[kt & 1];
    const bf16_t* vs = Vs[kt & 1];
    const bool actA = (kt <= iA);
    const int k0 = kt * 64;

    f32x4 saA[4] = {}, saB[4] = {};
    __builtin_amdgcn_s_setprio(1);
    if (actA) {
#pragma unroll
      for (int s = 0; s < 4; ++s) {
#pragma unroll
        for (int n = 0; n < 4; ++n) {
          bf16x8 bk = *(const bf16x8*)&ks[(n * 16 + q) * 128 + (((s * 4 + g) ^ (q & 7)) * 8)];
          saA[n] = __builtin_amdgcn_mfma_f32_16x16x32_bf16(aqA[s], bk, saA[n], 0, 0, 0);
          saB[n] = __builtin_amdgcn_mfma_f32_16x16x32_bf16(aqB[s], bk, saB[n], 0, 0, 0);
        }
      }
    } else {
#pragma unroll
      for (int s = 0; s < 4; ++s) {
#pragma unroll
        for (int n = 0; n < 4; ++n) {
          bf16x8 bk = *(const bf16x8*)&ks[(n * 16 + q) * 128 + (((s * 4 + g) ^ (q & 7)) * 8)];
          saB[n] = __builtin_amdgcn_mfma_f32_16x16x32_bf16(aqB[s], bk, saB[n], 0, 0, 0);
        }
      }
    }
    __builtin_amdgcn_s_setprio(0);

    bf16x8 paA[2], paB[2];
    auto softmax_p = [&](f32x4* sa, float* mst, float* lst, int itile,
                         bf16x8* pa, int qrow) {
      if (kt == itile) {
#pragma unroll
        for (int n = 0; n < 4; ++n)
#pragma unroll
          for (int j = 0; j < 4; ++j) {
            int kc = k0 + n * 16 + q;
            int qr = qrow + g * 4 + j;
            if (kc > qr) sa[n][j] = -1e30f;
          }
      }
      float mx[4];
#pragma unroll
      for (int j = 0; j < 4; ++j) {
        mx[j] = fmaxf(fmaxf(sa[0][j], sa[1][j]), fmaxf(sa[2][j], sa[3][j]));
#pragma unroll
        for (int off = 1; off < 16; off <<= 1)
          mx[j] = fmaxf(mx[j], __shfl_xor(mx[j], off, 16));
      }
      float ps[4][4], rsum[4];
#pragma unroll
      for (int j = 0; j < 4; ++j) rsum[j] = 0.0f;
      float mnew[4], corr[4];
#pragma unroll
      for (int j = 0; j < 4; ++j) {
        mnew[j] = fmaxf(mst[j], mx[j]);
        corr[j] = exp2f((mst[j] - mnew[j]) * LOG2E);
      }
#pragma unroll
      for (int n = 0; n < 4; ++n)
#pragma unroll
        for (int j = 0; j < 4; ++j) {
          ps[n][j] = exp2f((sa[n][j] - mnew[j]) * LOG2E);
          rsum[j] += ps[n][j];
        }
#pragma unroll
      for (int j = 0; j < 4; ++j) {
#pragma unroll
        for (int off = 1; off < 16; off <<= 1)
          rsum[j] += __shfl_xor(rsum[j], off, 16);
        lst[j] = lst[j] * corr[j] + rsum[j];
        mst[j] = mnew[j];
      }
#pragma unroll
      for (int n = 0; n < 4; ++n)
#pragma unroll
        for (int j = 0; j < 4; ++j)
          Ps[w][(g * 4 + j) * 72 + n * 16 + q] = (bf16_t)ps[n][j];
#pragma unroll
      for (int s2 = 0; s2 < 2; ++s2)
        pa[s2] = *(const bf16x8*)&Ps[w][q * 72 + s2 * 32 + g * 8];
      return corr;
    };

    float cA[4], cB[4];
    if (actA) {
      auto c = softmax_p(saA, mA, lA, iA, paA, iA * 64 + w * 16);
#pragma unroll
      for (int j = 0; j < 4; ++j) cA[j] = c[j];
#pragma unroll
      for (int n8 = 0; n8 < 8; ++n8)
#pragma unroll
        for (int j = 0; j < 4; ++j) oA[n8][j] *= cA[j];
    }
    {
      auto c = softmax_p(saB, mB, lB, iB, paB, iB * 64 + w * 16);
#pragma unroll
      for (int j = 0; j < 4; ++j) cB[j] = c[j];
#pragma unroll
      for (int n8 = 0; n8 < 8; ++n8)
#pragma unroll
        for (int j = 0; j < 4; ++j) oB[n8][j] *= cB[j];
    }

    __builtin_amdgcn_s_setprio(1);
    if (actA) {
#pragma unroll
      for (int s2 = 0; s2 < 2; ++s2)
#pragma unroll
        for (int n8 = 0; n8 < 8; ++n8) {
          bf16x8 bv = *(const bf16x8*)&vs[(n8 * 16 + q) * 64 + (((s2 * 4 + g) ^ (q & 7)) * 8)];
          oA[n8] = __builtin_amdgcn_mfma_f32_16x16x32_bf16(paA[s2], bv, oA[n8], 0, 0, 0);
          oB[n8] = __builtin_amdgcn_mfma_f32_16x16x32_bf16(paB[s2], bv, oB[n8], 0, 0, 0);
        }
    } else {
#pragma unroll
      for (int s2 = 0; s2 < 2; ++s2)
#pragma unroll
        for (int n8 = 0; n8 < 8; ++n8) {
          bf16x8 bv = *(const bf16x8*)&vs[(n8 * 16 + q) * 64 + (((s2 * 4 + g) ^ (q & 7)) * 8)];
          oB[n8] = __builtin_amdgcn_mfma_f32_16x16x32_bf16(paB[s2], bv, oB[n8], 0, 0, 0);
        }
    }
    __builtin_amdgcn_s_setprio(0);
  }

#pragma unroll
  for (int n8 = 0; n8 < 8; ++n8)
#pragma unroll
    for (int j = 0; j < 4; ++j) {
      int trA = iA * 64 + w * 16 + g * 4 + j;
      int trB = iB * 64 + w * 16 + g * 4 + j;
      Y[(size_t)(b * Tn + trA) * Dn + hh * DHn + n8 * 16 + q] =
          (bf16_t)(oA[n8][j] / lA[j]);
      Y[(size_t)(b * Tn + trB) * Dn + hh * DHn + n8 * 16 + q] =
          (bf16_t)(oB[n8][j] / lB[j]);
    }
}

// ---------------- launcher ----------------
extern "C" void kernel_launch(void* const* d_in, const int* in_sizes, int n_in,
                              void* d_out, int out_size, void* d_ws, size_t ws_size,
                              hipStream_t stream) {
  const float* x      = (const float*)d_in[0];
  const float* n1w    = (const float*)d_in[1];
  const float* n2w    = (const float*)d_in[2];
  const float* attn_w = (const float*)d_in[3];
  const float* proj_w = (const float*)d_in[4];
  const float* gate_w = (const float*)d_in[5];
  const float* val_w  = (const float*)d_in[6];
  const float* mlp_w  = (const float*)d_in[7];

  char* ws = (char*)d_ws;
  bf16_t* h    = (bf16_t*)(ws);                  // 16.78MB
  bf16_t* bufA = (bf16_t*)(ws + 16777216);       // 50.3MB
  bf16_t* bufB = (bf16_t*)(ws + 67108864);       // 50.3MB
  bf16_t* wb   = (bf16_t*)(ws + 117440512);      // 25.2MB

  bf16_t* qkv  = bufA;
  bf16_t* wbV  = bufA;   // val weights (bufA free after rope)
  bf16_t* Qb   = bufB;
  bf16_t* Kb   = Qb + (size_t)32 * Tn * DHn;
  bf16_t* Vt   = Kb + (size_t)32 * Tn * DHn;
  bf16_t* gv   = bufB;   // gate*val output (bufB free after attn)
  bf16_t* y    = h;
  bf16_t* P0   = h;      // split-K partial 0 (h free after gemmgv)
  bf16_t* P1   = bufA;   // split-K partial 1 (bufA free after gemmgv)
  float*  out  = (float*)d_out;

  // 1) h1 = rmsnorm(x)
  rmsnorm_k<<<BTn, 256, 0, stream>>>(x, n1w, h);
  // 2) qkv = h1 @ attn_w^T
  cvt_pad_k<<<(TD3 * Dn / 8 + 255) / 256, 256, 0, stream>>>(attn_w, wb, TD3, Dn, Dn, TD3 * Dn / 8);
  gemm256<0><<<(TD3 / 256) * (BTn / 256), 512, 0, stream>>>(h, wb, (void*)qkv, nullptr, BTn, TD3, Dn, TD3, BTn / 256);
  // 3) rope + split + V^T
  rope_k<<<dim3(Tn / 32, 32), 256, 0, stream>>>(qkv, Qb, Kb, Vt);
  // 4) attention -> y
  attn_k<<<dim3(16, 32), 256, 0, stream>>>(Qb, Kb, Vt, y);
  // 5) x1 = x + y @ proj_w^T  (fp32, into d_out)
  cvt_pad_k<<<(Dn * Dn / 8 + 255) / 256, 256, 0, stream>>>(proj_w, wb, Dn, Dn, Dn, Dn * Dn / 8);
  gemm256<1><<<(Dn / 256) * (BTn / 256), 512, 0, stream>>>(y, wb, (void*)out, (const void*)x, BTn, Dn, Dn, Dn, BTn / 256);
  // 6) h2 = rmsnorm(x1)
  rmsnorm_k<<<BTn, 256, 0, stream>>>(out, n2w, h);
  // 7+8) gv = silu(h2 @ gate_w^T) * (h2 @ val_w^T)  -- fused dual GEMM
  cvt_pad_k<<<(FGPn * Dn / 8 + 255) / 256, 256, 0, stream>>>(gate_w, wb, FGn, Dn, Dn, FGPn * Dn / 8);
  cvt_pad_k<<<(FGPn * Dn / 8 + 255) / 256, 256, 0, stream>>>(val_w, wbV, FGn, Dn, Dn, FGPn * Dn / 8);
  gemmgv<<<(FGPn / 128) * (BTn / 256), 512, 0, stream>>>(h, wb, wbV, gv, BTn, FGPn, Dn, FGPn, BTn / 256);
  // 9) mlp split-K=2 (BK=64): P0/P1 = gv[:, s*2752:] @ mlp_w[:, s*2752:]^T
  cvt_pad_k<<<(Dn * FGPn / 8 + 255) / 256, 256, 0, stream>>>(mlp_w, wb, Dn, FGn, FGPn, Dn * FGPn / 8);
  gemm_sk<<<256, 512, 0, stream>>>(gv, wb, P0, P1, FGPn, FGPn / 2, Dn);
  // 10) out += P0 + P1
  reduce_k<<<BTn * Dn / 8 / 256, 256, 0, stream>>>(out, P0, P1);
}

// Round 14
// 745.656 us; speedup vs baseline: 1.3203x; 1.0925x over previous
//
#include <hip/hip_runtime.h>
#include <hip/hip_bf16.h>
#include <stdint.h>

typedef __bf16 bf16_t;
typedef __bf16 bf16x8 __attribute__((ext_vector_type(8)));
typedef float  f32x4  __attribute__((ext_vector_type(4)));

#define DEV __device__ __forceinline__

constexpr int   Bn = 2, Tn = 2048, Dn = 2048, Hn = 16, DHn = 128;
constexpr int   BTn = Bn * Tn;          // 4096 rows
constexpr int   TD3 = 3 * Dn;           // 6144
constexpr int   FGn = 5461, FGPn = 5504; // pad to 43*128 (688 blocks, %8==0)
constexpr float EPSf   = 1e-5f;
constexpr float LOG2E  = 1.4426950408889634f;
constexpr float ASCALE = 0.08838834764831845f;   // 1/sqrt(128)
constexpr float LN1E4  = 9.210340371976184f;     // ln(10000)

// async global->LDS, 16B per lane, wave-uniform LDS base
DEV void gld16(void* lds, const void* g) {
  __builtin_amdgcn_global_load_lds(
      (__attribute__((address_space(1))) void*)(void*)g,
      (__attribute__((address_space(3))) void*)lds, 16, 0, 0);
}

// inline-asm LDS read, ordered only by explicit s_waitcnt lgkmcnt(N)
DEV bf16x8 dsr128(const bf16_t* p) {
  bf16x8 r;
  asm volatile("ds_read_b128 %0, %1"
               : "=v"(r)
               : "v"((const __attribute__((address_space(3))) bf16_t*)p));
  return r;
}

// ---------------- RMSNorm (fp32 in -> bf16 out) ----------------
__global__ __launch_bounds__(256)
void rmsnorm_k(const float* __restrict__ x, const float* __restrict__ w,
               bf16_t* __restrict__ out) {
  const int row = blockIdx.x;
  const int tid = threadIdx.x;
  const float* xr = x + (size_t)row * Dn;
  float4 a = ((const float4*)xr)[tid * 2];
  float4 b = ((const float4*)xr)[tid * 2 + 1];
  float ss = a.x*a.x + a.y*a.y + a.z*a.z + a.w*a.w
           + b.x*b.x + b.y*b.y + b.z*b.z + b.w*b.w;
#pragma unroll
  for (int off = 32; off > 0; off >>= 1) ss += __shfl_xor(ss, off, 64);
  __shared__ float red[4];
  if ((tid & 63) == 0) red[tid >> 6] = ss;
  __syncthreads();
  float tot = red[0] + red[1] + red[2] + red[3];
  float rms = rsqrtf(tot * (1.0f / Dn) + EPSf);
  float4 wa = ((const float4*)w)[tid * 2];
  float4 wb = ((const float4*)w)[tid * 2 + 1];
  bf16x8 o;
  o[0] = (bf16_t)(a.x * rms * wa.x); o[1] = (bf16_t)(a.y * rms * wa.y);
  o[2] = (bf16_t)(a.z * rms * wa.z); o[3] = (bf16_t)(a.w * rms * wa.w);
  o[4] = (bf16_t)(b.x * rms * wb.x); o[5] = (bf16_t)(b.y * rms * wb.y);
  o[6] = (bf16_t)(b.z * rms * wb.z); o[7] = (bf16_t)(b.w * rms * wb.w);
  *(bf16x8*)&out[(size_t)row * Dn + tid * 8] = o;
}

// ---------------- fp32 -> bf16 convert with zero padding ----------------
__global__ __launch_bounds__(256)
void cvt_pad_k(const float* __restrict__ src, bf16_t* __restrict__ dst,
               int srcR, int srcC, int dstC, int n8) {
  int i = blockIdx.x * 256 + threadIdx.x;
  if (i >= n8) return;
  long base = (long)i * 8;
  int r = (int)(base / dstC);
  int c = (int)(base % dstC);
  bf16x8 o;
#pragma unroll
  for (int k = 0; k < 8; ++k) {
    int cc = c + k;
    float v = (r < srcR && cc < srcC) ? src[(size_t)r * srcC + cc] : 0.0f;
    o[k] = (bf16_t)v;
  }
  *(bf16x8*)&dst[base] = o;
}

// ---------------- reduce: out += P0 + P1 (split-K partials) ----------------
__global__ __launch_bounds__(256)
void reduce_k(float* __restrict__ out, const bf16_t* __restrict__ P0,
              const bf16_t* __restrict__ P1) {
  int i = blockIdx.x * 256 + threadIdx.x;     // 8 elems per thread
  bf16x8 p0 = *(const bf16x8*)&P0[(size_t)i * 8];
  bf16x8 p1 = *(const bf16x8*)&P1[(size_t)i * 8];
  float4 o0 = ((const float4*)out)[i * 2];
  float4 o1 = ((const float4*)out)[i * 2 + 1];
  o0.x += (float)p0[0] + (float)p1[0];
  o0.y += (float)p0[1] + (float)p1[1];
  o0.z += (float)p0[2] + (float)p1[2];
  o0.w += (float)p0[3] + (float)p1[3];
  o1.x += (float)p0[4] + (float)p1[4];
  o1.y += (float)p0[5] + (float)p1[5];
  o1.z += (float)p0[6] + (float)p1[6];
  o1.w += (float)p0[7] + (float)p1[7];
  ((float4*)out)[i * 2]     = o0;
  ((float4*)out)[i * 2 + 1] = o1;
}

// ------- GEMM 256x256, BK=64 2-slot (gemm_sk structure = best measured) ---
// 880 TF on mlp: ~2930 cyc per 32-K equivalent. 128KB LDS, 1/CU.
// Per K64 step: {12 ds_read ; 4 gld ; lgkm(0) ; 32 MFMA} x2 ; vmcnt(0) ; bar.
// LDS layout: chunk16(r, c in [0,8)) at byte r*128 + ((c^(r&7))*16).
// EPI: 0 = bf16 store ; 1 = f32 out = resid + acc
template<int EPI>
__global__ __launch_bounds__(512, 2)
void gemm64(const bf16_t* __restrict__ A, const bf16_t* __restrict__ W,
            void* Cp, const void* Ep, int K, int ldc, int nby) {
  __shared__ __align__(128) bf16_t As[2][256 * 64];   // 2 x 32KB
  __shared__ __align__(128) bf16_t Bs[2][256 * 64];   // 2 x 32KB
  const int tid = threadIdx.x;
  const int lane = tid & 63, w = tid >> 6;
  const int wm = w >> 2, wn = w & 3;
  const int g = lane >> 4, q = lane & 15;

  const int nwg = gridDim.x;               // % 8 == 0
  const int cpx = nwg >> 3;
  const int nid = (blockIdx.x & 7) * cpx + (blockIdx.x >> 3);
  const int bx = nid / nby, by = nid % nby;
  const int row0 = by * 256, col0 = bx * 256;

  f32x4 acc[8][4] = {};

  const bf16_t* Asrc[4];
  const bf16_t* Wsrc[4];
  int aoff[4];
#pragma unroll
  for (int i = 0; i < 4; ++i) {
    int ci = i * 512 + tid;
    int r  = ci >> 3;
    int cs = (ci & 7) ^ (r & 7);
    Asrc[i] = A + (size_t)(row0 + r) * K + cs * 8;
    Wsrc[i] = W + (size_t)(col0 + r) * K + cs * 8;
    aoff[i] = i * 8192 + w * 1024;
  }

  int offA[2][8], offB[2][4];
#pragma unroll
  for (int kk = 0; kk < 2; ++kk) {
#pragma unroll
    for (int m = 0; m < 8; ++m) {
      int r = wm * 128 + m * 16 + q;
      offA[kk][m] = r * 128 + (((kk * 4 + g) ^ (r & 7)) * 16);
    }
#pragma unroll
    for (int n = 0; n < 4; ++n) {
      int r = wn * 64 + n * 16 + q;
      offB[kk][n] = r * 128 + (((kk * 4 + g) ^ (r & 7)) * 16);
    }
  }

  const int NT = K >> 6;
  auto stage = [&](int T, int h) {       // h: 0 = rounds 0,1 ; 1 = rounds 2,3
    const int slot = T & 1;
    const size_t kk = (size_t)T * 64;
#pragma unroll
    for (int i = 0; i < 2; ++i) {
      int rd = h * 2 + i;
      gld16((char*)As[slot] + aoff[rd], Asrc[rd] + kk);
      gld16((char*)Bs[slot] + aoff[rd], Wsrc[rd] + kk);
    }
  };

  bf16x8 af[8], bfr[4];

  auto half = [&](const char* as_, const char* bs_, int kk) {
#pragma unroll
    for (int m = 0; m < 8; ++m) af[m] = dsr128((const bf16_t*)(as_ + offA[kk][m]));
#pragma unroll
    for (int n = 0; n < 4; ++n) bfr[n] = dsr128((const bf16_t*)(bs_ + offB[kk][n]));
  };
  auto mfmas = [&]() {
    asm volatile("s_waitcnt lgkmcnt(0)" ::: "memory");
    __builtin_amdgcn_sched_barrier(0);
    __builtin_amdgcn_s_setprio(1);
#pragma unroll
    for (int m = 0; m < 8; ++m)
#pragma unroll
      for (int n = 0; n < 4; ++n)
        acc[m][n] = __builtin_amdgcn_mfma_f32_16x16x32_bf16(af[m], bfr[n], acc[m][n], 0, 0, 0);
    __builtin_amdgcn_s_setprio(0);
    __builtin_amdgcn_sched_barrier(0);
  };

  stage(0, 0); stage(0, 1);
  asm volatile("s_waitcnt vmcnt(0)" ::: "memory");
  asm volatile("s_barrier" ::: "memory");

  for (int T = 0; T < NT; ++T) {
    const char* as_ = (const char*)As[T & 1];
    const char* bs_ = (const char*)Bs[T & 1];
    const bool st = (T + 1 < NT);
    half(as_, bs_, 0);
    if (st) stage(T + 1, 0);
    mfmas();
    half(as_, bs_, 1);
    if (st) stage(T + 1, 1);
    mfmas();
    if (st) asm volatile("s_waitcnt vmcnt(0)" ::: "memory");
    asm volatile("s_barrier" ::: "memory");
  }

#pragma unroll
  for (int m = 0; m < 8; ++m) {
#pragma unroll
    for (int n = 0; n < 4; ++n) {
#pragma unroll
      for (int j = 0; j < 4; ++j) {
        int r = row0 + wm * 128 + m * 16 + g * 4 + j;
        int c = col0 + wn * 64 + n * 16 + q;
        size_t idx = (size_t)r * ldc + c;
        float v = acc[m][n][j];
        if (EPI == 0) ((bf16_t*)Cp)[idx] = (bf16_t)v;
        else          ((float*)Cp)[idx] = ((const float*)Ep)[idx] + v;
      }
    }
  }
}

// ---------------- GEMM 256x256 BK=32 (R13 1-barrier) — used for proj -----
template<int EPI>
__global__ __launch_bounds__(512, 2)
void gemm256(const bf16_t* __restrict__ A, const bf16_t* __restrict__ W,
             void* Cp, const void* Ep, int M, int N, int K, int ldc, int nby) {
  __shared__ __align__(128) bf16_t As[4][256 * 32];
  __shared__ __align__(128) bf16_t Bs[4][256 * 32];
  const int tid = threadIdx.x;
  const int lane = tid & 63, w = tid >> 6;
  const int wm = w >> 2, wn = w & 3;
  const int g = lane >> 4, q = lane & 15;

  const int nwg = gridDim.x;
  const int cpx = nwg >> 3;
  const int nid = (blockIdx.x & 7) * cpx + (blockIdx.x >> 3);
  const int bx = nid / nby, by = nid % nby;
  const int row0 = by * 256, col0 = bx * 256;

  f32x4 acc[8][4] = {};

  const bf16_t* Asrc[2];
  const bf16_t* Wsrc[2];
  int aoff[2];
#pragma unroll
  for (int i = 0; i < 2; ++i) {
    int line = i * 64 + (tid >> 3);
    int val  = (tid & 7) ^ (line & 7);
    int r    = (val >> 2) * 128 + line;
    int c    = val & 3;
    Asrc[i] = A + (size_t)(row0 + r) * K + c * 8;
    Wsrc[i] = W + (size_t)(col0 + r) * K + c * 8;
    aoff[i] = i * 8192 + w * 1024;
  }

  int offA[8], offB[4];
#pragma unroll
  for (int m = 0; m < 8; ++m) {
    int r = wm * 128 + m * 16 + q;
    offA[m] = (r & 127) * 128 + ((((r >> 7) * 4 + g) ^ (r & 7)) * 16);
  }
#pragma unroll
  for (int n = 0; n < 4; ++n) {
    int r = wn * 64 + n * 16 + q;
    offB[n] = (r & 127) * 128 + ((((r >> 7) * 4 + g) ^ (r & 7)) * 16);
  }

  const int NT = K >> 5;
  auto stage_full = [&](int T) {
    const int slot = T & 3, kk = T * 32;
#pragma unroll
    for (int i = 0; i < 2; ++i) {
      gld16((char*)As[slot] + aoff[i], Asrc[i] + kk);
      gld16((char*)Bs[slot] + aoff[i], Wsrc[i] + kk);
    }
  };

  bf16x8 af[8], bfr[4];

  auto step = [&](int T, bool do_stage, int waitsel) {
    const char* as_ = (const char*)As[T & 3];
    const char* bs_ = (const char*)Bs[T & 3];
#pragma unroll
    for (int m = 0; m < 8; ++m) af[m] = dsr128((const bf16_t*)(as_ + offA[m]));
#pragma unroll
    for (int n = 0; n < 4; ++n) bfr[n] = dsr128((const bf16_t*)(bs_ + offB[n]));
    if (do_stage) stage_full(T + 3);
    asm volatile("s_waitcnt lgkmcnt(0)" ::: "memory");
    __builtin_amdgcn_sched_barrier(0);
    __builtin_amdgcn_s_setprio(1);
#pragma unroll
    for (int m = 0; m < 8; ++m)
#pragma unroll
      for (int n = 0; n < 4; ++n)
        acc[m][n] = __builtin_amdgcn_mfma_f32_16x16x32_bf16(af[m], bfr[n], acc[m][n], 0, 0, 0);
    __builtin_amdgcn_s_setprio(0);
    __builtin_amdgcn_sched_barrier(0);
    if (waitsel == 2)      asm volatile("s_waitcnt vmcnt(8)" ::: "memory");
    else if (waitsel == 1) asm volatile("s_waitcnt vmcnt(4)" ::: "memory");
    else if (waitsel == 0) asm volatile("s_waitcnt vmcnt(0)" ::: "memory");
    asm volatile("s_barrier" ::: "memory");
  };

  stage_full(0); stage_full(1); stage_full(2);
  asm volatile("s_waitcnt vmcnt(8)" ::: "memory");
  asm volatile("s_barrier" ::: "memory");

  for (int T = 0; T < NT - 3; ++T) step(T, true, 2);
  step(NT - 3, false, 1);
  step(NT - 2, false, 0);
  step(NT - 1, false, 3);

#pragma unroll
  for (int m = 0; m < 8; ++m) {
#pragma unroll
    for (int n = 0; n < 4; ++n) {
#pragma unroll
      for (int j = 0; j < 4; ++j) {
        int r = row0 + wm * 128 + m * 16 + g * 4 + j;
        int c = col0 + wn * 64 + n * 16 + q;
        size_t idx = (size_t)r * ldc + c;
        float v = acc[m][n][j];
        if (EPI == 0) ((bf16_t*)Cp)[idx] = (bf16_t)v;
        else          ((float*)Cp)[idx] = ((const float*)Ep)[idx] + v;
      }
    }
  }
}

// -------- split-K=2 GEMM for mlp, BK=64 (R12, kept as-is) -----------------
__global__ __launch_bounds__(512, 2)
void gemm_sk(const bf16_t* __restrict__ A, const bf16_t* __restrict__ W,
             bf16_t* __restrict__ P0, bf16_t* __restrict__ P1,
             int ldk, int klen, int ldc) {
  __shared__ __align__(128) bf16_t As[2][256 * 64];   // 2 x 32KB
  __shared__ __align__(128) bf16_t Bs[2][256 * 64];   // 2 x 32KB
  const int tid = threadIdx.x;
  const int lane = tid & 63, w = tid >> 6;
  const int wm = w >> 2, wn = w & 3;
  const int g = lane >> 4, q = lane & 15;

  const int nid = (blockIdx.x & 7) * 32 + (blockIdx.x >> 3);  // 256 blocks
  const int s   = nid >> 7;              // K-half
  const int rem = nid & 127;
  const int bx = rem >> 4, by = rem & 15;
  const int row0 = by * 256, col0 = bx * 256;
  const int kofs = s * klen;
  bf16_t* P = s ? P1 : P0;

  f32x4 acc[8][4] = {};

  const bf16_t* Asrc[4];
  const bf16_t* Wsrc[4];
  int aoff[4];
#pragma unroll
  for (int i = 0; i < 4; ++i) {
    int ci = i * 512 + tid;
    int r  = ci >> 3;
    int cs = (ci & 7) ^ (r & 7);
    Asrc[i] = A + (size_t)(row0 + r) * ldk + kofs + cs * 8;
    Wsrc[i] = W + (size_t)(col0 + r) * ldk + kofs + cs * 8;
    aoff[i] = i * 8192 + w * 1024;
  }

  int offA[2][8], offB[2][4];
#pragma unroll
  for (int kk = 0; kk < 2; ++kk) {
#pragma unroll
    for (int m = 0; m < 8; ++m) {
      int r = wm * 128 + m * 16 + q;
      offA[kk][m] = r * 128 + (((kk * 4 + g) ^ (r & 7)) * 16);
    }
#pragma unroll
    for (int n = 0; n < 4; ++n) {
      int r = wn * 64 + n * 16 + q;
      offB[kk][n] = r * 128 + (((kk * 4 + g) ^ (r & 7)) * 16);
    }
  }

  const int NT = klen >> 6;              // 43 for klen=2752
  auto stage = [&](int T, int h) {
    const int slot = T & 1;
    const size_t kk = (size_t)T * 64;
#pragma unroll
    for (int i = 0; i < 2; ++i) {
      int rd = h * 2 + i;
      gld16((char*)As[slot] + aoff[rd], Asrc[rd] + kk);
      gld16((char*)Bs[slot] + aoff[rd], Wsrc[rd] + kk);
    }
  };

  bf16x8 af[8], bfr[4];

  auto half = [&](const char* as_, const char* bs_, int kk) {
#pragma unroll
    for (int m = 0; m < 8; ++m) af[m] = dsr128((const bf16_t*)(as_ + offA[kk][m]));
#pragma unroll
    for (int n = 0; n < 4; ++n) bfr[n] = dsr128((const bf16_t*)(bs_ + offB[kk][n]));
  };
  auto mfmas = [&]() {
    asm volatile("s_waitcnt lgkmcnt(0)" ::: "memory");
    __builtin_amdgcn_sched_barrier(0);
    __builtin_amdgcn_s_setprio(1);
#pragma unroll
    for (int m = 0; m < 8; ++m)
#pragma unroll
      for (int n = 0; n < 4; ++n)
        acc[m][n] = __builtin_amdgcn_mfma_f32_16x16x32_bf16(af[m], bfr[n], acc[m][n], 0, 0, 0);
    __builtin_amdgcn_s_setprio(0);
    __builtin_amdgcn_sched_barrier(0);
  };

  stage(0, 0); stage(0, 1);
  asm volatile("s_waitcnt vmcnt(0)" ::: "memory");
  asm volatile("s_barrier" ::: "memory");

  for (int T = 0; T < NT; ++T) {
    const char* as_ = (const char*)As[T & 1];
    const char* bs_ = (const char*)Bs[T & 1];
    const bool st = (T + 1 < NT);
    half(as_, bs_, 0);
    if (st) stage(T + 1, 0);
    mfmas();
    half(as_, bs_, 1);
    if (st) stage(T + 1, 1);
    mfmas();
    if (st) asm volatile("s_waitcnt vmcnt(0)" ::: "memory");
    asm volatile("s_barrier" ::: "memory");
  }

#pragma unroll
  for (int m = 0; m < 8; ++m)
#pragma unroll
    for (int n = 0; n < 4; ++n)
#pragma unroll
      for (int j = 0; j < 4; ++j) {
        int r = row0 + wm * 128 + m * 16 + g * 4 + j;
        int c = col0 + wn * 64 + n * 16 + q;
        P[(size_t)r * ldc + c] = (bf16_t)acc[m][n][j];
      }
}

// ------- fused gate+val dual GEMM, BK=64: Out = silu(A Wg^T)*(A Wv^T) -----
// gemm_sk skeleton; A 64KB + G 32KB + V 32KB = 128KB, 1/CU.
__global__ __launch_bounds__(512, 2)
void gemmgv(const bf16_t* __restrict__ A, const bf16_t* __restrict__ Wg,
            const bf16_t* __restrict__ Wv, bf16_t* __restrict__ Out,
            int K, int ldc, int nby) {
  __shared__ __align__(128) bf16_t As[2][256 * 64];   // 2 x 32KB
  __shared__ __align__(128) bf16_t Gs[2][128 * 64];   // 2 x 16KB
  __shared__ __align__(128) bf16_t Vs[2][128 * 64];   // 2 x 16KB
  const int tid = threadIdx.x;
  const int lane = tid & 63, w = tid >> 6;
  const int wm = w >> 2, wn = w & 3;
  const int g = lane >> 4, q = lane & 15;

  const int nwg = gridDim.x;                 // 688, % 8 == 0
  const int cpx = nwg >> 3;
  const int nid = (blockIdx.x & 7) * cpx + (blockIdx.x >> 3);
  const int bx = nid / nby, by = nid % nby;
  const int row0 = by * 256, col0 = bx * 128;

  f32x4 accg[8][2] = {}, accv[8][2] = {};

  // A staging: 4 rounds of 512 threads
  const bf16_t* Asrc[4];
  int aoff[4];
#pragma unroll
  for (int i = 0; i < 4; ++i) {
    int ci = i * 512 + tid;
    int r  = ci >> 3;
    int cs = (ci & 7) ^ (r & 7);
    Asrc[i] = A + (size_t)(row0 + r) * K + cs * 8;
    aoff[i] = i * 8192 + w * 1024;
  }
  // G/V staging: 2 rounds each (128 rows x 64 K)
  const bf16_t* Gsrc[2];
  const bf16_t* Vsrc[2];
  int boff[2];
#pragma unroll
  for (int i = 0; i < 2; ++i) {
    int ci = i * 512 + tid;
    int r  = ci >> 3;
    int cs = (ci & 7) ^ (r & 7);
    Gsrc[i] = Wg + (size_t)(col0 + r) * K + cs * 8;
    Vsrc[i] = Wv + (size_t)(col0 + r) * K + cs * 8;
    boff[i] = i * 8192 + w * 1024;
  }

  int offA[2][8], offB[2][2];
#pragma unroll
  for (int kk = 0; kk < 2; ++kk) {
#pragma unroll
    for (int m = 0; m < 8; ++m) {
      int r = wm * 128 + m * 16 + q;
      offA[kk][m] = r * 128 + (((kk * 4 + g) ^ (r & 7)) * 16);
    }
#pragma unroll
    for (int n = 0; n < 2; ++n) {
      int r = wn * 32 + n * 16 + q;
      offB[kk][n] = r * 128 + (((kk * 4 + g) ^ (r & 7)) * 16);
    }
  }

  const int NT = K >> 6;                 // 32
  auto stage = [&](int T, int h) {       // h=0: A rounds 0,1 + G0 + V0
    const int slot = T & 1;              // h=1: A rounds 2,3 + G1 + V1
    const size_t kk = (size_t)T * 64;
#pragma unroll
    for (int i = 0; i < 2; ++i) {
      int rd = h * 2 + i;
      gld16((char*)As[slot] + aoff[rd], Asrc[rd] + kk);
    }
    gld16((char*)Gs[slot] + boff[h], Gsrc[h] + kk);
    gld16((char*)Vs[slot] + boff[h], Vsrc[h] + kk);
  };

  bf16x8 af[8], bg[2], bv[2];

  auto half = [&](const char* as_, const char* gs_, const char* vs_, int kk) {
#pragma unroll
    for (int m = 0; m < 8; ++m) af[m] = dsr128((const bf16_t*)(as_ + offA[kk][m]));
#pragma unroll
    for (int n = 0; n < 2; ++n) {
      bg[n] = dsr128((const bf16_t*)(gs_ + offB[kk][n]));
      bv[n] = dsr128((const bf16_t*)(vs_ + offB[kk][n]));
    }
  };
  auto mfmas = [&]() {
    asm volatile("s_waitcnt lgkmcnt(0)" ::: "memory");
    __builtin_amdgcn_sched_barrier(0);
    __builtin_amdgcn_s_setprio(1);
#pragma unroll
    for (int m = 0; m < 8; ++m)
#pragma unroll
      for (int n = 0; n < 2; ++n) {
        accg[m][n] = __builtin_amdgcn_mfma_f32_16x16x32_bf16(af[m], bg[n], accg[m][n], 0, 0, 0);
        accv[m][n] = __builtin_amdgcn_mfma_f32_16x16x32_bf16(af[m], bv[n], accv[m][n], 0, 0, 0);
      }
    __builtin_amdgcn_s_setprio(0);
    __builtin_amdgcn_sched_barrier(0);
  };

  stage(0, 0); stage(0, 1);
  asm volatile("s_waitcnt vmcnt(0)" ::: "memory");
  asm volatile("s_barrier" ::: "memory");

  for (int T = 0; T < NT; ++T) {
    const char* as_ = (const char*)As[T & 1];
    const char* gs_ = (const char*)Gs[T & 1];
    const char* vs_ = (const char*)Vs[T & 1];
    const bool st = (T + 1 < NT);
    half(as_, gs_, vs_, 0);
    if (st) stage(T + 1, 0);
    mfmas();
    half(as_, gs_, vs_, 1);
    if (st) stage(T + 1, 1);
    mfmas();
    if (st) asm volatile("s_waitcnt vmcnt(0)" ::: "memory");
    asm volatile("s_barrier" ::: "memory");
  }

#pragma unroll
  for (int m = 0; m < 8; ++m) {
#pragma unroll
    for (int n = 0; n < 2; ++n) {
#pragma unroll
      for (int j = 0; j < 4; ++j) {
        int r = row0 + wm * 128 + m * 16 + g * 4 + j;
        int c = col0 + wn * 32 + n * 16 + q;
        float gt = accg[m][n][j];
        float sg = gt / (1.0f + __expf(-gt));
        Out[(size_t)r * ldc + c] = (bf16_t)(sg * accv[m][n][j]);
      }
    }
  }
}

// ---------------- RoPE + split + V transpose ----------------
__global__ __launch_bounds__(256)
void rope_k(const bf16_t* __restrict__ qkv, bf16_t* __restrict__ Qb,
            bf16_t* __restrict__ Kb, bf16_t* __restrict__ Vt) {
  const int t0 = blockIdx.x * 32;
  const int bh = blockIdx.y;
  const int b = bh >> 4, hh = bh & 15;
  __shared__ bf16_t Vl[32][132];

#pragma unroll
  for (int it = 0; it < 2; ++it) {
    int task = threadIdx.x + it * 256;
    int tt = task >> 4, ck = task & 15, d0 = ck * 8;
    int tg = t0 + tt;
    const bf16_t* srow = qkv + (size_t)(b * Tn + tg) * TD3 + hh * DHn + d0;
    bf16x8 qv = *(const bf16x8*)(srow);
    bf16x8 kv = *(const bf16x8*)(srow + Dn);
    bf16x8 vv = *(const bf16x8*)(srow + 2 * Dn);
    bf16x8 qo, ko;
#pragma unroll
    for (int p = 0; p < 4; ++p) {
      int jj = (d0 >> 1) + p;
      float fr = __expf(-((float)(2 * jj) / 128.0f) * LN1E4);
      float ang = (float)tg * fr;
      float cs = cosf(ang), sn = sinf(ang);
      float qe = (float)qv[2 * p], qod = (float)qv[2 * p + 1];
      float ke = (float)kv[2 * p], kod = (float)kv[2 * p + 1];
      qo[2 * p]     = (bf16_t)((qe * cs - qod * sn) * ASCALE);
      qo[2 * p + 1] = (bf16_t)((qod * cs + qe * sn) * ASCALE);
      ko[2 * p]     = (bf16_t)(ke * cs - kod * sn);
      ko[2 * p + 1] = (bf16_t)(kod * cs + ke * sn);
    }
    *(bf16x8*)&Qb[((size_t)bh * Tn + tg) * DHn + d0] = qo;
    *(bf16x8*)&Kb[((size_t)bh * Tn + tg) * DHn + d0] = ko;
    *(bf16x8*)&Vl[tt][d0] = vv;
  }
  __syncthreads();
#pragma unroll
  for (int it = 0; it < 2; ++it) {
    int task = threadIdx.x + it * 256;
    int dd = task >> 2, tc = (task & 3) * 8;
    bf16x8 ov;
#pragma unroll
    for (int i = 0; i < 8; ++i) ov[i] = Vl[tc + i][dd];
    *(bf16x8*)&Vt[((size_t)bh * DHn + dd) * Tn + t0 + tc] = ov;
  }
}

// ---------------- causal flash attention, paired q-tiles ----------------
__global__ __launch_bounds__(256, 2)
void attn_k(const bf16_t* __restrict__ Qb, const bf16_t* __restrict__ Kb,
            const bf16_t* __restrict__ Vt, bf16_t* __restrict__ Y) {
  const int orig = blockIdx.x + 16 * blockIdx.y;   // 512 blocks total
  const int nid  = (orig & 7) * 64 + (orig >> 3);  // XCD-chunked, bijective
  const int pi = nid & 15;
  const int bh = nid >> 4;
  const int b = bh >> 4, hh = bh & 15;
  const int tid = threadIdx.x, lane = tid & 63, w = tid >> 6;
  const int g = lane >> 4, q = lane & 15;
  const int iA = pi, iB = 31 - pi;
  const int kmax = iB;

  __shared__ bf16_t Ks[2][64 * 128];
  __shared__ bf16_t Vs[2][128 * 64];
  __shared__ bf16_t Ps[4][16 * 72];

  bf16x8 aqA[4], aqB[4];
  {
    const bf16_t* QrA = Qb + ((size_t)bh * Tn + iA * 64 + w * 16 + q) * DHn;
    const bf16_t* QrB = Qb + ((size_t)bh * Tn + iB * 64 + w * 16 + q) * DHn;
#pragma unroll
    for (int s = 0; s < 4; ++s) {
      aqA[s] = *(const bf16x8*)(QrA + s * 32 + g * 8);
      aqB[s] = *(const bf16x8*)(QrB + s * 32 + g * 8);
    }
  }

  f32x4 oA[8] = {}, oB[8] = {};
  float mA[4], lA[4], mB[4], lB[4];
#pragma unroll
  for (int j = 0; j < 4; ++j) {
    mA[j] = -__builtin_inff(); lA[j] = 0.0f;
    mB[j] = -__builtin_inff(); lB[j] = 0.0f;
  }

  auto stage = [&](int buf, int kt) {
    const int k0 = kt * 64;
#pragma unroll
    for (int l = 0; l < 4; ++l) {
      int ci = (w * 4 + l) * 64 + lane;
      int kr = ci >> 4, kc = (ci & 15) ^ (kr & 7);
      gld16((char*)Ks[buf] + (w * 4 + l) * 1024,
            Kb + ((size_t)bh * Tn + k0 + kr) * DHn + kc * 8);
      int vr = ci >> 3, vc = (ci & 7) ^ (vr & 7);
      gld16((char*)Vs[buf] + (w * 4 + l) * 1024,
            Vt + ((size_t)bh * DHn + vr) * Tn + k0 + vc * 8);
    }
  };

  stage(0, 0);

  for (int kt = 0; kt <= kmax; ++kt) {
    __syncthreads();
    if (kt < kmax) stage((kt + 1) & 1, kt + 1);
    const bf16_t* ks = Ks[kt & 1];
    const bf16_t* vs = Vs[kt & 1];
    const bool actA = (kt <= iA);
    const int k0 = kt * 64;

    f32x4 saA[4] = {}, saB[4] = {};
    __builtin_amdgcn_s_setprio(1);
    if (actA) {
#pragma unroll
      for (int s = 0; s < 4; ++s) {
#pragma unroll
        for (int n = 0; n < 4; ++n) {
          bf16x8 bk = *(const bf16x8*)&ks[(n * 16 + q) * 128 + (((s * 4 + g) ^ (q & 7)) * 8)];
          saA[n] = __builtin_amdgcn_mfma_f32_16x16x32_bf16(aqA[s], bk, saA[n], 0, 0, 0);
          saB[n] = __builtin_amdgcn_mfma_f32_16x16x32_bf16(aqB[s], bk, saB[n], 0, 0, 0);
        }
      }
    } else {
#pragma unroll
      for (int s = 0; s < 4; ++s) {
#pragma unroll
        for (int n = 0; n < 4; ++n) {
          bf16x8 bk = *(const bf16x8*)&ks[(n * 16 + q) * 128 + (((s * 4 + g) ^ (q & 7)) * 8)];
          saB[n] = __builtin_amdgcn_mfma_f32_16x16x32_bf16(aqB[s], bk, saB[n], 0, 0, 0);
        }
      }
    }
    __builtin_amdgcn_s_setprio(0);

    bf16x8 paA[2], paB[2];
    auto softmax_p = [&](f32x4* sa, float* mst, float* lst, int itile,
                         bf16x8* pa, int qrow) {
      if (kt == itile) {
#pragma unroll
        for (int n = 0; n < 4; ++n)
#pragma unroll
          for (int j = 0; j < 4; ++j) {
            int kc = k0 + n * 16 + q;
            int qr = qrow + g * 4 + j;
            if (kc > qr) sa[n][j] = -1e30f;
          }
      }
      float mx[4];
#pragma unroll
      for (int j = 0; j < 4; ++j) {
        mx[j] = fmaxf(fmaxf(sa[0][j], sa[1][j]), fmaxf(sa[2][j], sa[3][j]));
#pragma unroll
        for (int off = 1; off < 16; off <<= 1)
          mx[j] = fmaxf(mx[j], __shfl_xor(mx[j], off, 16));
      }
      float ps[4][4], rsum[4];
#pragma unroll
      for (int j = 0; j < 4; ++j) rsum[j] = 0.0f;
      float mnew[4], corr[4];
#pragma unroll
      for (int j = 0; j < 4; ++j) {
        mnew[j] = fmaxf(mst[j], mx[j]);
        corr[j] = exp2f((mst[j] - mnew[j]) * LOG2E);
      }
#pragma unroll
      for (int n = 0; n < 4; ++n)
#pragma unroll
        for (int j = 0; j < 4; ++j) {
          ps[n][j] = exp2f((sa[n][j] - mnew[j]) * LOG2E);
          rsum[j] += ps[n][j];
        }
#pragma unroll
      for (int j = 0; j < 4; ++j) {
#pragma unroll
        for (int off = 1; off < 16; off <<= 1)
          rsum[j] += __shfl_xor(rsum[j], off, 16);
        lst[j] = lst[j] * corr[j] + rsum[j];
        mst[j] = mnew[j];
      }
#pragma unroll
      for (int n = 0; n < 4; ++n)
#pragma unroll
        for (int j = 0; j < 4; ++j)
          Ps[w][(g * 4 + j) * 72 + n * 16 + q] = (bf16_t)ps[n][j];
#pragma unroll
      for (int s2 = 0; s2 < 2; ++s2)
        pa[s2] = *(const bf16x8*)&Ps[w][q * 72 + s2 * 32 + g * 8];
      return corr;
    };

    float cA[4], cB[4];
    if (actA) {
      auto c = softmax_p(saA, mA, lA, iA, paA, iA * 64 + w * 16);
#pragma unroll
      for (int j = 0; j < 4; ++j) cA[j] = c[j];
#pragma unroll
      for (int n8 = 0; n8 < 8; ++n8)
#pragma unroll
        for (int j = 0; j < 4; ++j) oA[n8][j] *= cA[j];
    }
    {
      auto c = softmax_p(saB, mB, lB, iB, paB, iB * 64 + w * 16);
#pragma unroll
      for (int j = 0; j < 4; ++j) cB[j] = c[j];
#pragma unroll
      for (int n8 = 0; n8 < 8; ++n8)
#pragma unroll
        for (int j = 0; j < 4; ++j) oB[n8][j] *= cB[j];
    }

    __builtin_amdgcn_s_setprio(1);
    if (actA) {
#pragma unroll
      for (int s2 = 0; s2 < 2; ++s2)
#pragma unroll
        for (int n8 = 0; n8 < 8; ++n8) {
          bf16x8 bv = *(const bf16x8*)&vs[(n8 * 16 + q) * 64 + (((s2 * 4 + g) ^ (q & 7)) * 8)];
          oA[n8] = __builtin_amdgcn_mfma_f32_16x16x32_bf16(paA[s2], bv, oA[n8], 0, 0, 0);
          oB[n8] = __builtin_amdgcn_mfma_f32_16x16x32_bf16(paB[s2], bv, oB[n8], 0, 0, 0);
        }
    } else {
#pragma unroll
      for (int s2 = 0; s2 < 2; ++s2)
#pragma unroll
        for (int n8 = 0; n8 < 8; ++n8) {
          bf16x8 bv = *(const bf16x8*)&vs[(n8 * 16 + q) * 64 + (((s2 * 4 + g) ^ (q & 7)) * 8)];
          oB[n8] = __builtin_amdgcn_mfma_f32_16x16x32_bf16(paB[s2], bv, oB[n8], 0, 0, 0);
        }
    }
    __builtin_amdgcn_s_setprio(0);
  }

#pragma unroll
  for (int n8 = 0; n8 < 8; ++n8)
#pragma unroll
    for (int j = 0; j < 4; ++j) {
      int trA = iA * 64 + w * 16 + g * 4 + j;
      int trB = iB * 64 + w * 16 + g * 4 + j;
      Y[(size_t)(b * Tn + trA) * Dn + hh * DHn + n8 * 16 + q] =
          (bf16_t)(oA[n8][j] / lA[j]);
      Y[(size_t)(b * Tn + trB) * Dn + hh * DHn + n8 * 16 + q] =
          (bf16_t)(oB[n8][j] / lB[j]);
    }
}

// ---------------- launcher ----------------
extern "C" void kernel_launch(void* const* d_in, const int* in_sizes, int n_in,
                              void* d_out, int out_size, void* d_ws, size_t ws_size,
                              hipStream_t stream) {
  const float* x      = (const float*)d_in[0];
  const float* n1w    = (const float*)d_in[1];
  const float* n2w    = (const float*)d_in[2];
  const float* attn_w = (const float*)d_in[3];
  const float* proj_w = (const float*)d_in[4];
  const float* gate_w = (const float*)d_in[5];
  const float* val_w  = (const float*)d_in[6];
  const float* mlp_w  = (const float*)d_in[7];

  char* ws = (char*)d_ws;
  bf16_t* h    = (bf16_t*)(ws);                  // 16.78MB
  bf16_t* bufA = (bf16_t*)(ws + 16777216);       // 50.3MB
  bf16_t* bufB = (bf16_t*)(ws + 67108864);       // 50.3MB
  bf16_t* wb   = (bf16_t*)(ws + 117440512);      // 25.2MB

  bf16_t* qkv  = bufA;
  bf16_t* wbV  = bufA;   // val weights (bufA free after rope)
  bf16_t* Qb   = bufB;
  bf16_t* Kb   = Qb + (size_t)32 * Tn * DHn;
  bf16_t* Vt   = Kb + (size_t)32 * Tn * DHn;
  bf16_t* gv   = bufB;   // gate*val output (bufB free after attn)
  bf16_t* y    = h;
  bf16_t* P0   = h;      // split-K partial 0 (h free after gemmgv)
  bf16_t* P1   = bufA;   // split-K partial 1 (bufA free after gemmgv)
  float*  out  = (float*)d_out;

  // 1) h1 = rmsnorm(x)
  rmsnorm_k<<<BTn, 256, 0, stream>>>(x, n1w, h);
  // 2) qkv = h1 @ attn_w^T   (BK=64 structure)
  cvt_pad_k<<<(TD3 * Dn / 8 + 255) / 256, 256, 0, stream>>>(attn_w, wb, TD3, Dn, Dn, TD3 * Dn / 8);
  gemm64<0><<<(TD3 / 256) * (BTn / 256), 512, 0, stream>>>(h, wb, (void*)qkv, nullptr, Dn, TD3, BTn / 256);
  // 3) rope + split + V^T
  rope_k<<<dim3(Tn / 32, 32), 256, 0, stream>>>(qkv, Qb, Kb, Vt);
  // 4) attention -> y
  attn_k<<<dim3(16, 32), 256, 0, stream>>>(Qb, Kb, Vt, y);
  // 5) x1 = x + y @ proj_w^T  (fp32, into d_out; BK=32 gemm256 for 2/CU)
  cvt_pad_k<<<(Dn * Dn / 8 + 255) / 256, 256, 0, stream>>>(proj_w, wb, Dn, Dn, Dn, Dn * Dn / 8);
  gemm256<1><<<(Dn / 256) * (BTn / 256), 512, 0, stream>>>(y, wb, (void*)out, (const void*)x, BTn, Dn, Dn, Dn, BTn / 256);
  // 6) h2 = rmsnorm(x1)
  rmsnorm_k<<<BTn, 256, 0, stream>>>(out, n2w, h);
  // 7+8) gv = silu(h2 @ gate_w^T) * (h2 @ val_w^T)  (BK=64 dual)
  cvt_pad_k<<<(FGPn * Dn / 8 + 255) / 256, 256, 0, stream>>>(gate_w, wb, FGn, Dn, Dn, FGPn * Dn / 8);
  cvt_pad_k<<<(FGPn * Dn / 8 + 255) / 256, 256, 0, stream>>>(val_w, wbV, FGn, Dn, Dn, FGPn * Dn / 8);
  gemmgv<<<(FGPn / 128) * (BTn / 256), 512, 0, stream>>>(h, wb, wbV, gv, Dn, FGPn, BTn / 256);
  // 9) mlp split-K=2 (BK=64): P0/P1 = gv[:, s*2752:] @ mlp_w[:, s*2752:]^T
  cvt_pad_k<<<(Dn * FGPn / 8 + 255) / 256, 256, 0, stream>>>(mlp_w, wb, Dn, FGn, FGPn, Dn * FGPn / 8);
  gemm_sk<<<256, 512, 0, stream>>>(gv, wb, P0, P1, FGPn, FGPn / 2, Dn);
  // 10) out += P0 + P1
  reduce_k<<<BTn * Dn / 8 / 256, 256, 0, stream>>>(out, P0, P1);
}

// Round 15
// 730.185 us; speedup vs baseline: 1.3483x; 1.0212x over previous
//
#include <hip/hip_runtime.h>
#include <hip/hip_bf16.h>
#include <stdint.h>

typedef __bf16 bf16_t;
typedef __bf16 bf16x8 __attribute__((ext_vector_type(8)));
typedef float  f32x4  __attribute__((ext_vector_type(4)));

#define DEV __device__ __forceinline__

constexpr int   Bn = 2, Tn = 2048, Dn = 2048, Hn = 16, DHn = 128;
constexpr int   BTn = Bn * Tn;          // 4096 rows
constexpr int   TD3 = 3 * Dn;           // 6144
constexpr int   FGn = 5461, FGPn = 5504; // pad to 43*128 (688 blocks, %8==0)
constexpr float EPSf   = 1e-5f;
constexpr float LOG2E  = 1.4426950408889634f;
constexpr float ASCALE = 0.08838834764831845f;   // 1/sqrt(128)
constexpr float LN1E4  = 9.210340371976184f;     // ln(10000)

// async global->LDS, 16B per lane, wave-uniform LDS base
DEV void gld16(void* lds, const void* g) {
  __builtin_amdgcn_global_load_lds(
      (__attribute__((address_space(1))) void*)(void*)g,
      (__attribute__((address_space(3))) void*)lds, 16, 0, 0);
}

// inline-asm LDS read, ordered only by explicit s_waitcnt lgkmcnt(N)
DEV bf16x8 dsr128(const bf16_t* p) {
  bf16x8 r;
  asm volatile("ds_read_b128 %0, %1"
               : "=v"(r)
               : "v"((const __attribute__((address_space(3))) bf16_t*)p));
  return r;
}

// ---------------- RMSNorm (fp32 in -> bf16 out) ----------------
__global__ __launch_bounds__(256)
void rmsnorm_k(const float* __restrict__ x, const float* __restrict__ w,
               bf16_t* __restrict__ out) {
  const int row = blockIdx.x;
  const int tid = threadIdx.x;
  const float* xr = x + (size_t)row * Dn;
  float4 a = ((const float4*)xr)[tid * 2];
  float4 b = ((const float4*)xr)[tid * 2 + 1];
  float ss = a.x*a.x + a.y*a.y + a.z*a.z + a.w*a.w
           + b.x*b.x + b.y*b.y + b.z*b.z + b.w*b.w;
#pragma unroll
  for (int off = 32; off > 0; off >>= 1) ss += __shfl_xor(ss, off, 64);
  __shared__ float red[4];
  if ((tid & 63) == 0) red[tid >> 6] = ss;
  __syncthreads();
  float tot = red[0] + red[1] + red[2] + red[3];
  float rms = rsqrtf(tot * (1.0f / Dn) + EPSf);
  float4 wa = ((const float4*)w)[tid * 2];
  float4 wb = ((const float4*)w)[tid * 2 + 1];
  bf16x8 o;
  o[0] = (bf16_t)(a.x * rms * wa.x); o[1] = (bf16_t)(a.y * rms * wa.y);
  o[2] = (bf16_t)(a.z * rms * wa.z); o[3] = (bf16_t)(a.w * rms * wa.w);
  o[4] = (bf16_t)(b.x * rms * wb.x); o[5] = (bf16_t)(b.y * rms * wb.y);
  o[6] = (bf16_t)(b.z * rms * wb.z); o[7] = (bf16_t)(b.w * rms * wb.w);
  *(bf16x8*)&out[(size_t)row * Dn + tid * 8] = o;
}

// ---------------- fp32 -> bf16 convert with zero padding ----------------
__global__ __launch_bounds__(256)
void cvt_pad_k(const float* __restrict__ src, bf16_t* __restrict__ dst,
               int srcR, int srcC, int dstC, int n8) {
  int i = blockIdx.x * 256 + threadIdx.x;
  if (i >= n8) return;
  long base = (long)i * 8;
  int r = (int)(base / dstC);
  int c = (int)(base % dstC);
  bf16x8 o;
#pragma unroll
  for (int k = 0; k < 8; ++k) {
    int cc = c + k;
    float v = (r < srcR && cc < srcC) ? src[(size_t)r * srcC + cc] : 0.0f;
    o[k] = (bf16_t)v;
  }
  *(bf16x8*)&dst[base] = o;
}

// ------------- reduce: out += P0 + P1 (mlp epilogue) ---------------------
__global__ __launch_bounds__(256)
void reduce_k(float* __restrict__ out, const bf16_t* __restrict__ P0,
              const bf16_t* __restrict__ P1) {
  int i = blockIdx.x * 256 + threadIdx.x;
  bf16x8 p0 = *(const bf16x8*)&P0[(size_t)i * 8];
  bf16x8 p1 = *(const bf16x8*)&P1[(size_t)i * 8];
  float4 o0 = ((const float4*)out)[i * 2];
  float4 o1 = ((const float4*)out)[i * 2 + 1];
  o0.x += (float)p0[0] + (float)p1[0];
  o0.y += (float)p0[1] + (float)p1[1];
  o0.z += (float)p0[2] + (float)p1[2];
  o0.w += (float)p0[3] + (float)p1[3];
  o1.x += (float)p0[4] + (float)p1[4];
  o1.y += (float)p0[5] + (float)p1[5];
  o1.z += (float)p0[6] + (float)p1[6];
  o1.w += (float)p0[7] + (float)p1[7];
  ((float4*)out)[i * 2]     = o0;
  ((float4*)out)[i * 2 + 1] = o1;
}

// ------------- reduce: out = E + P0 + P1 (proj epilogue, fp32 resid) -----
__global__ __launch_bounds__(256)
void reduce2e(float* __restrict__ out, const float* __restrict__ E,
              const bf16_t* __restrict__ P0, const bf16_t* __restrict__ P1) {
  int i = blockIdx.x * 256 + threadIdx.x;
  bf16x8 p0 = *(const bf16x8*)&P0[(size_t)i * 8];
  bf16x8 p1 = *(const bf16x8*)&P1[(size_t)i * 8];
  float4 e0 = ((const float4*)E)[i * 2];
  float4 e1 = ((const float4*)E)[i * 2 + 1];
  float4 o0, o1;
  o0.x = e0.x + (float)p0[0] + (float)p1[0];
  o0.y = e0.y + (float)p0[1] + (float)p1[1];
  o0.z = e0.z + (float)p0[2] + (float)p1[2];
  o0.w = e0.w + (float)p0[3] + (float)p1[3];
  o1.x = e1.x + (float)p0[4] + (float)p1[4];
  o1.y = e1.y + (float)p0[5] + (float)p1[5];
  o1.z = e1.z + (float)p0[6] + (float)p1[6];
  o1.w = e1.w + (float)p0[7] + (float)p1[7];
  ((float4*)out)[i * 2]     = o0;
  ((float4*)out)[i * 2 + 1] = o1;
}

// ------------- reduce: outb = bf16(P0 + P1) (qkv epilogue) ---------------
// In-place safe when outb aliases P1 (each thread reads then writes its own 16B).
__global__ __launch_bounds__(256)
void reduce2b(bf16_t* __restrict__ outb, const bf16_t* __restrict__ P0,
              const bf16_t* __restrict__ P1) {
  int i = blockIdx.x * 256 + threadIdx.x;
  bf16x8 p0 = *(const bf16x8*)&P0[(size_t)i * 8];
  bf16x8 p1 = *(const bf16x8*)&P1[(size_t)i * 8];
  bf16x8 o;
#pragma unroll
  for (int k = 0; k < 8; ++k) o[k] = (bf16_t)((float)p0[k] + (float)p1[k]);
  *(bf16x8*)&outb[(size_t)i * 8] = o;
}

// -------- split-K=2 GEMM, BK=64 2-slot (best measured: ~5860 cyc/K64) ----
// Parametrized: grid = 2*half blocks (%8==0); per-half tiles = (N/256)x(M/256),
// col-major flatten with nby = M/256. P[s] = A[:, s*klen:] @ W[:, s*klen:]^T.
// 128KB LDS, 1/CU. Per K64 step: {12 ds_read ; 4 gld ; lgkm(0) ; 32 MFMA} x2 ;
// vmcnt(0) ; barrier. LDS: chunk16(r, c in[0,8)) at byte r*128 + ((c^(r&7))*16).
__global__ __launch_bounds__(512, 2)
void gemm_sk(const bf16_t* __restrict__ A, const bf16_t* __restrict__ W,
             bf16_t* __restrict__ P0, bf16_t* __restrict__ P1,
             int ldk, int klen, int ldc, int nby) {
  __shared__ __align__(128) bf16_t As[2][256 * 64];   // 2 x 32KB
  __shared__ __align__(128) bf16_t Bs[2][256 * 64];   // 2 x 32KB
  const int tid = threadIdx.x;
  const int lane = tid & 63, w = tid >> 6;
  const int wm = w >> 2, wn = w & 3;
  const int g = lane >> 4, q = lane & 15;

  const int nwg = gridDim.x;               // % 8 == 0
  const int cpx = nwg >> 3;
  const int nid = (blockIdx.x & 7) * cpx + (blockIdx.x >> 3);
  const int half = nwg >> 1;
  const int s   = nid / half;
  const int rem = nid % half;
  const int bx = rem / nby, by = rem % nby;
  const int row0 = by * 256, col0 = bx * 256;
  const int kofs = s * klen;
  bf16_t* P = s ? P1 : P0;

  f32x4 acc[8][4] = {};

  const bf16_t* Asrc[4];
  const bf16_t* Wsrc[4];
  int aoff[4];
#pragma unroll
  for (int i = 0; i < 4; ++i) {
    int ci = i * 512 + tid;
    int r  = ci >> 3;
    int cs = (ci & 7) ^ (r & 7);
    Asrc[i] = A + (size_t)(row0 + r) * ldk + kofs + cs * 8;
    Wsrc[i] = W + (size_t)(col0 + r) * ldk + kofs + cs * 8;
    aoff[i] = i * 8192 + w * 1024;
  }

  int offA[2][8], offB[2][4];
#pragma unroll
  for (int kk = 0; kk < 2; ++kk) {
#pragma unroll
    for (int m = 0; m < 8; ++m) {
      int r = wm * 128 + m * 16 + q;
      offA[kk][m] = r * 128 + (((kk * 4 + g) ^ (r & 7)) * 16);
    }
#pragma unroll
    for (int n = 0; n < 4; ++n) {
      int r = wn * 64 + n * 16 + q;
      offB[kk][n] = r * 128 + (((kk * 4 + g) ^ (r & 7)) * 16);
    }
  }

  const int NT = klen >> 6;
  auto stage = [&](int T, int h) {
    const int slot = T & 1;
    const size_t kk = (size_t)T * 64;
#pragma unroll
    for (int i = 0; i < 2; ++i) {
      int rd = h * 2 + i;
      gld16((char*)As[slot] + aoff[rd], Asrc[rd] + kk);
      gld16((char*)Bs[slot] + aoff[rd], Wsrc[rd] + kk);
    }
  };

  bf16x8 af[8], bfr[4];

  auto half_rd = [&](const char* as_, const char* bs_, int kk) {
#pragma unroll
    for (int m = 0; m < 8; ++m) af[m] = dsr128((const bf16_t*)(as_ + offA[kk][m]));
#pragma unroll
    for (int n = 0; n < 4; ++n) bfr[n] = dsr128((const bf16_t*)(bs_ + offB[kk][n]));
  };
  auto mfmas = [&]() {
    asm volatile("s_waitcnt lgkmcnt(0)" ::: "memory");
    __builtin_amdgcn_sched_barrier(0);
    __builtin_amdgcn_s_setprio(1);
#pragma unroll
    for (int m = 0; m < 8; ++m)
#pragma unroll
      for (int n = 0; n < 4; ++n)
        acc[m][n] = __builtin_amdgcn_mfma_f32_16x16x32_bf16(af[m], bfr[n], acc[m][n], 0, 0, 0);
    __builtin_amdgcn_s_setprio(0);
    __builtin_amdgcn_sched_barrier(0);
  };

  stage(0, 0); stage(0, 1);
  asm volatile("s_waitcnt vmcnt(0)" ::: "memory");
  asm volatile("s_barrier" ::: "memory");

  for (int T = 0; T < NT; ++T) {
    const char* as_ = (const char*)As[T & 1];
    const char* bs_ = (const char*)Bs[T & 1];
    const bool st = (T + 1 < NT);
    half_rd(as_, bs_, 0);
    if (st) stage(T + 1, 0);
    mfmas();
    half_rd(as_, bs_, 1);
    if (st) stage(T + 1, 1);
    mfmas();
    if (st) asm volatile("s_waitcnt vmcnt(0)" ::: "memory");
    asm volatile("s_barrier" ::: "memory");
  }

#pragma unroll
  for (int m = 0; m < 8; ++m)
#pragma unroll
    for (int n = 0; n < 4; ++n)
#pragma unroll
      for (int j = 0; j < 4; ++j) {
        int r = row0 + wm * 128 + m * 16 + g * 4 + j;
        int c = col0 + wn * 64 + n * 16 + q;
        P[(size_t)r * ldc + c] = (bf16_t)acc[m][n][j];
      }
}

// ------- fused gate+val dual GEMM, BK=64: Out = silu(A Wg^T)*(A Wv^T) -----
// (R14 exact: 164us, MfmaUtil 51%)
__global__ __launch_bounds__(512, 2)
void gemmgv(const bf16_t* __restrict__ A, const bf16_t* __restrict__ Wg,
            const bf16_t* __restrict__ Wv, bf16_t* __restrict__ Out,
            int K, int ldc, int nby) {
  __shared__ __align__(128) bf16_t As[2][256 * 64];   // 2 x 32KB
  __shared__ __align__(128) bf16_t Gs[2][128 * 64];   // 2 x 16KB
  __shared__ __align__(128) bf16_t Vs[2][128 * 64];   // 2 x 16KB
  const int tid = threadIdx.x;
  const int lane = tid & 63, w = tid >> 6;
  const int wm = w >> 2, wn = w & 3;
  const int g = lane >> 4, q = lane & 15;

  const int nwg = gridDim.x;                 // 688, % 8 == 0
  const int cpx = nwg >> 3;
  const int nid = (blockIdx.x & 7) * cpx + (blockIdx.x >> 3);
  const int bx = nid / nby, by = nid % nby;
  const int row0 = by * 256, col0 = bx * 128;

  f32x4 accg[8][2] = {}, accv[8][2] = {};

  const bf16_t* Asrc[4];
  int aoff[4];
#pragma unroll
  for (int i = 0; i < 4; ++i) {
    int ci = i * 512 + tid;
    int r  = ci >> 3;
    int cs = (ci & 7) ^ (r & 7);
    Asrc[i] = A + (size_t)(row0 + r) * K + cs * 8;
    aoff[i] = i * 8192 + w * 1024;
  }
  const bf16_t* Gsrc[2];
  const bf16_t* Vsrc[2];
  int boff[2];
#pragma unroll
  for (int i = 0; i < 2; ++i) {
    int ci = i * 512 + tid;
    int r  = ci >> 3;
    int cs = (ci & 7) ^ (r & 7);
    Gsrc[i] = Wg + (size_t)(col0 + r) * K + cs * 8;
    Vsrc[i] = Wv + (size_t)(col0 + r) * K + cs * 8;
    boff[i] = i * 8192 + w * 1024;
  }

  int offA[2][8], offB[2][2];
#pragma unroll
  for (int kk = 0; kk < 2; ++kk) {
#pragma unroll
    for (int m = 0; m < 8; ++m) {
      int r = wm * 128 + m * 16 + q;
      offA[kk][m] = r * 128 + (((kk * 4 + g) ^ (r & 7)) * 16);
    }
#pragma unroll
    for (int n = 0; n < 2; ++n) {
      int r = wn * 32 + n * 16 + q;
      offB[kk][n] = r * 128 + (((kk * 4 + g) ^ (r & 7)) * 16);
    }
  }

  const int NT = K >> 6;                 // 32
  auto stage = [&](int T, int h) {
    const int slot = T & 1;
    const size_t kk = (size_t)T * 64;
#pragma unroll
    for (int i = 0; i < 2; ++i) {
      int rd = h * 2 + i;
      gld16((char*)As[slot] + aoff[rd], Asrc[rd] + kk);
    }
    gld16((char*)Gs[slot] + boff[h], Gsrc[h] + kk);
    gld16((char*)Vs[slot] + boff[h], Vsrc[h] + kk);
  };

  bf16x8 af[8], bg[2], bv[2];

  auto half_rd = [&](const char* as_, const char* gs_, const char* vs_, int kk) {
#pragma unroll
    for (int m = 0; m < 8; ++m) af[m] = dsr128((const bf16_t*)(as_ + offA[kk][m]));
#pragma unroll
    for (int n = 0; n < 2; ++n) {
      bg[n] = dsr128((const bf16_t*)(gs_ + offB[kk][n]));
      bv[n] = dsr128((const bf16_t*)(vs_ + offB[kk][n]));
    }
  };
  auto mfmas = [&]() {
    asm volatile("s_waitcnt lgkmcnt(0)" ::: "memory");
    __builtin_amdgcn_sched_barrier(0);
    __builtin_amdgcn_s_setprio(1);
#pragma unroll
    for (int m = 0; m < 8; ++m)
#pragma unroll
      for (int n = 0; n < 2; ++n) {
        accg[m][n] = __builtin_amdgcn_mfma_f32_16x16x32_bf16(af[m], bg[n], accg[m][n], 0, 0, 0);
        accv[m][n] = __builtin_amdgcn_mfma_f32_16x16x32_bf16(af[m], bv[n], accv[m][n], 0, 0, 0);
      }
    __builtin_amdgcn_s_setprio(0);
    __builtin_amdgcn_sched_barrier(0);
  };

  stage(0, 0); stage(0, 1);
  asm volatile("s_waitcnt vmcnt(0)" ::: "memory");
  asm volatile("s_barrier" ::: "memory");

  for (int T = 0; T < NT; ++T) {
    const char* as_ = (const char*)As[T & 1];
    const char* gs_ = (const char*)Gs[T & 1];
    const char* vs_ = (const char*)Vs[T & 1];
    const bool st = (T + 1 < NT);
    half_rd(as_, gs_, vs_, 0);
    if (st) stage(T + 1, 0);
    mfmas();
    half_rd(as_, gs_, vs_, 1);
    if (st) stage(T + 1, 1);
    mfmas();
    if (st) asm volatile("s_waitcnt vmcnt(0)" ::: "memory");
    asm volatile("s_barrier" ::: "memory");
  }

#pragma unroll
  for (int m = 0; m < 8; ++m) {
#pragma unroll
    for (int n = 0; n < 2; ++n) {
#pragma unroll
      for (int j = 0; j < 4; ++j) {
        int r = row0 + wm * 128 + m * 16 + g * 4 + j;
        int c = col0 + wn * 32 + n * 16 + q;
        float gt = accg[m][n][j];
        float sg = gt / (1.0f + __expf(-gt));
        Out[(size_t)r * ldc + c] = (bf16_t)(sg * accv[m][n][j]);
      }
    }
  }
}

// ---------------- RoPE + split + V transpose ----------------
__global__ __launch_bounds__(256)
void rope_k(const bf16_t* __restrict__ qkv, bf16_t* __restrict__ Qb,
            bf16_t* __restrict__ Kb, bf16_t* __restrict__ Vt) {
  const int t0 = blockIdx.x * 32;
  const int bh = blockIdx.y;
  const int b = bh >> 4, hh = bh & 15;
  __shared__ bf16_t Vl[32][132];

#pragma unroll
  for (int it = 0; it < 2; ++it) {
    int task = threadIdx.x + it * 256;
    int tt = task >> 4, ck = task & 15, d0 = ck * 8;
    int tg = t0 + tt;
    const bf16_t* srow = qkv + (size_t)(b * Tn + tg) * TD3 + hh * DHn + d0;
    bf16x8 qv = *(const bf16x8*)(srow);
    bf16x8 kv = *(const bf16x8*)(srow + Dn);
    bf16x8 vv = *(const bf16x8*)(srow + 2 * Dn);
    bf16x8 qo, ko;
#pragma unroll
    for (int p = 0; p < 4; ++p) {
      int jj = (d0 >> 1) + p;
      float fr = __expf(-((float)(2 * jj) / 128.0f) * LN1E4);
      float ang = (float)tg * fr;
      float cs = cosf(ang), sn = sinf(ang);
      float qe = (float)qv[2 * p], qod = (float)qv[2 * p + 1];
      float ke = (float)kv[2 * p], kod = (float)kv[2 * p + 1];
      qo[2 * p]     = (bf16_t)((qe * cs - qod * sn) * ASCALE);
      qo[2 * p + 1] = (bf16_t)((qod * cs + qe * sn) * ASCALE);
      ko[2 * p]     = (bf16_t)(ke * cs - kod * sn);
      ko[2 * p + 1] = (bf16_t)(kod * cs + ke * sn);
    }
    *(bf16x8*)&Qb[((size_t)bh * Tn + tg) * DHn + d0] = qo;
    *(bf16x8*)&Kb[((size_t)bh * Tn + tg) * DHn + d0] = ko;
    *(bf16x8*)&Vl[tt][d0] = vv;
  }
  __syncthreads();
#pragma unroll
  for (int it = 0; it < 2; ++it) {
    int task = threadIdx.x + it * 256;
    int dd = task >> 2, tc = (task & 3) * 8;
    bf16x8 ov;
#pragma unroll
    for (int i = 0; i < 8; ++i) ov[i] = Vl[tc + i][dd];
    *(bf16x8*)&Vt[((size_t)bh * DHn + dd) * Tn + t0 + tc] = ov;
  }
}

// ---------------- causal flash attention, paired q-tiles ----------------
__global__ __launch_bounds__(256, 2)
void attn_k(const bf16_t* __restrict__ Qb, const bf16_t* __restrict__ Kb,
            const bf16_t* __restrict__ Vt, bf16_t* __restrict__ Y) {
  const int orig = blockIdx.x + 16 * blockIdx.y;   // 512 blocks total
  const int nid  = (orig & 7) * 64 + (orig >> 3);  // XCD-chunked, bijective
  const int pi = nid & 15;
  const int bh = nid >> 4;
  const int b = bh >> 4, hh = bh & 15;
  const int tid = threadIdx.x, lane = tid & 63, w = tid >> 6;
  const int g = lane >> 4, q = lane & 15;
  const int iA = pi, iB = 31 - pi;
  const int kmax = iB;

  __shared__ bf16_t Ks[2][64 * 128];
  __shared__ bf16_t Vs[2][128 * 64];
  __shared__ bf16_t Ps[4][16 * 72];

  bf16x8 aqA[4], aqB[4];
  {
    const bf16_t* QrA = Qb + ((size_t)bh * Tn + iA * 64 + w * 16 + q) * DHn;
    const bf16_t* QrB = Qb + ((size_t)bh * Tn + iB * 64 + w * 16 + q) * DHn;
#pragma unroll
    for (int s = 0; s < 4; ++s) {
      aqA[s] = *(const bf16x8*)(QrA + s * 32 + g * 8);
      aqB[s] = *(const bf16x8*)(QrB + s * 32 + g * 8);
    }
  }

  f32x4 oA[8] = {}, oB[8] = {};
  float mA[4], lA[4], mB[4], lB[4];
#pragma unroll
  for (int j = 0; j < 4; ++j) {
    mA[j] = -__builtin_inff(); lA[j] = 0.0f;
    mB[j] = -__builtin_inff(); lB[j] = 0.0f;
  }

  auto stage = [&](int buf, int kt) {
    const int k0 = kt * 64;
#pragma unroll
    for (int l = 0; l < 4; ++l) {
      int ci = (w * 4 + l) * 64 + lane;
      int kr = ci >> 4, kc = (ci & 15) ^ (kr & 7);
      gld16((char*)Ks[buf] + (w * 4 + l) * 1024,
            Kb + ((size_t)bh * Tn + k0 + kr) * DHn + kc * 8);
      int vr = ci >> 3, vc = (ci & 7) ^ (vr & 7);
      gld16((char*)Vs[buf] + (w * 4 + l) * 1024,
            Vt + ((size_t)bh * DHn + vr) * Tn + k0 + vc * 8);
    }
  };

  stage(0, 0);

  for (int kt = 0; kt <= kmax; ++kt) {
    __syncthreads();
    if (kt < kmax) stage((kt + 1) & 1, kt + 1);
    const bf16_t* ks = Ks[kt & 1];
    const bf16_t* vs = Vs[kt & 1];
    const bool actA = (kt <= iA);
    const int k0 = kt * 64;

    f32x4 saA[4] = {}, saB[4] = {};
    __builtin_amdgcn_s_setprio(1);
    if (actA) {
#pragma unroll
      for (int s = 0; s < 4; ++s) {
#pragma unroll
        for (int n = 0; n < 4; ++n) {
          bf16x8 bk = *(const bf16x8*)&ks[(n * 16 + q) * 128 + (((s * 4 + g) ^ (q & 7)) * 8)];
          saA[n] = __builtin_amdgcn_mfma_f32_16x16x32_bf16(aqA[s], bk, saA[n], 0, 0, 0);
          saB[n] = __builtin_amdgcn_mfma_f32_16x16x32_bf16(aqB[s], bk, saB[n], 0, 0, 0);
        }
      }
    } else {
#pragma unroll
      for (int s = 0; s < 4; ++s) {
#pragma unroll
        for (int n = 0; n < 4; ++n) {
          bf16x8 bk = *(const bf16x8*)&ks[(n * 16 + q) * 128 + (((s * 4 + g) ^ (q & 7)) * 8)];
          saB[n] = __builtin_amdgcn_mfma_f32_16x16x32_bf16(aqB[s], bk, saB[n], 0, 0, 0);
        }
      }
    }
    __builtin_amdgcn_s_setprio(0);

    bf16x8 paA[2], paB[2];
    auto softmax_p = [&](f32x4* sa, float* mst, float* lst, int itile,
                         bf16x8* pa, int qrow) {
      if (kt == itile) {
#pragma unroll
        for (int n = 0; n < 4; ++n)
#pragma unroll
          for (int j = 0; j < 4; ++j) {
            int kc = k0 + n * 16 + q;
            int qr = qrow + g * 4 + j;
            if (kc > qr) sa[n][j] = -1e30f;
          }
      }
      float mx[4];
#pragma unroll
      for (int j = 0; j < 4; ++j) {
        mx[j] = fmaxf(fmaxf(sa[0][j], sa[1][j]), fmaxf(sa[2][j], sa[3][j]));
#pragma unroll
        for (int off = 1; off < 16; off <<= 1)
          mx[j] = fmaxf(mx[j], __shfl_xor(mx[j], off, 16));
      }
      float ps[4][4], rsum[4];
#pragma unroll
      for (int j = 0; j < 4; ++j) rsum[j] = 0.0f;
      float mnew[4], corr[4];
#pragma unroll
      for (int j = 0; j < 4; ++j) {
        mnew[j] = fmaxf(mst[j], mx[j]);
        corr[j] = exp2f((mst[j] - mnew[j]) * LOG2E);
      }
#pragma unroll
      for (int n = 0; n < 4; ++n)
#pragma unroll
        for (int j = 0; j < 4; ++j) {
          ps[n][j] = exp2f((sa[n][j] - mnew[j]) * LOG2E);
          rsum[j] += ps[n][j];
        }
#pragma unroll
      for (int j = 0; j < 4; ++j) {
#pragma unroll
        for (int off = 1; off < 16; off <<= 1)
          rsum[j] += __shfl_xor(rsum[j], off, 16);
        lst[j] = lst[j] * corr[j] + rsum[j];
        mst[j] = mnew[j];
      }
#pragma unroll
      for (int n = 0; n < 4; ++n)
#pragma unroll
        for (int j = 0; j < 4; ++j)
          Ps[w][(g * 4 + j) * 72 + n * 16 + q] = (bf16_t)ps[n][j];
#pragma unroll
      for (int s2 = 0; s2 < 2; ++s2)
        pa[s2] = *(const bf16x8*)&Ps[w][q * 72 + s2 * 32 + g * 8];
      return corr;
    };

    float cA[4], cB[4];
    if (actA) {
      auto c = softmax_p(saA, mA, lA, iA, paA, iA * 64 + w * 16);
#pragma unroll
      for (int j = 0; j < 4; ++j) cA[j] = c[j];
#pragma unroll
      for (int n8 = 0; n8 < 8; ++n8)
#pragma unroll
        for (int j = 0; j < 4; ++j) oA[n8][j] *= cA[j];
    }
    {
      auto c = softmax_p(saB, mB, lB, iB, paB, iB * 64 + w * 16);
#pragma unroll
      for (int j = 0; j < 4; ++j) cB[j] = c[j];
#pragma unroll
      for (int n8 = 0; n8 < 8; ++n8)
#pragma unroll
        for (int j = 0; j < 4; ++j) oB[n8][j] *= cB[j];
    }

    __builtin_amdgcn_s_setprio(1);
    if (actA) {
#pragma unroll
      for (int s2 = 0; s2 < 2; ++s2)
#pragma unroll
        for (int n8 = 0; n8 < 8; ++n8) {
          bf16x8 bv = *(const bf16x8*)&vs[(n8 * 16 + q) * 64 + (((s2 * 4 + g) ^ (q & 7)) * 8)];
          oA[n8] = __builtin_amdgcn_mfma_f32_16x16x32_bf16(paA[s2], bv, oA[n8], 0, 0, 0);
          oB[n8] = __builtin_amdgcn_mfma_f32_16x16x32_bf16(paB[s2], bv, oB[n8], 0, 0, 0);
        }
    } else {
#pragma unroll
      for (int s2 = 0; s2 < 2; ++s2)
#pragma unroll
        for (int n8 = 0; n8 < 8; ++n8) {
          bf16x8 bv = *(const bf16x8*)&vs[(n8 * 16 + q) * 64 + (((s2 * 4 + g) ^ (q & 7)) * 8)];
          oB[n8] = __builtin_amdgcn_mfma_f32_16x16x32_bf16(paB[s2], bv, oB[n8], 0, 0, 0);
        }
    }
    __builtin_amdgcn_s_setprio(0);
  }

#pragma unroll
  for (int n8 = 0; n8 < 8; ++n8)
#pragma unroll
    for (int j = 0; j < 4; ++j) {
      int trA = iA * 64 + w * 16 + g * 4 + j;
      int trB = iB * 64 + w * 16 + g * 4 + j;
      Y[(size_t)(b * Tn + trA) * Dn + hh * DHn + n8 * 16 + q] =
          (bf16_t)(oA[n8][j] / lA[j]);
      Y[(size_t)(b * Tn + trB) * Dn + hh * DHn + n8 * 16 + q] =
          (bf16_t)(oB[n8][j] / lB[j]);
    }
}

// ---------------- launcher ----------------
extern "C" void kernel_launch(void* const* d_in, const int* in_sizes, int n_in,
                              void* d_out, int out_size, void* d_ws, size_t ws_size,
                              hipStream_t stream) {
  const float* x      = (const float*)d_in[0];
  const float* n1w    = (const float*)d_in[1];
  const float* n2w    = (const float*)d_in[2];
  const float* attn_w = (const float*)d_in[3];
  const float* proj_w = (const float*)d_in[4];
  const float* gate_w = (const float*)d_in[5];
  const float* val_w  = (const float*)d_in[6];
  const float* mlp_w  = (const float*)d_in[7];

  char* ws = (char*)d_ws;
  bf16_t* h    = (bf16_t*)(ws);                  // 16.78MB
  bf16_t* bufA = (bf16_t*)(ws + 16777216);       // 50.3MB
  bf16_t* bufB = (bf16_t*)(ws + 67108864);       // 50.3MB
  bf16_t* wb   = (bf16_t*)(ws + 117440512);      // 25.2MB

  bf16_t* Pq0  = bufB;                 // qkv partial 0 (50.3MB)
  bf16_t* Pq1  = bufA;                 // qkv partial 1; reduce2b in-place -> qkv
  bf16_t* qkv  = bufA;
  bf16_t* Qb   = bufB;
  bf16_t* Kb   = Qb + (size_t)32 * Tn * DHn;
  bf16_t* Vt   = Kb + (size_t)32 * Tn * DHn;
  bf16_t* y    = h;
  bf16_t* Pp0  = bufA;                 // proj partial 0 (16.78MB)
  bf16_t* Pp1  = bufA + (size_t)BTn * Dn;  // proj partial 1
  bf16_t* wbV  = bufA;                 // val weights (bufA free after proj reduce)
  bf16_t* gv   = bufB;                 // gate*val output (bufB free after attn)
  bf16_t* Pm0  = h;                    // mlp partial 0 (h free after gemmgv)
  bf16_t* Pm1  = bufA;                 // mlp partial 1
  float*  out  = (float*)d_out;

  // 1) h1 = rmsnorm(x)
  rmsnorm_k<<<BTn, 256, 0, stream>>>(x, n1w, h);
  // 2) qkv = h1 @ attn_w^T  (split-K=2, 768 blocks = 3 full generations)
  cvt_pad_k<<<(TD3 * Dn / 8 + 255) / 256, 256, 0, stream>>>(attn_w, wb, TD3, Dn, Dn, TD3 * Dn / 8);
  gemm_sk<<<768, 512, 0, stream>>>(h, wb, Pq0, Pq1, Dn, Dn / 2, TD3, BTn / 256);
  reduce2b<<<BTn * TD3 / 8 / 256, 256, 0, stream>>>(qkv, Pq0, Pq1);
  // 3) rope + split + V^T  (consumes qkv=bufA; overwrites bufB)
  rope_k<<<dim3(Tn / 32, 32), 256, 0, stream>>>(qkv, Qb, Kb, Vt);
  // 4) attention -> y (=h; h1 dead after qkv)
  attn_k<<<dim3(16, 32), 256, 0, stream>>>(Qb, Kb, Vt, y);
  // 5) x1 = x + y @ proj_w^T  (split-K=2, 256 blocks full-chip)
  cvt_pad_k<<<(Dn * Dn / 8 + 255) / 256, 256, 0, stream>>>(proj_w, wb, Dn, Dn, Dn, Dn * Dn / 8);
  gemm_sk<<<256, 512, 0, stream>>>(y, wb, Pp0, Pp1, Dn, Dn / 2, Dn, BTn / 256);
  reduce2e<<<BTn * Dn / 8 / 256, 256, 0, stream>>>(out, x, Pp0, Pp1);
  // 6) h2 = rmsnorm(x1)
  rmsnorm_k<<<BTn, 256, 0, stream>>>(out, n2w, h);
  // 7+8) gv = silu(h2 @ gate_w^T) * (h2 @ val_w^T)  (BK=64 dual)
  cvt_pad_k<<<(FGPn * Dn / 8 + 255) / 256, 256, 0, stream>>>(gate_w, wb, FGn, Dn, Dn, FGPn * Dn / 8);
  cvt_pad_k<<<(FGPn * Dn / 8 + 255) / 256, 256, 0, stream>>>(val_w, wbV, FGn, Dn, Dn, FGPn * Dn / 8);
  gemmgv<<<(FGPn / 128) * (BTn / 256), 512, 0, stream>>>(h, wb, wbV, gv, Dn, FGPn, BTn / 256);
  // 9) mlp split-K=2 (256 blocks): P0/P1 = gv[:, s*2752:] @ mlp_w[:, s*2752:]^T
  cvt_pad_k<<<(Dn * FGPn / 8 + 255) / 256, 256, 0, stream>>>(mlp_w, wb, Dn, FGn, FGPn, Dn * FGPn / 8);
  gemm_sk<<<256, 512, 0, stream>>>(gv, wb, Pm0, Pm1, FGPn, FGPn / 2, Dn, BTn / 256);
  // 10) out += P0 + P1
  reduce_k<<<BTn * Dn / 8 / 256, 256, 0, stream>>>(out, Pm0, Pm1);
}

// Round 16
// 711.116 us; speedup vs baseline: 1.3844x; 1.0268x over previous
//
#include <hip/hip_runtime.h>
#include <hip/hip_bf16.h>
#include <stdint.h>

typedef __bf16 bf16_t;
typedef __bf16 bf16x8 __attribute__((ext_vector_type(8)));
typedef float  f32x4  __attribute__((ext_vector_type(4)));

#define DEV __device__ __forceinline__

constexpr int   Bn = 2, Tn = 2048, Dn = 2048, Hn = 16, DHn = 128;
constexpr int   BTn = Bn * Tn;          // 4096 rows
constexpr int   TD3 = 3 * Dn;           // 6144
constexpr int   FGn = 5461, FGPn = 5504; // pad to 43*128 (688 blocks, %8==0)
constexpr float EPSf   = 1e-5f;
constexpr float LOG2E  = 1.4426950408889634f;
constexpr float ASCALE = 0.08838834764831845f;   // 1/sqrt(128)
constexpr float LN1E4  = 9.210340371976184f;     // ln(10000)

// async global->LDS, 16B per lane, wave-uniform LDS base
DEV void gld16(void* lds, const void* g) {
  __builtin_amdgcn_global_load_lds(
      (__attribute__((address_space(1))) void*)(void*)g,
      (__attribute__((address_space(3))) void*)lds, 16, 0, 0);
}

// inline-asm LDS read, ordered only by explicit s_waitcnt lgkmcnt(N)
DEV bf16x8 dsr128(const bf16_t* p) {
  bf16x8 r;
  asm volatile("ds_read_b128 %0, %1"
               : "=v"(r)
               : "v"((const __attribute__((address_space(3))) bf16_t*)p));
  return r;
}

// ---------------- RMSNorm (fp32 in -> bf16 out) ----------------
__global__ __launch_bounds__(256)
void rmsnorm_k(const float* __restrict__ x, const float* __restrict__ w,
               bf16_t* __restrict__ out) {
  const int row = blockIdx.x;
  const int tid = threadIdx.x;
  const float* xr = x + (size_t)row * Dn;
  float4 a = ((const float4*)xr)[tid * 2];
  float4 b = ((const float4*)xr)[tid * 2 + 1];
  float ss = a.x*a.x + a.y*a.y + a.z*a.z + a.w*a.w
           + b.x*b.x + b.y*b.y + b.z*b.z + b.w*b.w;
#pragma unroll
  for (int off = 32; off > 0; off >>= 1) ss += __shfl_xor(ss, off, 64);
  __shared__ float red[4];
  if ((tid & 63) == 0) red[tid >> 6] = ss;
  __syncthreads();
  float tot = red[0] + red[1] + red[2] + red[3];
  float rms = rsqrtf(tot * (1.0f / Dn) + EPSf);
  float4 wa = ((const float4*)w)[tid * 2];
  float4 wb = ((const float4*)w)[tid * 2 + 1];
  bf16x8 o;
  o[0] = (bf16_t)(a.x * rms * wa.x); o[1] = (bf16_t)(a.y * rms * wa.y);
  o[2] = (bf16_t)(a.z * rms * wa.z); o[3] = (bf16_t)(a.w * rms * wa.w);
  o[4] = (bf16_t)(b.x * rms * wb.x); o[5] = (bf16_t)(b.y * rms * wb.y);
  o[6] = (bf16_t)(b.z * rms * wb.z); o[7] = (bf16_t)(b.w * rms * wb.w);
  *(bf16x8*)&out[(size_t)row * Dn + tid * 8] = o;
}

// ------- fused: x1 = x + P0 + P1 (fp32 out) ; h = rmsnorm(x1)*w (bf16) ----
__global__ __launch_bounds__(256)
void rms_fused(const float* __restrict__ x, const bf16_t* __restrict__ P0,
               const bf16_t* __restrict__ P1, const float* __restrict__ w,
               float* __restrict__ out, bf16_t* __restrict__ h) {
  const int row = blockIdx.x;
  const int tid = threadIdx.x;
  const size_t base = (size_t)row * Dn + tid * 8;
  float4 a = ((const float4*)(x + base))[0];
  float4 b = ((const float4*)(x + base))[1];
  bf16x8 p0 = *(const bf16x8*)&P0[base];
  bf16x8 p1 = *(const bf16x8*)&P1[base];
  float v[8];
  v[0] = a.x + (float)p0[0] + (float)p1[0];
  v[1] = a.y + (float)p0[1] + (float)p1[1];
  v[2] = a.z + (float)p0[2] + (float)p1[2];
  v[3] = a.w + (float)p0[3] + (float)p1[3];
  v[4] = b.x + (float)p0[4] + (float)p1[4];
  v[5] = b.y + (float)p0[5] + (float)p1[5];
  v[6] = b.z + (float)p0[6] + (float)p1[6];
  v[7] = b.w + (float)p0[7] + (float)p1[7];
  float4 o0 = {v[0], v[1], v[2], v[3]};
  float4 o1 = {v[4], v[5], v[6], v[7]};
  ((float4*)(out + base))[0] = o0;
  ((float4*)(out + base))[1] = o1;
  float ss = 0.f;
#pragma unroll
  for (int k = 0; k < 8; ++k) ss += v[k] * v[k];
#pragma unroll
  for (int off = 32; off > 0; off >>= 1) ss += __shfl_xor(ss, off, 64);
  __shared__ float red[4];
  if ((tid & 63) == 0) red[tid >> 6] = ss;
  __syncthreads();
  float tot = red[0] + red[1] + red[2] + red[3];
  float rms = rsqrtf(tot * (1.0f / Dn) + EPSf);
  float4 wa = ((const float4*)w)[tid * 2];
  float4 wb = ((const float4*)w)[tid * 2 + 1];
  bf16x8 o;
  o[0] = (bf16_t)(v[0] * rms * wa.x); o[1] = (bf16_t)(v[1] * rms * wa.y);
  o[2] = (bf16_t)(v[2] * rms * wa.z); o[3] = (bf16_t)(v[3] * rms * wa.w);
  o[4] = (bf16_t)(v[4] * rms * wb.x); o[5] = (bf16_t)(v[5] * rms * wb.y);
  o[6] = (bf16_t)(v[6] * rms * wb.z); o[7] = (bf16_t)(v[7] * rms * wb.w);
  *(bf16x8*)&h[base] = o;
}

// ---------------- fp32 -> bf16 convert with zero padding ----------------
__global__ __launch_bounds__(256)
void cvt_pad_k(const float* __restrict__ src, bf16_t* __restrict__ dst,
               int srcR, int srcC, int dstC, int n8) {
  int i = blockIdx.x * 256 + threadIdx.x;
  if (i >= n8) return;
  long base = (long)i * 8;
  int r = (int)(base / dstC);
  int c = (int)(base % dstC);
  bf16x8 o;
#pragma unroll
  for (int k = 0; k < 8; ++k) {
    int cc = c + k;
    float v = (r < srcR && cc < srcC) ? src[(size_t)r * srcC + cc] : 0.0f;
    o[k] = (bf16_t)v;
  }
  *(bf16x8*)&dst[base] = o;
}

// ------------- reduce: out += P0 + P1 (mlp epilogue) ---------------------
__global__ __launch_bounds__(256)
void reduce_k(float* __restrict__ out, const bf16_t* __restrict__ P0,
              const bf16_t* __restrict__ P1) {
  int i = blockIdx.x * 256 + threadIdx.x;
  bf16x8 p0 = *(const bf16x8*)&P0[(size_t)i * 8];
  bf16x8 p1 = *(const bf16x8*)&P1[(size_t)i * 8];
  float4 o0 = ((const float4*)out)[i * 2];
  float4 o1 = ((const float4*)out)[i * 2 + 1];
  o0.x += (float)p0[0] + (float)p1[0];
  o0.y += (float)p0[1] + (float)p1[1];
  o0.z += (float)p0[2] + (float)p1[2];
  o0.w += (float)p0[3] + (float)p1[3];
  o1.x += (float)p0[4] + (float)p1[4];
  o1.y += (float)p0[5] + (float)p1[5];
  o1.z += (float)p0[6] + (float)p1[6];
  o1.w += (float)p0[7] + (float)p1[7];
  ((float4*)out)[i * 2]     = o0;
  ((float4*)out)[i * 2 + 1] = o1;
}

// -------- split-K=2 GEMM, BK=64 2-slot (best measured: ~5860 cyc/K64) ----
__global__ __launch_bounds__(512, 2)
void gemm_sk(const bf16_t* __restrict__ A, const bf16_t* __restrict__ W,
             bf16_t* __restrict__ P0, bf16_t* __restrict__ P1,
             int ldk, int klen, int ldc, int nby) {
  __shared__ __align__(128) bf16_t As[2][256 * 64];   // 2 x 32KB
  __shared__ __align__(128) bf16_t Bs[2][256 * 64];   // 2 x 32KB
  const int tid = threadIdx.x;
  const int lane = tid & 63, w = tid >> 6;
  const int wm = w >> 2, wn = w & 3;
  const int g = lane >> 4, q = lane & 15;

  const int nwg = gridDim.x;               // % 8 == 0
  const int cpx = nwg >> 3;
  const int nid = (blockIdx.x & 7) * cpx + (blockIdx.x >> 3);
  const int half = nwg >> 1;
  const int s   = nid / half;
  const int rem = nid % half;
  const int bx = rem / nby, by = rem % nby;
  const int row0 = by * 256, col0 = bx * 256;
  const int kofs = s * klen;
  bf16_t* P = s ? P1 : P0;

  f32x4 acc[8][4] = {};

  const bf16_t* Asrc[4];
  const bf16_t* Wsrc[4];
  int aoff[4];
#pragma unroll
  for (int i = 0; i < 4; ++i) {
    int ci = i * 512 + tid;
    int r  = ci >> 3;
    int cs = (ci & 7) ^ (r & 7);
    Asrc[i] = A + (size_t)(row0 + r) * ldk + kofs + cs * 8;
    Wsrc[i] = W + (size_t)(col0 + r) * ldk + kofs + cs * 8;
    aoff[i] = i * 8192 + w * 1024;
  }

  int offA[2][8], offB[2][4];
#pragma unroll
  for (int kk = 0; kk < 2; ++kk) {
#pragma unroll
    for (int m = 0; m < 8; ++m) {
      int r = wm * 128 + m * 16 + q;
      offA[kk][m] = r * 128 + (((kk * 4 + g) ^ (r & 7)) * 16);
    }
#pragma unroll
    for (int n = 0; n < 4; ++n) {
      int r = wn * 64 + n * 16 + q;
      offB[kk][n] = r * 128 + (((kk * 4 + g) ^ (r & 7)) * 16);
    }
  }

  const int NT = klen >> 6;
  auto stage = [&](int T, int h) {
    const int slot = T & 1;
    const size_t kk = (size_t)T * 64;
#pragma unroll
    for (int i = 0; i < 2; ++i) {
      int rd = h * 2 + i;
      gld16((char*)As[slot] + aoff[rd], Asrc[rd] + kk);
      gld16((char*)Bs[slot] + aoff[rd], Wsrc[rd] + kk);
    }
  };

  bf16x8 af[8], bfr[4];

  auto half_rd = [&](const char* as_, const char* bs_, int kk) {
#pragma unroll
    for (int m = 0; m < 8; ++m) af[m] = dsr128((const bf16_t*)(as_ + offA[kk][m]));
#pragma unroll
    for (int n = 0; n < 4; ++n) bfr[n] = dsr128((const bf16_t*)(bs_ + offB[kk][n]));
  };
  auto mfmas = [&]() {
    asm volatile("s_waitcnt lgkmcnt(0)" ::: "memory");
    __builtin_amdgcn_sched_barrier(0);
    __builtin_amdgcn_s_setprio(1);
#pragma unroll
    for (int m = 0; m < 8; ++m)
#pragma unroll
      for (int n = 0; n < 4; ++n)
        acc[m][n] = __builtin_amdgcn_mfma_f32_16x16x32_bf16(af[m], bfr[n], acc[m][n], 0, 0, 0);
    __builtin_amdgcn_s_setprio(0);
    __builtin_amdgcn_sched_barrier(0);
  };

  stage(0, 0); stage(0, 1);
  asm volatile("s_waitcnt vmcnt(0)" ::: "memory");
  asm volatile("s_barrier" ::: "memory");

  for (int T = 0; T < NT; ++T) {
    const char* as_ = (const char*)As[T & 1];
    const char* bs_ = (const char*)Bs[T & 1];
    const bool st = (T + 1 < NT);
    half_rd(as_, bs_, 0);
    if (st) stage(T + 1, 0);
    mfmas();
    half_rd(as_, bs_, 1);
    if (st) stage(T + 1, 1);
    mfmas();
    if (st) asm volatile("s_waitcnt vmcnt(0)" ::: "memory");
    asm volatile("s_barrier" ::: "memory");
  }

#pragma unroll
  for (int m = 0; m < 8; ++m)
#pragma unroll
    for (int n = 0; n < 4; ++n)
#pragma unroll
      for (int j = 0; j < 4; ++j) {
        int r = row0 + wm * 128 + m * 16 + g * 4 + j;
        int c = col0 + wn * 64 + n * 16 + q;
        P[(size_t)r * ldc + c] = (bf16_t)acc[m][n][j];
      }
}

// ------- fused gate+val dual GEMM, BK=64: Out = silu(A Wg^T)*(A Wv^T) -----
__global__ __launch_bounds__(512, 2)
void gemmgv(const bf16_t* __restrict__ A, const bf16_t* __restrict__ Wg,
            const bf16_t* __restrict__ Wv, bf16_t* __restrict__ Out,
            int K, int ldc, int nby) {
  __shared__ __align__(128) bf16_t As[2][256 * 64];   // 2 x 32KB
  __shared__ __align__(128) bf16_t Gs[2][128 * 64];   // 2 x 16KB
  __shared__ __align__(128) bf16_t Vs[2][128 * 64];   // 2 x 16KB
  const int tid = threadIdx.x;
  const int lane = tid & 63, w = tid >> 6;
  const int wm = w >> 2, wn = w & 3;
  const int g = lane >> 4, q = lane & 15;

  const int nwg = gridDim.x;                 // 688, % 8 == 0
  const int cpx = nwg >> 3;
  const int nid = (blockIdx.x & 7) * cpx + (blockIdx.x >> 3);
  const int bx = nid / nby, by = nid % nby;
  const int row0 = by * 256, col0 = bx * 128;

  f32x4 accg[8][2] = {}, accv[8][2] = {};

  const bf16_t* Asrc[4];
  int aoff[4];
#pragma unroll
  for (int i = 0; i < 4; ++i) {
    int ci = i * 512 + tid;
    int r  = ci >> 3;
    int cs = (ci & 7) ^ (r & 7);
    Asrc[i] = A + (size_t)(row0 + r) * K + cs * 8;
    aoff[i] = i * 8192 + w * 1024;
  }
  const bf16_t* Gsrc[2];
  const bf16_t* Vsrc[2];
  int boff[2];
#pragma unroll
  for (int i = 0; i < 2; ++i) {
    int ci = i * 512 + tid;
    int r  = ci >> 3;
    int cs = (ci & 7) ^ (r & 7);
    Gsrc[i] = Wg + (size_t)(col0 + r) * K + cs * 8;
    Vsrc[i] = Wv + (size_t)(col0 + r) * K + cs * 8;
    boff[i] = i * 8192 + w * 1024;
  }

  int offA[2][8], offB[2][2];
#pragma unroll
  for (int kk = 0; kk < 2; ++kk) {
#pragma unroll
    for (int m = 0; m < 8; ++m) {
      int r = wm * 128 + m * 16 + q;
      offA[kk][m] = r * 128 + (((kk * 4 + g) ^ (r & 7)) * 16);
    }
#pragma unroll
    for (int n = 0; n < 2; ++n) {
      int r = wn * 32 + n * 16 + q;
      offB[kk][n] = r * 128 + (((kk * 4 + g) ^ (r & 7)) * 16);
    }
  }

  const int NT = K >> 6;                 // 32
  auto stage = [&](int T, int h) {
    const int slot = T & 1;
    const size_t kk = (size_t)T * 64;
#pragma unroll
    for (int i = 0; i < 2; ++i) {
      int rd = h * 2 + i;
      gld16((char*)As[slot] + aoff[rd], Asrc[rd] + kk);
    }
    gld16((char*)Gs[slot] + boff[h], Gsrc[h] + kk);
    gld16((char*)Vs[slot] + boff[h], Vsrc[h] + kk);
  };

  bf16x8 af[8], bg[2], bv[2];

  auto half_rd = [&](const char* as_, const char* gs_, const char* vs_, int kk) {
#pragma unroll
    for (int m = 0; m < 8; ++m) af[m] = dsr128((const bf16_t*)(as_ + offA[kk][m]));
#pragma unroll
    for (int n = 0; n < 2; ++n) {
      bg[n] = dsr128((const bf16_t*)(gs_ + offB[kk][n]));
      bv[n] = dsr128((const bf16_t*)(vs_ + offB[kk][n]));
    }
  };
  auto mfmas = [&]() {
    asm volatile("s_waitcnt lgkmcnt(0)" ::: "memory");
    __builtin_amdgcn_sched_barrier(0);
    __builtin_amdgcn_s_setprio(1);
#pragma unroll
    for (int m = 0; m < 8; ++m)
#pragma unroll
      for (int n = 0; n < 2; ++n) {
        accg[m][n] = __builtin_amdgcn_mfma_f32_16x16x32_bf16(af[m], bg[n], accg[m][n], 0, 0, 0);
        accv[m][n] = __builtin_amdgcn_mfma_f32_16x16x32_bf16(af[m], bv[n], accv[m][n], 0, 0, 0);
      }
    __builtin_amdgcn_s_setprio(0);
    __builtin_amdgcn_sched_barrier(0);
  };

  stage(0, 0); stage(0, 1);
  asm volatile("s_waitcnt vmcnt(0)" ::: "memory");
  asm volatile("s_barrier" ::: "memory");

  for (int T = 0; T < NT; ++T) {
    const char* as_ = (const char*)As[T & 1];
    const char* gs_ = (const char*)Gs[T & 1];
    const char* vs_ = (const char*)Vs[T & 1];
    const bool st = (T + 1 < NT);
    half_rd(as_, gs_, vs_, 0);
    if (st) stage(T + 1, 0);
    mfmas();
    half_rd(as_, gs_, vs_, 1);
    if (st) stage(T + 1, 1);
    mfmas();
    if (st) asm volatile("s_waitcnt vmcnt(0)" ::: "memory");
    asm volatile("s_barrier" ::: "memory");
  }

#pragma unroll
  for (int m = 0; m < 8; ++m) {
#pragma unroll
    for (int n = 0; n < 2; ++n) {
#pragma unroll
      for (int j = 0; j < 4; ++j) {
        int r = row0 + wm * 128 + m * 16 + g * 4 + j;
        int c = col0 + wn * 32 + n * 16 + q;
        float gt = accg[m][n][j];
        float sg = gt / (1.0f + __expf(-gt));
        Out[(size_t)r * ldc + c] = (bf16_t)(sg * accv[m][n][j]);
      }
    }
  }
}

// -------- fused RoPE: reads qkv split-K partials (P0+P1), split + V^T ----
__global__ __launch_bounds__(256)
void rope_fused(const bf16_t* __restrict__ P0, const bf16_t* __restrict__ P1,
                bf16_t* __restrict__ Qb, bf16_t* __restrict__ Kb,
                bf16_t* __restrict__ Vt) {
  const int t0 = blockIdx.x * 32;
  const int bh = blockIdx.y;
  const int b = bh >> 4, hh = bh & 15;
  __shared__ bf16_t Vl[32][132];

#pragma unroll
  for (int it = 0; it < 2; ++it) {
    int task = threadIdx.x + it * 256;
    int tt = task >> 4, ck = task & 15, d0 = ck * 8;
    int tg = t0 + tt;
    const size_t rb = (size_t)(b * Tn + tg) * TD3 + hh * DHn + d0;
    bf16x8 q0 = *(const bf16x8*)&P0[rb];
    bf16x8 q1 = *(const bf16x8*)&P1[rb];
    bf16x8 k0 = *(const bf16x8*)&P0[rb + Dn];
    bf16x8 k1 = *(const bf16x8*)&P1[rb + Dn];
    bf16x8 v0 = *(const bf16x8*)&P0[rb + 2 * Dn];
    bf16x8 v1 = *(const bf16x8*)&P1[rb + 2 * Dn];
    bf16x8 qo, ko, vo;
#pragma unroll
    for (int p = 0; p < 4; ++p) {
      int jj = (d0 >> 1) + p;
      float fr = __expf(-((float)(2 * jj) / 128.0f) * LN1E4);
      float ang = (float)tg * fr;
      float cs = cosf(ang), sn = sinf(ang);
      float qe = (float)q0[2 * p] + (float)q1[2 * p];
      float qod = (float)q0[2 * p + 1] + (float)q1[2 * p + 1];
      float ke = (float)k0[2 * p] + (float)k1[2 * p];
      float kod = (float)k0[2 * p + 1] + (float)k1[2 * p + 1];
      qo[2 * p]     = (bf16_t)((qe * cs - qod * sn) * ASCALE);
      qo[2 * p + 1] = (bf16_t)((qod * cs + qe * sn) * ASCALE);
      ko[2 * p]     = (bf16_t)(ke * cs - kod * sn);
      ko[2 * p + 1] = (bf16_t)(kod * cs + ke * sn);
      vo[2 * p]     = (bf16_t)((float)v0[2 * p] + (float)v1[2 * p]);
      vo[2 * p + 1] = (bf16_t)((float)v0[2 * p + 1] + (float)v1[2 * p + 1]);
    }
    *(bf16x8*)&Qb[((size_t)bh * Tn + tg) * DHn + d0] = qo;
    *(bf16x8*)&Kb[((size_t)bh * Tn + tg) * DHn + d0] = ko;
    *(bf16x8*)&Vl[tt][d0] = vo;
  }
  __syncthreads();
#pragma unroll
  for (int it = 0; it < 2; ++it) {
    int task = threadIdx.x + it * 256;
    int dd = task >> 2, tc = (task & 3) * 8;
    bf16x8 ov;
#pragma unroll
    for (int i = 0; i < 8; ++i) ov[i] = Vl[tc + i][dd];
    *(bf16x8*)&Vt[((size_t)bh * DHn + dd) * Tn + t0 + tc] = ov;
  }
}

// ---------------- causal flash attention, paired q-tiles ----------------
__global__ __launch_bounds__(256, 2)
void attn_k(const bf16_t* __restrict__ Qb, const bf16_t* __restrict__ Kb,
            const bf16_t* __restrict__ Vt, bf16_t* __restrict__ Y) {
  const int orig = blockIdx.x + 16 * blockIdx.y;   // 512 blocks total
  const int nid  = (orig & 7) * 64 + (orig >> 3);  // XCD-chunked, bijective
  const int pi = nid & 15;
  const int bh = nid >> 4;
  const int b = bh >> 4, hh = bh & 15;
  const int tid = threadIdx.x, lane = tid & 63, w = tid >> 6;
  const int g = lane >> 4, q = lane & 15;
  const int iA = pi, iB = 31 - pi;
  const int kmax = iB;

  __shared__ bf16_t Ks[2][64 * 128];
  __shared__ bf16_t Vs[2][128 * 64];
  __shared__ bf16_t Ps[4][16 * 72];

  bf16x8 aqA[4], aqB[4];
  {
    const bf16_t* QrA = Qb + ((size_t)bh * Tn + iA * 64 + w * 16 + q) * DHn;
    const bf16_t* QrB = Qb + ((size_t)bh * Tn + iB * 64 + w * 16 + q) * DHn;
#pragma unroll
    for (int s = 0; s < 4; ++s) {
      aqA[s] = *(const bf16x8*)(QrA + s * 32 + g * 8);
      aqB[s] = *(const bf16x8*)(QrB + s * 32 + g * 8);
    }
  }

  f32x4 oA[8] = {}, oB[8] = {};
  float mA[4], lA[4], mB[4], lB[4];
#pragma unroll
  for (int j = 0; j < 4; ++j) {
    mA[j] = -__builtin_inff(); lA[j] = 0.0f;
    mB[j] = -__builtin_inff(); lB[j] = 0.0f;
  }

  auto stage = [&](int buf, int kt) {
    const int k0 = kt * 64;
#pragma unroll
    for (int l = 0; l < 4; ++l) {
      int ci = (w * 4 + l) * 64 + lane;
      int kr = ci >> 4, kc = (ci & 15) ^ (kr & 7);
      gld16((char*)Ks[buf] + (w * 4 + l) * 1024,
            Kb + ((size_t)bh * Tn + k0 + kr) * DHn + kc * 8);
      int vr = ci >> 3, vc = (ci & 7) ^ (vr & 7);
      gld16((char*)Vs[buf] + (w * 4 + l) * 1024,
            Vt + ((size_t)bh * DHn + vr) * Tn + k0 + vc * 8);
    }
  };

  stage(0, 0);

  for (int kt = 0; kt <= kmax; ++kt) {
    __syncthreads();
    if (kt < kmax) stage((kt + 1) & 1, kt + 1);
    const bf16_t* ks = Ks[kt & 1];
    const bf16_t* vs = Vs[kt & 1];
    const bool actA = (kt <= iA);
    const int k0 = kt * 64;

    f32x4 saA[4] = {}, saB[4] = {};
    __builtin_amdgcn_s_setprio(1);
    if (actA) {
#pragma unroll
      for (int s = 0; s < 4; ++s) {
#pragma unroll
        for (int n = 0; n < 4; ++n) {
          bf16x8 bk = *(const bf16x8*)&ks[(n * 16 + q) * 128 + (((s * 4 + g) ^ (q & 7)) * 8)];
          saA[n] = __builtin_amdgcn_mfma_f32_16x16x32_bf16(aqA[s], bk, saA[n], 0, 0, 0);
          saB[n] = __builtin_amdgcn_mfma_f32_16x16x32_bf16(aqB[s], bk, saB[n], 0, 0, 0);
        }
      }
    } else {
#pragma unroll
      for (int s = 0; s < 4; ++s) {
#pragma unroll
        for (int n = 0; n < 4; ++n) {
          bf16x8 bk = *(const bf16x8*)&ks[(n * 16 + q) * 128 + (((s * 4 + g) ^ (q & 7)) * 8)];
          saB[n] = __builtin_amdgcn_mfma_f32_16x16x32_bf16(aqB[s], bk, saB[n], 0, 0, 0);
        }
      }
    }
    __builtin_amdgcn_s_setprio(0);

    bf16x8 paA[2], paB[2];
    auto softmax_p = [&](f32x4* sa, float* mst, float* lst, int itile,
                         bf16x8* pa, int qrow) {
      if (kt == itile) {
#pragma unroll
        for (int n = 0; n < 4; ++n)
#pragma unroll
          for (int j = 0; j < 4; ++j) {
            int kc = k0 + n * 16 + q;
            int qr = qrow + g * 4 + j;
            if (kc > qr) sa[n][j] = -1e30f;
          }
      }
      float mx[4];
#pragma unroll
      for (int j = 0; j < 4; ++j) {
        mx[j] = fmaxf(fmaxf(sa[0][j], sa[1][j]), fmaxf(sa[2][j], sa[3][j]));
#pragma unroll
        for (int off = 1; off < 16; off <<= 1)
          mx[j] = fmaxf(mx[j], __shfl_xor(mx[j], off, 16));
      }
      float ps[4][4], rsum[4];
#pragma unroll
      for (int j = 0; j < 4; ++j) rsum[j] = 0.0f;
      float mnew[4], corr[4];
#pragma unroll
      for (int j = 0; j < 4; ++j) {
        mnew[j] = fmaxf(mst[j], mx[j]);
        corr[j] = exp2f((mst[j] - mnew[j]) * LOG2E);
      }
#pragma unroll
      for (int n = 0; n < 4; ++n)
#pragma unroll
        for (int j = 0; j < 4; ++j) {
          ps[n][j] = exp2f((sa[n][j] - mnew[j]) * LOG2E);
          rsum[j] += ps[n][j];
        }
#pragma unroll
      for (int j = 0; j < 4; ++j) {
#pragma unroll
        for (int off = 1; off < 16; off <<= 1)
          rsum[j] += __shfl_xor(rsum[j], off, 16);
        lst[j] = lst[j] * corr[j] + rsum[j];
        mst[j] = mnew[j];
      }
#pragma unroll
      for (int n = 0; n < 4; ++n)
#pragma unroll
        for (int j = 0; j < 4; ++j)
          Ps[w][(g * 4 + j) * 72 + n * 16 + q] = (bf16_t)ps[n][j];
#pragma unroll
      for (int s2 = 0; s2 < 2; ++s2)
        pa[s2] = *(const bf16x8*)&Ps[w][q * 72 + s2 * 32 + g * 8];
      return corr;
    };

    float cA[4], cB[4];
    if (actA) {
      auto c = softmax_p(saA, mA, lA, iA, paA, iA * 64 + w * 16);
#pragma unroll
      for (int j = 0; j < 4; ++j) cA[j] = c[j];
#pragma unroll
      for (int n8 = 0; n8 < 8; ++n8)
#pragma unroll
        for (int j = 0; j < 4; ++j) oA[n8][j] *= cA[j];
    }
    {
      auto c = softmax_p(saB, mB, lB, iB, paB, iB * 64 + w * 16);
#pragma unroll
      for (int j = 0; j < 4; ++j) cB[j] = c[j];
#pragma unroll
      for (int n8 = 0; n8 < 8; ++n8)
#pragma unroll
        for (int j = 0; j < 4; ++j) oB[n8][j] *= cB[j];
    }

    __builtin_amdgcn_s_setprio(1);
    if (actA) {
#pragma unroll
      for (int s2 = 0; s2 < 2; ++s2)
#pragma unroll
        for (int n8 = 0; n8 < 8; ++n8) {
          bf16x8 bv = *(const bf16x8*)&vs[(n8 * 16 + q) * 64 + (((s2 * 4 + g) ^ (q & 7)) * 8)];
          oA[n8] = __builtin_amdgcn_mfma_f32_16x16x32_bf16(paA[s2], bv, oA[n8], 0, 0, 0);
          oB[n8] = __builtin_amdgcn_mfma_f32_16x16x32_bf16(paB[s2], bv, oB[n8], 0, 0, 0);
        }
    } else {
#pragma unroll
      for (int s2 = 0; s2 < 2; ++s2)
#pragma unroll
        for (int n8 = 0; n8 < 8; ++n8) {
          bf16x8 bv = *(const bf16x8*)&vs[(n8 * 16 + q) * 64 + (((s2 * 4 + g) ^ (q & 7)) * 8)];
          oB[n8] = __builtin_amdgcn_mfma_f32_16x16x32_bf16(paB[s2], bv, oB[n8], 0, 0, 0);
        }
    }
    __builtin_amdgcn_s_setprio(0);
  }

#pragma unroll
  for (int n8 = 0; n8 < 8; ++n8)
#pragma unroll
    for (int j = 0; j < 4; ++j) {
      int trA = iA * 64 + w * 16 + g * 4 + j;
      int trB = iB * 64 + w * 16 + g * 4 + j;
      Y[(size_t)(b * Tn + trA) * Dn + hh * DHn + n8 * 16 + q] =
          (bf16_t)(oA[n8][j] / lA[j]);
      Y[(size_t)(b * Tn + trB) * Dn + hh * DHn + n8 * 16 + q] =
          (bf16_t)(oB[n8][j] / lB[j]);
    }
}

// ---------------- launcher ----------------
// Liveness plan (all stream-ordered):
//  h:    h1 -> y(attn out) -> h2 -> Pm0
//  bufA: Pq1 -> Pp0/Pp1 -> wbV(val weights) -> Pm1
//  bufB: Pq0 -> gv
//  wb:   attn_w -> Qb -> proj_w -> gate_w -> mlp_w
//  dout: Kb+Vt (scratch) -> x1 -> final out
extern "C" void kernel_launch(void* const* d_in, const int* in_sizes, int n_in,
                              void* d_out, int out_size, void* d_ws, size_t ws_size,
                              hipStream_t stream) {
  const float* x      = (const float*)d_in[0];
  const float* n1w    = (const float*)d_in[1];
  const float* n2w    = (const float*)d_in[2];
  const float* attn_w = (const float*)d_in[3];
  const float* proj_w = (const float*)d_in[4];
  const float* gate_w = (const float*)d_in[5];
  const float* val_w  = (const float*)d_in[6];
  const float* mlp_w  = (const float*)d_in[7];

  char* ws = (char*)d_ws;
  bf16_t* h    = (bf16_t*)(ws);                  // 16.78MB
  bf16_t* bufA = (bf16_t*)(ws + 16777216);       // 50.3MB
  bf16_t* bufB = (bf16_t*)(ws + 67108864);       // 50.3MB
  bf16_t* wb   = (bf16_t*)(ws + 117440512);      // 25.2MB

  bf16_t* Pq0  = bufB;                 // qkv partial 0
  bf16_t* Pq1  = bufA;                 // qkv partial 1
  bf16_t* Qb   = wb;                   // 16.78MB (attn_w dead after qkv gemm)
  bf16_t* Kb   = (bf16_t*)d_out;       // d_out scratch lower 16.78MB
  bf16_t* Vt   = (bf16_t*)d_out + (size_t)32 * Tn * DHn;  // upper 16.78MB
  bf16_t* y    = h;
  bf16_t* Pp0  = bufA;                 // proj partial 0 (16.78MB)
  bf16_t* Pp1  = bufA + (size_t)BTn * Dn;  // proj partial 1
  bf16_t* wbV  = bufA;                 // val weights (Pp dead after rms_fused)
  bf16_t* gv   = bufB;                 // gate*val (Pq0 dead after rope)
  bf16_t* Pm0  = h;                    // mlp partial 0 (h2 dead after gemmgv)
  bf16_t* Pm1  = bufA;                 // mlp partial 1 (wbV dead after gemmgv)
  float*  out  = (float*)d_out;

  // 1) h1 = rmsnorm(x)
  rmsnorm_k<<<BTn, 256, 0, stream>>>(x, n1w, h);
  // 2) qkv partials (split-K=2, 768 blocks = 3 full generations)
  cvt_pad_k<<<(TD3 * Dn / 8 + 255) / 256, 256, 0, stream>>>(attn_w, wb, TD3, Dn, Dn, TD3 * Dn / 8);
  gemm_sk<<<768, 512, 0, stream>>>(h, wb, Pq0, Pq1, Dn, Dn / 2, TD3, BTn / 256);
  // 3) fused reduce+rope+split+V^T: Q->wb, K/Vt->d_out scratch
  rope_fused<<<dim3(Tn / 32, 32), 256, 0, stream>>>(Pq0, Pq1, Qb, Kb, Vt);
  // 4) attention -> y (=h)
  attn_k<<<dim3(16, 32), 256, 0, stream>>>(Qb, Kb, Vt, y);
  // 5) proj partials (split-K=2, 256 blocks full-chip)
  cvt_pad_k<<<(Dn * Dn / 8 + 255) / 256, 256, 0, stream>>>(proj_w, wb, Dn, Dn, Dn, Dn * Dn / 8);
  gemm_sk<<<256, 512, 0, stream>>>(y, wb, Pp0, Pp1, Dn, Dn / 2, Dn, BTn / 256);
  // 6) fused: x1 = x + Pp0 + Pp1 -> out(d_out; K/Vt dead) ; h2 = rmsnorm(x1)
  rms_fused<<<BTn, 256, 0, stream>>>(x, Pp0, Pp1, n2w, out, h);
  // 7+8) gv = silu(h2 @ gate_w^T) * (h2 @ val_w^T)
  cvt_pad_k<<<(FGPn * Dn / 8 + 255) / 256, 256, 0, stream>>>(gate_w, wb, FGn, Dn, Dn, FGPn * Dn / 8);
  cvt_pad_k<<<(FGPn * Dn / 8 + 255) / 256, 256, 0, stream>>>(val_w, wbV, FGn, Dn, Dn, FGPn * Dn / 8);
  gemmgv<<<(FGPn / 128) * (BTn / 256), 512, 0, stream>>>(h, wb, wbV, gv, Dn, FGPn, BTn / 256);
  // 9) mlp partials (split-K=2, 256 blocks)
  cvt_pad_k<<<(Dn * FGPn / 8 + 255) / 256, 256, 0, stream>>>(mlp_w, wb, Dn, FGn, FGPn, Dn * FGPn / 8);
  gemm_sk<<<256, 512, 0, stream>>>(gv, wb, Pm0, Pm1, FGPn, FGPn / 2, Dn, BTn / 256);
  // 10) out += Pm0 + Pm1
  reduce_k<<<BTn * Dn / 8 / 256, 256, 0, stream>>>(out, Pm0, Pm1);
}